// Round 1
// baseline (4927.637 us; speedup 1.0000x reference)
//
#include <hip/hip_runtime.h>
#include <math.h>

#define B_    8
#define SEQ_  8192
#define D_    512
#define N_    1023
#define DWT_  511
#define DFF_  2048
#define MR_   (B_ * DWT_)          // 4088 rows for all [B*L, D] GEMMs

// ---------------- d_out layout (flat concat of the 5 outputs) ----------------
#define PREDS_O    0
#define RECON_O    768
#define RECON_LEN  1022
#define PATCHES_O  (RECON_O + 8*512*1022)   // 4186880
#define OUT_LL_O   (PATCHES_O + 8*512*1023) // 8377088
#define OUT_LH_O   (OUT_LL_O + 8*512*511)   // 10470144

// ---------------- workspace layout (floats) ----------------
#define WS_MEAN   ((size_t)0)
#define WS_STD    ((size_t)8)
#define WS_XN     ((size_t)16)
#define WS_PSEQ   ((size_t)65552)
#define WS_LLSEQ  ((size_t)4255760)
#define WS_LHSEQ  ((size_t)6348816)
#define WS_Q      ((size_t)8441872)
#define WS_K      ((size_t)10534928)
#define WS_V      ((size_t)12627984)
#define WS_OT     ((size_t)14721040)
#define WS_LLOUT  ((size_t)16814096)
#define WS_LHOUT  ((size_t)18907152)
#define WS_CROSS  ((size_t)21000208)
#define WS_GATE   ((size_t)23093264)
#define WS_LLF    ((size_t)23097352)
#define WS_LHF    ((size_t)25190408)
// aliases (phase-disjoint):
#define WS_HID    WS_Q        // 8372224 floats = Q+K+V+OT region exactly
#define WS_LLO    WS_LLOUT
#define WS_LHO    WS_LHOUT
#define WS_PART   WS_CROSS    // 1022*768 = 784896 < 2093056

// ---------------------------------------------------------------------------
__global__ __launch_bounds__(256) void k_revin(const float* __restrict__ x,
    const float* __restrict__ rw, const float* __restrict__ rb,
    float* __restrict__ meanp, float* __restrict__ stdp, float* __restrict__ xn)
{
  __shared__ float rs[256], rs2[256];
  int b = blockIdx.x, tid = threadIdx.x;
  const float* xb = x + (size_t)b * SEQ_;
  float s = 0.f, s2 = 0.f;
  for (int i = tid; i < SEQ_; i += 256) { float v = xb[i]; s += v; s2 += v * v; }
  rs[tid] = s; rs2[tid] = s2; __syncthreads();
  for (int o = 128; o > 0; o >>= 1) {
    if (tid < o) { rs[tid] += rs[tid + o]; rs2[tid] += rs2[tid + o]; }
    __syncthreads();
  }
  float mu = rs[0] / SEQ_;
  float var = rs2[0] / SEQ_ - mu * mu;
  float sd = sqrtf(var + 1e-5f);
  if (tid == 0) { meanp[b] = mu; stdp[b] = sd; }
  float w = rw[0], bb = rb[0], inv = 1.f / sd;
  for (int i = tid; i < SEQ_; i += 256)
    xn[(size_t)b * SEQ_ + i] = (xb[i] - mu) * inv * w + bb;
}

// ---------------------------------------------------------------------------
__global__ __launch_bounds__(512) void k_patch(const float* __restrict__ xn,
    const float* __restrict__ pW, const float* __restrict__ pb,
    const float* __restrict__ pos, float* __restrict__ p_seq)
{
  __shared__ float sx[16];
  int n = blockIdx.x, b = blockIdx.y, d = threadIdx.x;
  if (threadIdx.x < 16) sx[threadIdx.x] = xn[(size_t)b * SEQ_ + n * 8 + threadIdx.x];
  __syncthreads();
  float acc = pb[d] + pos[(size_t)n * D_ + d];
#pragma unroll
  for (int k = 0; k < 16; ++k) acc += sx[k] * pW[k * D_ + d];
  p_seq[((size_t)b * N_ + n) * D_ + d] = acc;
}

// ---------------------------------------------------------------------------
__global__ __launch_bounds__(256) void k_transpose(const float* __restrict__ p_seq,
                                                   float* __restrict__ outp)
{
  __shared__ float tile[32][33];
  int d0 = blockIdx.x * 32, n0 = blockIdx.y * 32, b = blockIdx.z;
  int tx = threadIdx.x, ty = threadIdx.y;
#pragma unroll
  for (int r = 0; r < 4; ++r) {
    int n = n0 + ty + 8 * r;
    if (n < N_) tile[ty + 8 * r][tx] = p_seq[((size_t)b * N_ + n) * D_ + d0 + tx];
  }
  __syncthreads();
#pragma unroll
  for (int r = 0; r < 4; ++r) {
    int d = d0 + ty + 8 * r, n = n0 + tx;
    if (n < N_) outp[((size_t)b * D_ + d) * N_ + n] = tile[tx][ty + 8 * r];
  }
}

// ---------------------------------------------------------------------------
__global__ __launch_bounds__(512) void k_dwt(const float* __restrict__ p_seq,
    const float* __restrict__ h, const float* __restrict__ g,
    float* __restrict__ ll_seq, float* __restrict__ lh_seq,
    float* __restrict__ ll_out, float* __restrict__ lh_out)
{
  int t = blockIdx.x, b = blockIdx.y, d = threadIdx.x;
  float ah = 0.f, ag = 0.f;
#pragma unroll
  for (int k = 0; k < 4; ++k) {
    int n = 2 * t + k - 1;
    if (n >= 0 && n < N_) {
      float v = p_seq[((size_t)b * N_ + n) * D_ + d];
      ah += v * h[d * 4 + k];
      ag += v * g[d * 4 + k];
    }
  }
  ll_seq[((size_t)b * DWT_ + t) * D_ + d] = ah;
  lh_seq[((size_t)b * DWT_ + t) * D_ + d] = ag;
  ll_out[((size_t)b * D_ + d) * DWT_ + t] = ah;
  lh_out[((size_t)b * D_ + d) * DWT_ + t] = ag;
}

// ---------------------------------------------------------------------------
// C[M,N] = A[M,K] @ W[K,N] (+bias[n]) (+res[m,n]); K multiple of 16, N mult of 64
__global__ __launch_bounds__(256) void k_gemm(const float* __restrict__ A,
    const float* __restrict__ W, const float* __restrict__ bias,
    const float* __restrict__ res, float* __restrict__ C, int M, int N, int K)
{
  __shared__ float sA[16][64];
  __shared__ float sB[16][64];
  int tid = threadIdx.x;
  int n0 = blockIdx.x * 64, m0 = blockIdx.y * 64;
  int tx = tid & 15, ty = tid >> 4;
  float acc[4][4] = {};
  for (int k0 = 0; k0 < K; k0 += 16) {
    {
      int r = tid >> 2, c = (tid & 3) << 2;
      int row = m0 + r;
      const float* src = A + (size_t)(row < M ? row : (M - 1)) * K + k0 + c;
      float4 v = *(const float4*)src;
      if (row >= M) { v.x = v.y = v.z = v.w = 0.f; }
      sA[c + 0][r] = v.x; sA[c + 1][r] = v.y; sA[c + 2][r] = v.z; sA[c + 3][r] = v.w;
    }
    {
      int r = tid >> 4, c = (tid & 15) << 2;
      float4 v = *(const float4*)(W + (size_t)(k0 + r) * N + n0 + c);
      *(float4*)&sB[r][c] = v;
    }
    __syncthreads();
#pragma unroll
    for (int kk = 0; kk < 16; ++kk) {
      float4 a4 = *(float4*)&sA[kk][ty * 4];
      float4 b4 = *(float4*)&sB[kk][tx * 4];
      float av[4] = {a4.x, a4.y, a4.z, a4.w};
      float bv[4] = {b4.x, b4.y, b4.z, b4.w};
#pragma unroll
      for (int i = 0; i < 4; ++i)
#pragma unroll
        for (int j = 0; j < 4; ++j) acc[i][j] += av[i] * bv[j];
    }
    __syncthreads();
  }
#pragma unroll
  for (int i = 0; i < 4; ++i) {
    int m = m0 + ty * 4 + i;
    if (m >= M) break;
#pragma unroll
    for (int j = 0; j < 4; ++j) {
      int n = n0 + tx * 4 + j;
      float v = acc[i][j];
      if (bias) v += bias[n];
      if (res) v += res[(size_t)m * N + n];
      C[(size_t)m * N + n] = v;
    }
  }
}

// ---------------------------------------------------------------------------
__global__ __launch_bounds__(64) void k_gate(const float* __restrict__ lh_seq,
    const float* __restrict__ raw_tau, float* __restrict__ gate)
{
  int row = blockIdx.x, lane = threadIdx.x;
  float s = 0.f;
#pragma unroll
  for (int j = 0; j < 8; ++j) s += fabsf(lh_seq[(size_t)row * D_ + lane + 64 * j]);
#pragma unroll
  for (int off = 32; off; off >>= 1) s += __shfl_xor(s, off);
  if (lane == 0) {
    float tau = 1.f / (1.f + expf(-raw_tau[0]));
    float e = s / (float)D_;
    gate[row] = 1.f / (1.f + expf(-(e - tau) * 10.f));
  }
}

// ---------------------------------------------------------------------------
// one wave per query; lane = head-dim element (Dh=64). gate nullable.
__global__ __launch_bounds__(256) void k_attn(const float* __restrict__ Q,
    const float* __restrict__ K, const float* __restrict__ V,
    float* __restrict__ O, const float* __restrict__ gate)
{
  int bh = blockIdx.x;
  int b = bh >> 3, h = bh & 7;
  int w = threadIdx.x >> 6, lane = threadIdx.x & 63;
  int q = blockIdx.y * 4 + w;
  if (q >= DWT_) return;
  size_t base = ((size_t)b * DWT_) * D_ + h * 64 + lane;
  float qv = Q[base + (size_t)q * D_] * 0.125f;   // 1/sqrt(64)
  float vals[8];
#pragma unroll
  for (int j = 0; j < 8; ++j) {
    float sv = -3.0e38f;
    int mbase = j * 64;
    int mmax = (j == 7) ? 63 : 64;
    for (int i = 0; i < mmax; ++i) {
      float dd = qv * K[base + (size_t)(mbase + i) * D_];
#pragma unroll
      for (int off = 32; off; off >>= 1) dd += __shfl_xor(dd, off);
      sv = (lane == i) ? dd : sv;
    }
    vals[j] = sv;
  }
  float gmax = -3.0e38f;
#pragma unroll
  for (int j = 0; j < 8; ++j) gmax = fmaxf(gmax, vals[j]);
#pragma unroll
  for (int off = 32; off; off >>= 1) gmax = fmaxf(gmax, __shfl_xor(gmax, off));
  float lsum = 0.f;
#pragma unroll
  for (int j = 0; j < 8; ++j) { float e = expf(vals[j] - gmax); vals[j] = e; lsum += e; }
#pragma unroll
  for (int off = 32; off; off >>= 1) lsum += __shfl_xor(lsum, off);
  float inv = 1.f / lsum;
#pragma unroll
  for (int j = 0; j < 8; ++j) {
    int m = j * 64 + lane;
    float gv = 1.f;
    if (gate) gv = gate[(size_t)b * DWT_ + (m < DWT_ ? m : 0)];
    vals[j] *= inv * gv;
  }
  float acc = 0.f;
#pragma unroll
  for (int j = 0; j < 8; ++j) {
    int mbase = j * 64;
    int mmax = (j == 7) ? 63 : 64;
    for (int i = 0; i < mmax; ++i) {
      float wgt = __shfl(vals[j], i);
      acc += wgt * V[base + (size_t)(mbase + i) * D_];
    }
  }
  O[base + (size_t)q * D_] = acc;
}

// ---------------------------------------------------------------------------
__global__ __launch_bounds__(256) void k_ln(const float* __restrict__ a,
    const float* __restrict__ b2, const float* __restrict__ c,
    const float* __restrict__ g, const float* __restrict__ beta,
    float* __restrict__ outp)
{
  __shared__ float red[256], red2[256];
  int row = blockIdx.x, tid = threadIdx.x;
  size_t base = (size_t)row * D_;
  float v0 = a[base + tid], v1 = a[base + tid + 256];
  if (b2) { v0 += b2[base + tid]; v1 += b2[base + tid + 256]; }
  if (c)  { v0 += c[base + tid];  v1 += c[base + tid + 256]; }
  red[tid] = v0 + v1; red2[tid] = v0 * v0 + v1 * v1;
  __syncthreads();
  for (int o = 128; o > 0; o >>= 1) {
    if (tid < o) { red[tid] += red[tid + o]; red2[tid] += red2[tid + o]; }
    __syncthreads();
  }
  float mu = red[0] / (float)D_;
  float var = red2[0] / (float)D_ - mu * mu;
  float rstd = rsqrtf(var + 1e-5f);
  outp[base + tid]       = (v0 - mu) * rstd * g[tid] + beta[tid];
  outp[base + tid + 256] = (v1 - mu) * rstd * g[tid + 256] + beta[tid + 256];
}

// ---------------------------------------------------------------------------
__global__ void k_gelu(float* __restrict__ p, int n)
{
  int i = blockIdx.x * blockDim.x + threadIdx.x;
  int stride = gridDim.x * blockDim.x;
  for (; i < n; i += stride) {
    float v = p[i];
    p[i] = 0.5f * v * (1.f + erff(v * 0.70710678118654752f));
  }
}

// ---------------------------------------------------------------------------
// block x = branch*511 + t; computes partial[x][b*96+p] = sum_d fused * W
__global__ __launch_bounds__(256) void k_head_partial(
    const float* __restrict__ llo, const float* __restrict__ lho,
    const float* __restrict__ llg, const float* __restrict__ lhg,
    const float* __restrict__ hw, float* __restrict__ part)
{
  __shared__ float lds[8][512];
  int x = blockIdx.x;
  int branch = x / DWT_, t = x % DWT_;
  const float* seq = branch ? lho : llo;
  const float* gt  = branch ? lhg : llg;
  int tid = threadIdx.x;
  for (int i = tid; i < 8 * 512; i += 256) {
    int b = i >> 9, d = i & 511;
    lds[b][d] = seq[((size_t)b * DWT_ + t) * D_ + d] * gt[(size_t)t * D_ + d];
  }
  __syncthreads();
  size_t kbase = (size_t)x * D_;
  float acc[3] = {0.f, 0.f, 0.f};
  int pb[3], pr[3];
#pragma unroll
  for (int pi = 0; pi < 3; ++pi) {
    int pidx = tid + 256 * pi; pb[pi] = pidx / 96; pr[pi] = pidx % 96;
  }
  for (int k = 0; k < 512; ++k) {
    const float* wrow = hw + (kbase + k) * 96;
#pragma unroll
    for (int pi = 0; pi < 3; ++pi) acc[pi] += lds[pb[pi]][k] * wrow[pr[pi]];
  }
#pragma unroll
  for (int pi = 0; pi < 3; ++pi) part[(size_t)x * 768 + tid + 256 * pi] = acc[pi];
}

__global__ __launch_bounds__(128) void k_head_final(const float* __restrict__ part,
    const float* __restrict__ hb, const float* __restrict__ rw,
    const float* __restrict__ rb, const float* __restrict__ meanp,
    const float* __restrict__ stdp, float* __restrict__ preds)
{
  int b = blockIdx.x, p = threadIdx.x;
  if (p >= 96) return;
  float acc = hb[p];
  for (int c = 0; c < 1022; ++c) acc += part[(size_t)c * 768 + b * 96 + p];
  preds[b * 96 + p] = (acc - rb[0]) / (rw[0] + 1e-10f) * stdp[b] + meanp[b];
}

// ---------------------------------------------------------------------------
// inverse DWT (transposed grouped conv), output length 1022
__global__ __launch_bounds__(512) void k_recon(const float* __restrict__ llo,
    const float* __restrict__ lho, const float* __restrict__ h,
    const float* __restrict__ g, float* __restrict__ outp)
{
  int o = blockIdx.x, b = blockIdx.y, d = threadIdx.x;
  const float* hd = h + d * 4;
  const float* gd = g + d * 4;
  float acc = 0.f;
  if ((o & 1) == 0) {
    int t = o >> 1;
    if (t >= 1) {
      size_t i = ((size_t)b * DWT_ + t - 1) * D_ + d;
      acc += llo[i] * hd[3] + lho[i] * gd[3];
    }
    size_t i = ((size_t)b * DWT_ + t) * D_ + d;
    acc += llo[i] * hd[1] + lho[i] * gd[1];
  } else {
    int t = (o - 1) >> 1;
    size_t i = ((size_t)b * DWT_ + t) * D_ + d;
    acc += llo[i] * hd[2] + lho[i] * gd[2];
    if (t + 1 < DWT_) {
      size_t i2 = ((size_t)b * DWT_ + t + 1) * D_ + d;
      acc += llo[i2] * hd[0] + lho[i2] * gd[0];
    }
  }
  outp[((size_t)b * D_ + d) * RECON_LEN + o] = acc;
}

// ---------------------------------------------------------------------------
extern "C" void kernel_launch(void* const* d_in, const int* in_sizes, int n_in,
                              void* d_out, int out_size, void* d_ws, size_t ws_size,
                              hipStream_t stream)
{
  const float* x       = (const float*)d_in[0];
  const float* revin_w = (const float*)d_in[1];
  const float* revin_b = (const float*)d_in[2];
  const float* patch_W = (const float*)d_in[3];
  const float* patch_b = (const float*)d_in[4];
  const float* pos_emb = (const float*)d_in[5];
  const float* dwt_h   = (const float*)d_in[6];
  const float* dwt_g   = (const float*)d_in[7];
  const float* raw_tau = (const float*)d_in[8];
  const float* attn_W  = (const float*)d_in[9];
  const float* attn_b  = (const float*)d_in[10];
  const float* mlp_W1  = (const float*)d_in[11];
  const float* mlp_b1  = (const float*)d_in[12];
  const float* mlp_W2  = (const float*)d_in[13];
  const float* mlp_b2  = (const float*)d_in[14];
  const float* ln_g    = (const float*)d_in[15];
  const float* ln_b    = (const float*)d_in[16];
  const float* ll_gate = (const float*)d_in[17];
  const float* lh_gate = (const float*)d_in[18];
  const float* head_W  = (const float*)d_in[19];
  const float* head_b  = (const float*)d_in[20];

  float* ws  = (float*)d_ws;
  float* out = (float*)d_out;

  float* meanp = ws + WS_MEAN;
  float* stdp  = ws + WS_STD;
  float* xn    = ws + WS_XN;
  float* pseq  = ws + WS_PSEQ;
  float* llseq = ws + WS_LLSEQ;
  float* lhseq = ws + WS_LHSEQ;
  float* Qb    = ws + WS_Q;
  float* Kb    = ws + WS_K;
  float* Vb    = ws + WS_V;
  float* Ob    = ws + WS_OT;
  float* llout = ws + WS_LLOUT;
  float* lhout = ws + WS_LHOUT;
  float* crossb= ws + WS_CROSS;
  float* gateb = ws + WS_GATE;
  float* llf   = ws + WS_LLF;
  float* lhf   = ws + WS_LHF;
  float* hid   = ws + WS_HID;
  float* llo   = ws + WS_LLO;
  float* lho   = ws + WS_LHO;
  float* part  = ws + WS_PART;

  auto gemm = [&](const float* A, const float* W, const float* bias,
                  const float* res, float* C, int M, int N, int K) {
    dim3 g((N + 63) / 64, (M + 63) / 64);
    k_gemm<<<g, 256, 0, stream>>>(A, W, bias, res, C, M, N, K);
  };

  // ---- stage 0: RevIN + patch embed + patches output + DWT ----
  k_revin<<<8, 256, 0, stream>>>(x, revin_w, revin_b, meanp, stdp, xn);
  k_patch<<<dim3(N_, B_), 512, 0, stream>>>(xn, patch_W, patch_b, pos_emb, pseq);
  k_transpose<<<dim3(16, 32, B_), dim3(32, 8), 0, stream>>>(pseq, out + PATCHES_O);
  k_dwt<<<dim3(DWT_, B_), 512, 0, stream>>>(pseq, dwt_h, dwt_g, llseq, lhseq,
                                            out + OUT_LL_O, out + OUT_LH_O);

  // ---- stage 1: three MHAs ----
  auto mha = [&](const float* qx, const float* kx, const float* vx, int widx,
                 const float* gate, float* dst) {
    const float* W  = attn_W + (size_t)widx * 4 * D_ * D_;
    const float* bb = attn_b + (size_t)widx * 4 * D_;
    gemm(qx, W + 0 * D_ * D_, bb + 0 * D_, nullptr, Qb, MR_, D_, D_);
    gemm(kx, W + 1 * D_ * D_, bb + 1 * D_, nullptr, Kb, MR_, D_, D_);
    gemm(vx, W + 2 * D_ * D_, bb + 2 * D_, nullptr, Vb, MR_, D_, D_);
    k_attn<<<dim3(B_ * 8, 128), 256, 0, stream>>>(Qb, Kb, Vb, Ob, gate);
    gemm(Ob, W + 3 * D_ * D_, bb + 3 * D_, nullptr, dst, MR_, D_, D_);
  };

  mha(llseq, llseq, llseq, 0, nullptr, llout);
  k_gate<<<MR_, 64, 0, stream>>>(lhseq, raw_tau, gateb);
  mha(lhseq, lhseq, lhseq, 1, gateb, lhout);
  mha(llout, lhout, lhout, 2, nullptr, crossb);

  // ---- stage 2: LN + MLP ----
  k_ln<<<MR_, 256, 0, stream>>>(llseq, llout, crossb, ln_g, ln_b, llf);
  k_ln<<<MR_, 256, 0, stream>>>(lhseq, lhout, nullptr, ln_g + D_, ln_b + D_, lhf);

  gemm(llf, mlp_W1, mlp_b1, nullptr, hid, MR_, DFF_, D_);
  k_gelu<<<2048, 256, 0, stream>>>(hid, MR_ * DFF_);
  gemm(hid, mlp_W2, mlp_b2, llf, llo, MR_, D_, DFF_);

  gemm(lhf, mlp_W1 + (size_t)D_ * DFF_, mlp_b1 + DFF_, nullptr, hid, MR_, DFF_, D_);
  k_gelu<<<2048, 256, 0, stream>>>(hid, MR_ * DFF_);
  gemm(hid, mlp_W2 + (size_t)DFF_ * D_, mlp_b2 + D_, lhf, lho, MR_, D_, DFF_);

  // ---- stage 3: head + denorm ----
  k_head_partial<<<2 * DWT_, 256, 0, stream>>>(llo, lho, ll_gate, lh_gate, head_W, part);
  k_head_final<<<B_, 128, 0, stream>>>(part, head_b, revin_w, revin_b, meanp, stdp,
                                       out + PREDS_O);

  // ---- stage 4: inverse DWT recon ----
  k_recon<<<dim3(RECON_LEN, B_), 512, 0, stream>>>(llo, lho, dwt_h, dwt_g, out + RECON_O);
}

// Round 2
// 1994.856 us; speedup vs baseline: 2.4702x; 2.4702x over previous
//
#include <hip/hip_runtime.h>
#include <math.h>

#define B_    8
#define SEQ_  8192
#define D_    512
#define N_    1023
#define DWT_  511
#define DFF_  2048
#define MR_   (B_ * DWT_)          // 4088 rows for all [B*L, D] GEMMs

// ---------------- d_out layout (flat concat of the 5 outputs) ----------------
#define PREDS_O    0
#define RECON_O    768
#define RECON_LEN  1022
#define PATCHES_O  (RECON_O + 8*512*1022)   // 4186880
#define OUT_LL_O   (PATCHES_O + 8*512*1023) // 8377088
#define OUT_LH_O   (OUT_LL_O + 8*512*511)   // 10470144

// ---------------- workspace layout (floats) ----------------
#define WS_MEAN   ((size_t)0)
#define WS_STD    ((size_t)8)
#define WS_XN     ((size_t)16)
#define WS_PSEQ   ((size_t)65552)
#define WS_LLSEQ  ((size_t)4255760)
#define WS_LHSEQ  ((size_t)6348816)
#define WS_Q      ((size_t)8441872)
#define WS_K      ((size_t)10534928)
#define WS_V      ((size_t)12627984)
#define WS_OT     ((size_t)14721040)
#define WS_LLOUT  ((size_t)16814096)
#define WS_LHOUT  ((size_t)18907152)
#define WS_CROSS  ((size_t)21000208)
#define WS_GATE   ((size_t)23093264)
#define WS_LLF    ((size_t)23097352)
#define WS_LHF    ((size_t)25190408)
// aliases (phase-disjoint):
#define WS_HID    WS_Q        // 8372224 floats = Q+K+V+OT region exactly
#define WS_LLO    WS_LLOUT
#define WS_LHO    WS_LHOUT
#define WS_PART   WS_CROSS    // 1022*768 = 784896 < 2093056

// ---------------------------------------------------------------------------
__global__ __launch_bounds__(256) void k_revin(const float* __restrict__ x,
    const float* __restrict__ rw, const float* __restrict__ rb,
    float* __restrict__ meanp, float* __restrict__ stdp, float* __restrict__ xn)
{
  __shared__ float rs[256], rs2[256];
  int b = blockIdx.x, tid = threadIdx.x;
  const float* xb = x + (size_t)b * SEQ_;
  float s = 0.f, s2 = 0.f;
  for (int i = tid; i < SEQ_; i += 256) { float v = xb[i]; s += v; s2 += v * v; }
  rs[tid] = s; rs2[tid] = s2; __syncthreads();
  for (int o = 128; o > 0; o >>= 1) {
    if (tid < o) { rs[tid] += rs[tid + o]; rs2[tid] += rs2[tid + o]; }
    __syncthreads();
  }
  float mu = rs[0] / SEQ_;
  float var = rs2[0] / SEQ_ - mu * mu;
  float sd = sqrtf(var + 1e-5f);
  if (tid == 0) { meanp[b] = mu; stdp[b] = sd; }
  float w = rw[0], bb = rb[0], inv = 1.f / sd;
  for (int i = tid; i < SEQ_; i += 256)
    xn[(size_t)b * SEQ_ + i] = (xb[i] - mu) * inv * w + bb;
}

// ---------------------------------------------------------------------------
__global__ __launch_bounds__(512) void k_patch(const float* __restrict__ xn,
    const float* __restrict__ pW, const float* __restrict__ pb,
    const float* __restrict__ pos, float* __restrict__ p_seq)
{
  __shared__ float sx[16];
  int n = blockIdx.x, b = blockIdx.y, d = threadIdx.x;
  if (threadIdx.x < 16) sx[threadIdx.x] = xn[(size_t)b * SEQ_ + n * 8 + threadIdx.x];
  __syncthreads();
  float acc = pb[d] + pos[(size_t)n * D_ + d];
#pragma unroll
  for (int k = 0; k < 16; ++k) acc += sx[k] * pW[k * D_ + d];
  p_seq[((size_t)b * N_ + n) * D_ + d] = acc;
}

// ---------------------------------------------------------------------------
__global__ __launch_bounds__(256) void k_transpose(const float* __restrict__ p_seq,
                                                   float* __restrict__ outp)
{
  __shared__ float tile[32][33];
  int d0 = blockIdx.x * 32, n0 = blockIdx.y * 32, b = blockIdx.z;
  int tx = threadIdx.x, ty = threadIdx.y;
#pragma unroll
  for (int r = 0; r < 4; ++r) {
    int n = n0 + ty + 8 * r;
    if (n < N_) tile[ty + 8 * r][tx] = p_seq[((size_t)b * N_ + n) * D_ + d0 + tx];
  }
  __syncthreads();
#pragma unroll
  for (int r = 0; r < 4; ++r) {
    int d = d0 + ty + 8 * r, n = n0 + tx;
    if (n < N_) outp[((size_t)b * D_ + d) * N_ + n] = tile[tx][ty + 8 * r];
  }
}

// ---------------------------------------------------------------------------
__global__ __launch_bounds__(512) void k_dwt(const float* __restrict__ p_seq,
    const float* __restrict__ h, const float* __restrict__ g,
    float* __restrict__ ll_seq, float* __restrict__ lh_seq,
    float* __restrict__ ll_out, float* __restrict__ lh_out)
{
  int t = blockIdx.x, b = blockIdx.y, d = threadIdx.x;
  float ah = 0.f, ag = 0.f;
#pragma unroll
  for (int k = 0; k < 4; ++k) {
    int n = 2 * t + k - 1;
    if (n >= 0 && n < N_) {
      float v = p_seq[((size_t)b * N_ + n) * D_ + d];
      ah += v * h[d * 4 + k];
      ag += v * g[d * 4 + k];
    }
  }
  ll_seq[((size_t)b * DWT_ + t) * D_ + d] = ah;
  lh_seq[((size_t)b * DWT_ + t) * D_ + d] = ag;
  ll_out[((size_t)b * D_ + d) * DWT_ + t] = ah;
  lh_out[((size_t)b * D_ + d) * DWT_ + t] = ag;
}

// ---------------------------------------------------------------------------
// C[M,N] = A[M,K] @ W[K,N] (+bias[n]) (+res[m,n]); K multiple of 16, N mult of 64
__global__ __launch_bounds__(256) void k_gemm(const float* __restrict__ A,
    const float* __restrict__ W, const float* __restrict__ bias,
    const float* __restrict__ res, float* __restrict__ C, int M, int N, int K)
{
  __shared__ float sA[16][64];
  __shared__ float sB[16][64];
  int tid = threadIdx.x;
  int n0 = blockIdx.x * 64, m0 = blockIdx.y * 64;
  int tx = tid & 15, ty = tid >> 4;
  float acc[4][4] = {};
  for (int k0 = 0; k0 < K; k0 += 16) {
    {
      int r = tid >> 2, c = (tid & 3) << 2;
      int row = m0 + r;
      const float* src = A + (size_t)(row < M ? row : (M - 1)) * K + k0 + c;
      float4 v = *(const float4*)src;
      if (row >= M) { v.x = v.y = v.z = v.w = 0.f; }
      sA[c + 0][r] = v.x; sA[c + 1][r] = v.y; sA[c + 2][r] = v.z; sA[c + 3][r] = v.w;
    }
    {
      int r = tid >> 4, c = (tid & 15) << 2;
      float4 v = *(const float4*)(W + (size_t)(k0 + r) * N + n0 + c);
      *(float4*)&sB[r][c] = v;
    }
    __syncthreads();
#pragma unroll
    for (int kk = 0; kk < 16; ++kk) {
      float4 a4 = *(float4*)&sA[kk][ty * 4];
      float4 b4 = *(float4*)&sB[kk][tx * 4];
      float av[4] = {a4.x, a4.y, a4.z, a4.w};
      float bv[4] = {b4.x, b4.y, b4.z, b4.w};
#pragma unroll
      for (int i = 0; i < 4; ++i)
#pragma unroll
        for (int j = 0; j < 4; ++j) acc[i][j] += av[i] * bv[j];
    }
    __syncthreads();
  }
#pragma unroll
  for (int i = 0; i < 4; ++i) {
    int m = m0 + ty * 4 + i;
    if (m >= M) break;
#pragma unroll
    for (int j = 0; j < 4; ++j) {
      int n = n0 + tx * 4 + j;
      float v = acc[i][j];
      if (bias) v += bias[n];
      if (res) v += res[(size_t)m * N + n];
      C[(size_t)m * N + n] = v;
    }
  }
}

// ---------------------------------------------------------------------------
__global__ __launch_bounds__(64) void k_gate(const float* __restrict__ lh_seq,
    const float* __restrict__ raw_tau, float* __restrict__ gate)
{
  int row = blockIdx.x, lane = threadIdx.x;
  float s = 0.f;
#pragma unroll
  for (int j = 0; j < 8; ++j) s += fabsf(lh_seq[(size_t)row * D_ + lane + 64 * j]);
#pragma unroll
  for (int off = 32; off; off >>= 1) s += __shfl_xor(s, off);
  if (lane == 0) {
    float tau = 1.f / (1.f + expf(-raw_tau[0]));
    float e = s / (float)D_;
    gate[row] = 1.f / (1.f + expf(-(e - tau) * 10.f));
  }
}

// ---------------------------------------------------------------------------
// Fused flash attention. Block = (b,h,qtile of 64). 256 threads.
// Thread (qg=tid>>4, kg=tid&15): QK micro-tile 4q x 4k; PV: 4q x 4e (e0=kg*4).
// K/V/Q tiles in LDS with float4-slot XOR swizzle c4 ^ ((row>>2)&15).
__global__ __launch_bounds__(256) void k_fattn(const float* __restrict__ Q,
    const float* __restrict__ K, const float* __restrict__ V,
    float* __restrict__ O, const float* __restrict__ gate)
{
  __shared__ __align__(16) float sQ[4096];
  __shared__ __align__(16) float sK[4096];
  __shared__ __align__(16) float sV[4096];
  __shared__ __align__(16) float sS[64][68];
  __shared__ float sG[64];

  const int bh = blockIdx.x;
  const int b = bh >> 3, h = bh & 7;
  const int q0 = blockIdx.y * 64;
  const int tid = threadIdx.x;
  const int qg = tid >> 4;      // 0..15
  const int kg = tid & 15;      // 0..15
  const bool hg = (gate != nullptr);

  const size_t hbase = (size_t)b * DWT_ * D_ + h * 64;

#define SLOT(row, c4) ((((row) << 4) + ((c4) ^ (((row) >> 2) & 15))) << 2)

  // stage Q tile (scaled by 1/sqrt(Dh))
  for (int i = tid; i < 1024; i += 256) {
    int row = i >> 4, c4 = i & 15;
    int qrow = q0 + row; if (qrow > DWT_ - 1) qrow = DWT_ - 1;
    float4 v = *(const float4*)(Q + hbase + (size_t)qrow * D_ + c4 * 4);
    v.x *= 0.125f; v.y *= 0.125f; v.z *= 0.125f; v.w *= 0.125f;
    *(float4*)(sQ + SLOT(row, c4)) = v;
  }

  float m[4], l[4], acc[4][4];
#pragma unroll
  for (int qq = 0; qq < 4; ++qq) {
    m[qq] = -1e30f; l[qq] = 0.f;
#pragma unroll
    for (int e = 0; e < 4; ++e) acc[qq][e] = 0.f;
  }

  for (int kt = 0; kt < 8; ++kt) {
    int k0 = kt * 64;
    __syncthreads();                       // prior-tile PV reads complete
    for (int i = tid; i < 1024; i += 256) {
      int row = i >> 4, c4 = i & 15;
      int krow = k0 + row;
      int cr = krow > DWT_ - 1 ? DWT_ - 1 : krow;
      const float* srcK = K + hbase + (size_t)cr * D_ + c4 * 4;
      const float* srcV = V + hbase + (size_t)cr * D_ + c4 * 4;
      float4 kv = *(const float4*)srcK;
      float4 vv = *(const float4*)srcV;
      *(float4*)(sK + SLOT(row, c4)) = kv;
      *(float4*)(sV + SLOT(row, c4)) = vv;
    }
    if (hg && tid < 64) {
      int kk = k0 + tid;
      sG[tid] = (kk < DWT_) ? gate[(size_t)b * DWT_ + kk] : 0.f;
    }
    __syncthreads();

    // ---- QK^T: 4x4 micro-tile ----
    float s[4][4] = {};
#pragma unroll
    for (int d4 = 0; d4 < 16; ++d4) {
      float4 qv[4], kv[4];
#pragma unroll
      for (int qq = 0; qq < 4; ++qq) qv[qq] = *(float4*)(sQ + SLOT(qg * 4 + qq, d4));
#pragma unroll
      for (int kk = 0; kk < 4; ++kk) kv[kk] = *(float4*)(sK + SLOT(kg * 4 + kk, d4));
#pragma unroll
      for (int qq = 0; qq < 4; ++qq)
#pragma unroll
        for (int kk = 0; kk < 4; ++kk)
          s[qq][kk] += qv[qq].x * kv[kk].x + qv[qq].y * kv[kk].y +
                       qv[qq].z * kv[kk].z + qv[qq].w * kv[kk].w;
    }
#pragma unroll
    for (int kk = 0; kk < 4; ++kk)
      if (k0 + kg * 4 + kk >= DWT_) {
#pragma unroll
        for (int qq = 0; qq < 4; ++qq) s[qq][kk] = -1e30f;
      }
#pragma unroll
    for (int qq = 0; qq < 4; ++qq)
      *(float4*)&sS[qg * 4 + qq][kg * 4] = make_float4(s[qq][0], s[qq][1], s[qq][2], s[qq][3]);
    __syncthreads();

    // ---- row max scan (broadcast reads) ----
    float tm[4];
#pragma unroll
    for (int qq = 0; qq < 4; ++qq) {
      const float* row = sS[qg * 4 + qq];
      float mm = -1e30f;
#pragma unroll
      for (int k = 0; k < 64; k += 4) {
        float4 v = *(const float4*)(row + k);
        mm = fmaxf(mm, fmaxf(fmaxf(v.x, v.y), fmaxf(v.z, v.w)));
      }
      tm[qq] = mm;
    }
    // ---- online-softmax update; write p over s ----
#pragma unroll
    for (int qq = 0; qq < 4; ++qq) {
      float mn = fmaxf(m[qq], tm[qq]);
      float corr = __expf(m[qq] - mn);
      m[qq] = mn; l[qq] *= corr;
#pragma unroll
      for (int e = 0; e < 4; ++e) acc[qq][e] *= corr;
      float p0 = __expf(s[qq][0] - mn), p1 = __expf(s[qq][1] - mn);
      float p2 = __expf(s[qq][2] - mn), p3 = __expf(s[qq][3] - mn);
      *(float4*)&sS[qg * 4 + qq][kg * 4] = make_float4(p0, p1, p2, p3);
    }
    __syncthreads();

    // ---- PV + denominator ----
#pragma unroll 4
    for (int k = 0; k < 64; ++k) {
      float4 vv = *(float4*)(sV + SLOT(k, kg));
      float g = hg ? sG[k] : 1.0f;
#pragma unroll
      for (int qq = 0; qq < 4; ++qq) {
        float p = sS[qg * 4 + qq][k];
        l[qq] += p;
        float pg = p * g;
        acc[qq][0] += pg * vv.x; acc[qq][1] += pg * vv.y;
        acc[qq][2] += pg * vv.z; acc[qq][3] += pg * vv.w;
      }
    }
  }

#pragma unroll
  for (int qq = 0; qq < 4; ++qq) {
    int q = q0 + qg * 4 + qq;
    if (q >= DWT_) continue;
    float inv = 1.f / l[qq];
    float4 o = make_float4(acc[qq][0] * inv, acc[qq][1] * inv,
                           acc[qq][2] * inv, acc[qq][3] * inv);
    *(float4*)(O + hbase + (size_t)q * D_ + kg * 4) = o;
  }
#undef SLOT
}

// ---------------------------------------------------------------------------
__global__ __launch_bounds__(256) void k_ln(const float* __restrict__ a,
    const float* __restrict__ b2, const float* __restrict__ c,
    const float* __restrict__ g, const float* __restrict__ beta,
    float* __restrict__ outp)
{
  __shared__ float red[256], red2[256];
  int row = blockIdx.x, tid = threadIdx.x;
  size_t base = (size_t)row * D_;
  float v0 = a[base + tid], v1 = a[base + tid + 256];
  if (b2) { v0 += b2[base + tid]; v1 += b2[base + tid + 256]; }
  if (c)  { v0 += c[base + tid];  v1 += c[base + tid + 256]; }
  red[tid] = v0 + v1; red2[tid] = v0 * v0 + v1 * v1;
  __syncthreads();
  for (int o = 128; o > 0; o >>= 1) {
    if (tid < o) { red[tid] += red[tid + o]; red2[tid] += red2[tid + o]; }
    __syncthreads();
  }
  float mu = red[0] / (float)D_;
  float var = red2[0] / (float)D_ - mu * mu;
  float rstd = rsqrtf(var + 1e-5f);
  outp[base + tid]       = (v0 - mu) * rstd * g[tid] + beta[tid];
  outp[base + tid + 256] = (v1 - mu) * rstd * g[tid + 256] + beta[tid + 256];
}

// ---------------------------------------------------------------------------
__global__ void k_gelu(float* __restrict__ p, int n)
{
  int i = blockIdx.x * blockDim.x + threadIdx.x;
  int stride = gridDim.x * blockDim.x;
  for (; i < n; i += stride) {
    float v = p[i];
    p[i] = 0.5f * v * (1.f + erff(v * 0.70710678118654752f));
  }
}

// ---------------------------------------------------------------------------
// block x = branch*511 + t; computes partial[x][b*96+p] = sum_d fused * W
__global__ __launch_bounds__(256) void k_head_partial(
    const float* __restrict__ llo, const float* __restrict__ lho,
    const float* __restrict__ llg, const float* __restrict__ lhg,
    const float* __restrict__ hw, float* __restrict__ part)
{
  __shared__ float lds[8][512];
  int x = blockIdx.x;
  int branch = x / DWT_, t = x % DWT_;
  const float* seq = branch ? lho : llo;
  const float* gt  = branch ? lhg : llg;
  int tid = threadIdx.x;
  for (int i = tid; i < 8 * 512; i += 256) {
    int b = i >> 9, d = i & 511;
    lds[b][d] = seq[((size_t)b * DWT_ + t) * D_ + d] * gt[(size_t)t * D_ + d];
  }
  __syncthreads();
  size_t kbase = (size_t)x * D_;
  float acc[3] = {0.f, 0.f, 0.f};
  int pb[3], pr[3];
#pragma unroll
  for (int pi = 0; pi < 3; ++pi) {
    int pidx = tid + 256 * pi; pb[pi] = pidx / 96; pr[pi] = pidx % 96;
  }
  for (int k = 0; k < 512; ++k) {
    const float* wrow = hw + (kbase + k) * 96;
#pragma unroll
    for (int pi = 0; pi < 3; ++pi) acc[pi] += lds[pb[pi]][k] * wrow[pr[pi]];
  }
#pragma unroll
  for (int pi = 0; pi < 3; ++pi) part[(size_t)x * 768 + tid + 256 * pi] = acc[pi];
}

__global__ __launch_bounds__(128) void k_head_final(const float* __restrict__ part,
    const float* __restrict__ hb, const float* __restrict__ rw,
    const float* __restrict__ rb, const float* __restrict__ meanp,
    const float* __restrict__ stdp, float* __restrict__ preds)
{
  int b = blockIdx.x, p = threadIdx.x;
  if (p >= 96) return;
  float acc = hb[p];
  for (int c = 0; c < 1022; ++c) acc += part[(size_t)c * 768 + b * 96 + p];
  preds[b * 96 + p] = (acc - rb[0]) / (rw[0] + 1e-10f) * stdp[b] + meanp[b];
}

// ---------------------------------------------------------------------------
// inverse DWT (transposed grouped conv), output length 1022
__global__ __launch_bounds__(512) void k_recon(const float* __restrict__ llo,
    const float* __restrict__ lho, const float* __restrict__ h,
    const float* __restrict__ g, float* __restrict__ outp)
{
  int o = blockIdx.x, b = blockIdx.y, d = threadIdx.x;
  const float* hd = h + d * 4;
  const float* gd = g + d * 4;
  float acc = 0.f;
  if ((o & 1) == 0) {
    int t = o >> 1;
    if (t >= 1) {
      size_t i = ((size_t)b * DWT_ + t - 1) * D_ + d;
      acc += llo[i] * hd[3] + lho[i] * gd[3];
    }
    size_t i = ((size_t)b * DWT_ + t) * D_ + d;
    acc += llo[i] * hd[1] + lho[i] * gd[1];
  } else {
    int t = (o - 1) >> 1;
    size_t i = ((size_t)b * DWT_ + t) * D_ + d;
    acc += llo[i] * hd[2] + lho[i] * gd[2];
    if (t + 1 < DWT_) {
      size_t i2 = ((size_t)b * DWT_ + t + 1) * D_ + d;
      acc += llo[i2] * hd[0] + lho[i2] * gd[0];
    }
  }
  outp[((size_t)b * D_ + d) * RECON_LEN + o] = acc;
}

// ---------------------------------------------------------------------------
extern "C" void kernel_launch(void* const* d_in, const int* in_sizes, int n_in,
                              void* d_out, int out_size, void* d_ws, size_t ws_size,
                              hipStream_t stream)
{
  const float* x       = (const float*)d_in[0];
  const float* revin_w = (const float*)d_in[1];
  const float* revin_b = (const float*)d_in[2];
  const float* patch_W = (const float*)d_in[3];
  const float* patch_b = (const float*)d_in[4];
  const float* pos_emb = (const float*)d_in[5];
  const float* dwt_h   = (const float*)d_in[6];
  const float* dwt_g   = (const float*)d_in[7];
  const float* raw_tau = (const float*)d_in[8];
  const float* attn_W  = (const float*)d_in[9];
  const float* attn_b  = (const float*)d_in[10];
  const float* mlp_W1  = (const float*)d_in[11];
  const float* mlp_b1  = (const float*)d_in[12];
  const float* mlp_W2  = (const float*)d_in[13];
  const float* mlp_b2  = (const float*)d_in[14];
  const float* ln_g    = (const float*)d_in[15];
  const float* ln_b    = (const float*)d_in[16];
  const float* ll_gate = (const float*)d_in[17];
  const float* lh_gate = (const float*)d_in[18];
  const float* head_W  = (const float*)d_in[19];
  const float* head_b  = (const float*)d_in[20];

  float* ws  = (float*)d_ws;
  float* out = (float*)d_out;

  float* meanp = ws + WS_MEAN;
  float* stdp  = ws + WS_STD;
  float* xn    = ws + WS_XN;
  float* pseq  = ws + WS_PSEQ;
  float* llseq = ws + WS_LLSEQ;
  float* lhseq = ws + WS_LHSEQ;
  float* Qb    = ws + WS_Q;
  float* Kb    = ws + WS_K;
  float* Vb    = ws + WS_V;
  float* Ob    = ws + WS_OT;
  float* llout = ws + WS_LLOUT;
  float* lhout = ws + WS_LHOUT;
  float* crossb= ws + WS_CROSS;
  float* gateb = ws + WS_GATE;
  float* llf   = ws + WS_LLF;
  float* lhf   = ws + WS_LHF;
  float* hid   = ws + WS_HID;
  float* llo   = ws + WS_LLO;
  float* lho   = ws + WS_LHO;
  float* part  = ws + WS_PART;

  auto gemm = [&](const float* A, const float* W, const float* bias,
                  const float* res, float* C, int M, int N, int K) {
    dim3 g((N + 63) / 64, (M + 63) / 64);
    k_gemm<<<g, 256, 0, stream>>>(A, W, bias, res, C, M, N, K);
  };

  // ---- stage 0: RevIN + patch embed + patches output + DWT ----
  k_revin<<<8, 256, 0, stream>>>(x, revin_w, revin_b, meanp, stdp, xn);
  k_patch<<<dim3(N_, B_), 512, 0, stream>>>(xn, patch_W, patch_b, pos_emb, pseq);
  k_transpose<<<dim3(16, 32, B_), dim3(32, 8), 0, stream>>>(pseq, out + PATCHES_O);
  k_dwt<<<dim3(DWT_, B_), 512, 0, stream>>>(pseq, dwt_h, dwt_g, llseq, lhseq,
                                            out + OUT_LL_O, out + OUT_LH_O);

  // ---- stage 1: three MHAs ----
  auto mha = [&](const float* qx, const float* kx, const float* vx, int widx,
                 const float* gate, float* dst) {
    const float* W  = attn_W + (size_t)widx * 4 * D_ * D_;
    const float* bb = attn_b + (size_t)widx * 4 * D_;
    gemm(qx, W + 0 * D_ * D_, bb + 0 * D_, nullptr, Qb, MR_, D_, D_);
    gemm(kx, W + 1 * D_ * D_, bb + 1 * D_, nullptr, Kb, MR_, D_, D_);
    gemm(vx, W + 2 * D_ * D_, bb + 2 * D_, nullptr, Vb, MR_, D_, D_);
    k_fattn<<<dim3(B_ * 8, 8), 256, 0, stream>>>(Qb, Kb, Vb, Ob, gate);
    gemm(Ob, W + 3 * D_ * D_, bb + 3 * D_, nullptr, dst, MR_, D_, D_);
  };

  mha(llseq, llseq, llseq, 0, nullptr, llout);
  k_gate<<<MR_, 64, 0, stream>>>(lhseq, raw_tau, gateb);
  mha(lhseq, lhseq, lhseq, 1, gateb, lhout);
  mha(llout, lhout, lhout, 2, nullptr, crossb);

  // ---- stage 2: LN + MLP ----
  k_ln<<<MR_, 256, 0, stream>>>(llseq, llout, crossb, ln_g, ln_b, llf);
  k_ln<<<MR_, 256, 0, stream>>>(lhseq, lhout, nullptr, ln_g + D_, ln_b + D_, lhf);

  gemm(llf, mlp_W1, mlp_b1, nullptr, hid, MR_, DFF_, D_);
  k_gelu<<<2048, 256, 0, stream>>>(hid, MR_ * DFF_);
  gemm(hid, mlp_W2, mlp_b2, llf, llo, MR_, D_, DFF_);

  gemm(lhf, mlp_W1 + (size_t)D_ * DFF_, mlp_b1 + DFF_, nullptr, hid, MR_, DFF_, D_);
  k_gelu<<<2048, 256, 0, stream>>>(hid, MR_ * DFF_);
  gemm(hid, mlp_W2 + (size_t)DFF_ * D_, mlp_b2 + D_, lhf, lho, MR_, D_, DFF_);

  // ---- stage 3: head + denorm ----
  k_head_partial<<<2 * DWT_, 256, 0, stream>>>(llo, lho, ll_gate, lh_gate, head_W, part);
  k_head_final<<<B_, 128, 0, stream>>>(part, head_b, revin_w, revin_b, meanp, stdp,
                                       out + PREDS_O);

  // ---- stage 4: inverse DWT recon ----
  k_recon<<<dim3(RECON_LEN, B_), 512, 0, stream>>>(llo, lho, dwt_h, dwt_g, out + RECON_O);
}

// Round 3
// 1428.877 us; speedup vs baseline: 3.4486x; 1.3961x over previous
//
#include <hip/hip_runtime.h>
#include <math.h>

#define B_    8
#define SEQ_  8192
#define D_    512
#define N_    1023
#define DWT_  511
#define DFF_  2048
#define MR_   (B_ * DWT_)          // 4088 rows for all [B*L, D] GEMMs

// ---------------- d_out layout (flat concat of the 5 outputs) ----------------
#define PREDS_O    0
#define RECON_O    768
#define RECON_LEN  1022
#define PATCHES_O  (RECON_O + 8*512*1022)   // 4186880
#define OUT_LL_O   (PATCHES_O + 8*512*1023) // 8377088
#define OUT_LH_O   (OUT_LL_O + 8*512*511)   // 10470144

// ---------------- workspace layout (floats) ----------------
#define WS_MEAN   ((size_t)0)
#define WS_STD    ((size_t)8)
#define WS_XN     ((size_t)16)
#define WS_PSEQ   ((size_t)65552)
#define WS_LLSEQ  ((size_t)4255760)
#define WS_LHSEQ  ((size_t)6348816)
#define WS_Q      ((size_t)8441872)
#define WS_K      ((size_t)10534928)
#define WS_V      ((size_t)12627984)
#define WS_OT     ((size_t)14721040)
#define WS_LLOUT  ((size_t)16814096)
#define WS_LHOUT  ((size_t)18907152)
#define WS_CROSS  ((size_t)21000208)
#define WS_GATE   ((size_t)23093264)
#define WS_LLF    ((size_t)23097352)
#define WS_LHF    ((size_t)25190408)
// aliases (phase-disjoint):
#define WS_HID    WS_Q        // 8372224 floats = Q+K+V+OT region exactly
#define WS_LLO    WS_LLOUT
#define WS_LHO    WS_LHOUT
#define WS_PART   WS_CROSS    // 1022*768 = 784896 < 2093056
// bf16 transposed weights live in the pseq region (dead after k_dwt):
// arena = (unsigned short*)(ws + WS_PSEQ); attn: 12 x [512][512] @ z*262144;
// W1T: 2 x [2048][512] @ 3145728 + br*1048576; W2T: 2 x [512][2048] @ +2097152.
// total 7340032 bf16 = 3670016 float-slots < pseq region 4190208. OK.

using bf16x8 = __attribute__((ext_vector_type(8))) short;
using u16x8  = __attribute__((ext_vector_type(8))) unsigned short;
using f32x4  = __attribute__((ext_vector_type(4))) float;

__device__ inline unsigned short f2bf(float f) {
  unsigned u = __float_as_uint(f);
  u += 0x7fffu + ((u >> 16) & 1u);    // round-to-nearest-even
  return (unsigned short)(u >> 16);
}

// ---------------------------------------------------------------------------
__global__ __launch_bounds__(256) void k_revin(const float* __restrict__ x,
    const float* __restrict__ rw, const float* __restrict__ rb,
    float* __restrict__ meanp, float* __restrict__ stdp, float* __restrict__ xn)
{
  __shared__ float rs[256], rs2[256];
  int b = blockIdx.x, tid = threadIdx.x;
  const float* xb = x + (size_t)b * SEQ_;
  float s = 0.f, s2 = 0.f;
  for (int i = tid; i < SEQ_; i += 256) { float v = xb[i]; s += v; s2 += v * v; }
  rs[tid] = s; rs2[tid] = s2; __syncthreads();
  for (int o = 128; o > 0; o >>= 1) {
    if (tid < o) { rs[tid] += rs[tid + o]; rs2[tid] += rs2[tid + o]; }
    __syncthreads();
  }
  float mu = rs[0] / SEQ_;
  float var = rs2[0] / SEQ_ - mu * mu;
  float sd = sqrtf(var + 1e-5f);
  if (tid == 0) { meanp[b] = mu; stdp[b] = sd; }
  float w = rw[0], bb = rb[0], inv = 1.f / sd;
  for (int i = tid; i < SEQ_; i += 256)
    xn[(size_t)b * SEQ_ + i] = (xb[i] - mu) * inv * w + bb;
}

// ---------------------------------------------------------------------------
__global__ __launch_bounds__(512) void k_patch(const float* __restrict__ xn,
    const float* __restrict__ pW, const float* __restrict__ pb,
    const float* __restrict__ pos, float* __restrict__ p_seq)
{
  __shared__ float sx[16];
  int n = blockIdx.x, b = blockIdx.y, d = threadIdx.x;
  if (threadIdx.x < 16) sx[threadIdx.x] = xn[(size_t)b * SEQ_ + n * 8 + threadIdx.x];
  __syncthreads();
  float acc = pb[d] + pos[(size_t)n * D_ + d];
#pragma unroll
  for (int k = 0; k < 16; ++k) acc += sx[k] * pW[k * D_ + d];
  p_seq[((size_t)b * N_ + n) * D_ + d] = acc;
}

// ---------------------------------------------------------------------------
__global__ __launch_bounds__(256) void k_transpose(const float* __restrict__ p_seq,
                                                   float* __restrict__ outp)
{
  __shared__ float tile[32][33];
  int d0 = blockIdx.x * 32, n0 = blockIdx.y * 32, b = blockIdx.z;
  int tx = threadIdx.x, ty = threadIdx.y;
#pragma unroll
  for (int r = 0; r < 4; ++r) {
    int n = n0 + ty + 8 * r;
    if (n < N_) tile[ty + 8 * r][tx] = p_seq[((size_t)b * N_ + n) * D_ + d0 + tx];
  }
  __syncthreads();
#pragma unroll
  for (int r = 0; r < 4; ++r) {
    int d = d0 + ty + 8 * r, n = n0 + tx;
    if (n < N_) outp[((size_t)b * D_ + d) * N_ + n] = tile[tx][ty + 8 * r];
  }
}

// ---------------------------------------------------------------------------
__global__ __launch_bounds__(512) void k_dwt(const float* __restrict__ p_seq,
    const float* __restrict__ h, const float* __restrict__ g,
    float* __restrict__ ll_seq, float* __restrict__ lh_seq,
    float* __restrict__ ll_out, float* __restrict__ lh_out)
{
  int t = blockIdx.x, b = blockIdx.y, d = threadIdx.x;
  float ah = 0.f, ag = 0.f;
#pragma unroll
  for (int k = 0; k < 4; ++k) {
    int n = 2 * t + k - 1;
    if (n >= 0 && n < N_) {
      float v = p_seq[((size_t)b * N_ + n) * D_ + d];
      ah += v * h[d * 4 + k];
      ag += v * g[d * 4 + k];
    }
  }
  ll_seq[((size_t)b * DWT_ + t) * D_ + d] = ah;
  lh_seq[((size_t)b * DWT_ + t) * D_ + d] = ag;
  ll_out[((size_t)b * D_ + d) * DWT_ + t] = ah;
  lh_out[((size_t)b * D_ + d) * DWT_ + t] = ag;
}

// ---------------------------------------------------------------------------
// weight transpose+convert: src fp32 [K][N] (z-th matrix) -> dst bf16 [N][K]
__global__ __launch_bounds__(256) void k_wt(const float* __restrict__ src,
    unsigned short* __restrict__ dst, int K, int N)
{
  __shared__ float t[32][33];
  int z = blockIdx.z;
  src += (size_t)z * K * N;
  dst += (size_t)z * K * N;
  int n0 = blockIdx.x * 32, k0 = blockIdx.y * 32;
  int tx = threadIdx.x, ty = threadIdx.y;     // (32, 8)
#pragma unroll
  for (int r = 0; r < 4; ++r)
    t[ty + 8 * r][tx] = src[(size_t)(k0 + ty + 8 * r) * N + n0 + tx];
  __syncthreads();
#pragma unroll
  for (int r = 0; r < 4; ++r)
    dst[(size_t)(n0 + ty + 8 * r) * K + k0 + tx] = f2bf(t[tx][ty + 8 * r]);
}

// ---------------------------------------------------------------------------
// C[M,N] = A[M,K](fp32) @ WT[N,K](bf16)^T + bias (+res) (opt gelu), via MFMA.
// BN=128, BK=64, 256 threads (4 waves). BM=64: waves 1x4 (tile 64x32);
// BM=128: waves 2x2 (tile 64x64). XOR swizzle slot^(row&7) on 16B slots.
template<int BM>
__global__ __launch_bounds__(256) void k_gemm_mfma(
    const float* __restrict__ A, const unsigned short* __restrict__ WT,
    const float* __restrict__ bias, const float* __restrict__ res,
    float* __restrict__ C, int M, int N, int K, int act)
{
  __shared__ unsigned char lds[(BM + 128) * 128];
  unsigned char* sA = lds;
  unsigned char* sB = lds + BM * 128;

  const int tid = threadIdx.x;
  const int wid = tid >> 6, lane = tid & 63;
  const int n0 = blockIdx.x * 128, m0 = blockIdx.y * BM;
  constexpr int MI = 4;
  constexpr int NI = (BM == 128) ? 4 : 2;
  const int wrow = (BM == 128) ? (wid >> 1) * 64 : 0;
  const int wcol = (BM == 128) ? (wid & 1) * 64 : wid * 32;
  const int l16 = lane & 15, lh = lane >> 4;

  f32x4 acc[MI][NI];
#pragma unroll
  for (int i = 0; i < MI; ++i)
#pragma unroll
    for (int j = 0; j < NI; ++j) acc[i][j] = (f32x4){0.f, 0.f, 0.f, 0.f};

  constexpr int AITER = BM / 32;   // (BM*64)/(256*8)
  for (int k0 = 0; k0 < K; k0 += 64) {
    __syncthreads();
    // ---- stage A (fp32 -> bf16) ----
#pragma unroll
    for (int it = 0; it < AITER; ++it) {
      int i = it * 256 + tid;
      int row = i >> 3, oct = i & 7;
      int gr = m0 + row; if (gr > M - 1) gr = M - 1;
      const float* src = A + (size_t)gr * K + k0 + oct * 8;
      float4 v0 = *(const float4*)src;
      float4 v1 = *(const float4*)(src + 4);
      u16x8 pk;
      pk[0] = f2bf(v0.x); pk[1] = f2bf(v0.y); pk[2] = f2bf(v0.z); pk[3] = f2bf(v0.w);
      pk[4] = f2bf(v1.x); pk[5] = f2bf(v1.y); pk[6] = f2bf(v1.z); pk[7] = f2bf(v1.w);
      *(u16x8*)(sA + row * 128 + ((oct ^ (row & 7)) << 4)) = pk;
    }
    // ---- stage B (already bf16, [N][K]) ----
#pragma unroll
    for (int it = 0; it < 4; ++it) {
      int i = it * 256 + tid;
      int row = i >> 3, oct = i & 7;
      uint4 v = *(const uint4*)(WT + (size_t)(n0 + row) * K + k0 + oct * 8);
      *(uint4*)(sB + row * 128 + ((oct ^ (row & 7)) << 4)) = v;
    }
    __syncthreads();
    // ---- MFMA ----
#pragma unroll
    for (int s = 0; s < 2; ++s) {
      bf16x8 af[MI], bfr[NI];
#pragma unroll
      for (int i = 0; i < MI; ++i) {
        int r = wrow + i * 16 + l16;
        af[i] = *(const bf16x8*)(sA + r * 128 + (((s * 4 + lh) ^ (r & 7)) << 4));
      }
#pragma unroll
      for (int j = 0; j < NI; ++j) {
        int r = wcol + j * 16 + l16;
        bfr[j] = *(const bf16x8*)(sB + r * 128 + (((s * 4 + lh) ^ (r & 7)) << 4));
      }
#pragma unroll
      for (int i = 0; i < MI; ++i)
#pragma unroll
        for (int j = 0; j < NI; ++j)
          acc[i][j] = __builtin_amdgcn_mfma_f32_16x16x32_bf16(af[i], bfr[j],
                                                              acc[i][j], 0, 0, 0);
    }
  }
  // ---- epilogue: bias (+gelu) (+res), predicated M-tail ----
#pragma unroll
  for (int i = 0; i < MI; ++i) {
#pragma unroll
    for (int r = 0; r < 4; ++r) {
      int m = m0 + wrow + i * 16 + lh * 4 + r;
      if (m >= M) continue;
#pragma unroll
      for (int j = 0; j < NI; ++j) {
        int n = n0 + wcol + j * 16 + l16;
        float v = acc[i][j][r] + bias[n];
        if (act) v = 0.5f * v * (1.f + erff(v * 0.70710678118654752f));
        if (res) v += res[(size_t)m * N + n];
        C[(size_t)m * N + n] = v;
      }
    }
  }
}

// ---------------------------------------------------------------------------
__global__ __launch_bounds__(64) void k_gate(const float* __restrict__ lh_seq,
    const float* __restrict__ raw_tau, float* __restrict__ gate)
{
  int row = blockIdx.x, lane = threadIdx.x;
  float s = 0.f;
#pragma unroll
  for (int j = 0; j < 8; ++j) s += fabsf(lh_seq[(size_t)row * D_ + lane + 64 * j]);
#pragma unroll
  for (int off = 32; off; off >>= 1) s += __shfl_xor(s, off);
  if (lane == 0) {
    float tau = 1.f / (1.f + expf(-raw_tau[0]));
    float e = s / (float)D_;
    gate[row] = 1.f / (1.f + expf(-(e - tau) * 10.f));
  }
}

// ---------------------------------------------------------------------------
// Fused flash attention (unchanged from round 2).
__global__ __launch_bounds__(256) void k_fattn(const float* __restrict__ Q,
    const float* __restrict__ K, const float* __restrict__ V,
    float* __restrict__ O, const float* __restrict__ gate)
{
  __shared__ __align__(16) float sQ[4096];
  __shared__ __align__(16) float sK[4096];
  __shared__ __align__(16) float sV[4096];
  __shared__ __align__(16) float sS[64][68];
  __shared__ float sG[64];

  const int bh = blockIdx.x;
  const int b = bh >> 3, h = bh & 7;
  const int q0 = blockIdx.y * 64;
  const int tid = threadIdx.x;
  const int qg = tid >> 4;
  const int kg = tid & 15;
  const bool hg = (gate != nullptr);

  const size_t hbase = (size_t)b * DWT_ * D_ + h * 64;

#define SLOT(row, c4) ((((row) << 4) + ((c4) ^ (((row) >> 2) & 15))) << 2)

  for (int i = tid; i < 1024; i += 256) {
    int row = i >> 4, c4 = i & 15;
    int qrow = q0 + row; if (qrow > DWT_ - 1) qrow = DWT_ - 1;
    float4 v = *(const float4*)(Q + hbase + (size_t)qrow * D_ + c4 * 4);
    v.x *= 0.125f; v.y *= 0.125f; v.z *= 0.125f; v.w *= 0.125f;
    *(float4*)(sQ + SLOT(row, c4)) = v;
  }

  float m[4], l[4], acc[4][4];
#pragma unroll
  for (int qq = 0; qq < 4; ++qq) {
    m[qq] = -1e30f; l[qq] = 0.f;
#pragma unroll
    for (int e = 0; e < 4; ++e) acc[qq][e] = 0.f;
  }

  for (int kt = 0; kt < 8; ++kt) {
    int k0 = kt * 64;
    __syncthreads();
    for (int i = tid; i < 1024; i += 256) {
      int row = i >> 4, c4 = i & 15;
      int krow = k0 + row;
      int cr = krow > DWT_ - 1 ? DWT_ - 1 : krow;
      float4 kv = *(const float4*)(K + hbase + (size_t)cr * D_ + c4 * 4);
      float4 vv = *(const float4*)(V + hbase + (size_t)cr * D_ + c4 * 4);
      *(float4*)(sK + SLOT(row, c4)) = kv;
      *(float4*)(sV + SLOT(row, c4)) = vv;
    }
    if (hg && tid < 64) {
      int kk = k0 + tid;
      sG[tid] = (kk < DWT_) ? gate[(size_t)b * DWT_ + kk] : 0.f;
    }
    __syncthreads();

    float s[4][4] = {};
#pragma unroll
    for (int d4 = 0; d4 < 16; ++d4) {
      float4 qv[4], kv[4];
#pragma unroll
      for (int qq = 0; qq < 4; ++qq) qv[qq] = *(float4*)(sQ + SLOT(qg * 4 + qq, d4));
#pragma unroll
      for (int kk = 0; kk < 4; ++kk) kv[kk] = *(float4*)(sK + SLOT(kg * 4 + kk, d4));
#pragma unroll
      for (int qq = 0; qq < 4; ++qq)
#pragma unroll
        for (int kk = 0; kk < 4; ++kk)
          s[qq][kk] += qv[qq].x * kv[kk].x + qv[qq].y * kv[kk].y +
                       qv[qq].z * kv[kk].z + qv[qq].w * kv[kk].w;
    }
#pragma unroll
    for (int kk = 0; kk < 4; ++kk)
      if (k0 + kg * 4 + kk >= DWT_) {
#pragma unroll
        for (int qq = 0; qq < 4; ++qq) s[qq][kk] = -1e30f;
      }
#pragma unroll
    for (int qq = 0; qq < 4; ++qq)
      *(float4*)&sS[qg * 4 + qq][kg * 4] = make_float4(s[qq][0], s[qq][1], s[qq][2], s[qq][3]);
    __syncthreads();

    float tm[4];
#pragma unroll
    for (int qq = 0; qq < 4; ++qq) {
      const float* row = sS[qg * 4 + qq];
      float mm = -1e30f;
#pragma unroll
      for (int k = 0; k < 64; k += 4) {
        float4 v = *(const float4*)(row + k);
        mm = fmaxf(mm, fmaxf(fmaxf(v.x, v.y), fmaxf(v.z, v.w)));
      }
      tm[qq] = mm;
    }
#pragma unroll
    for (int qq = 0; qq < 4; ++qq) {
      float mn = fmaxf(m[qq], tm[qq]);
      float corr = __expf(m[qq] - mn);
      m[qq] = mn; l[qq] *= corr;
#pragma unroll
      for (int e = 0; e < 4; ++e) acc[qq][e] *= corr;
      float p0 = __expf(s[qq][0] - mn), p1 = __expf(s[qq][1] - mn);
      float p2 = __expf(s[qq][2] - mn), p3 = __expf(s[qq][3] - mn);
      *(float4*)&sS[qg * 4 + qq][kg * 4] = make_float4(p0, p1, p2, p3);
    }
    __syncthreads();

#pragma unroll 4
    for (int k = 0; k < 64; ++k) {
      float4 vv = *(float4*)(sV + SLOT(k, kg));
      float g = hg ? sG[k] : 1.0f;
#pragma unroll
      for (int qq = 0; qq < 4; ++qq) {
        float p = sS[qg * 4 + qq][k];
        l[qq] += p;
        float pg = p * g;
        acc[qq][0] += pg * vv.x; acc[qq][1] += pg * vv.y;
        acc[qq][2] += pg * vv.z; acc[qq][3] += pg * vv.w;
      }
    }
  }

#pragma unroll
  for (int qq = 0; qq < 4; ++qq) {
    int q = q0 + qg * 4 + qq;
    if (q >= DWT_) continue;
    float inv = 1.f / l[qq];
    float4 o = make_float4(acc[qq][0] * inv, acc[qq][1] * inv,
                           acc[qq][2] * inv, acc[qq][3] * inv);
    *(float4*)(O + hbase + (size_t)q * D_ + kg * 4) = o;
  }
#undef SLOT
}

// ---------------------------------------------------------------------------
__global__ __launch_bounds__(256) void k_ln(const float* __restrict__ a,
    const float* __restrict__ b2, const float* __restrict__ c,
    const float* __restrict__ g, const float* __restrict__ beta,
    float* __restrict__ outp)
{
  __shared__ float red[256], red2[256];
  int row = blockIdx.x, tid = threadIdx.x;
  size_t base = (size_t)row * D_;
  float v0 = a[base + tid], v1 = a[base + tid + 256];
  if (b2) { v0 += b2[base + tid]; v1 += b2[base + tid + 256]; }
  if (c)  { v0 += c[base + tid];  v1 += c[base + tid + 256]; }
  red[tid] = v0 + v1; red2[tid] = v0 * v0 + v1 * v1;
  __syncthreads();
  for (int o = 128; o > 0; o >>= 1) {
    if (tid < o) { red[tid] += red[tid + o]; red2[tid] += red2[tid + o]; }
    __syncthreads();
  }
  float mu = red[0] / (float)D_;
  float var = red2[0] / (float)D_ - mu * mu;
  float rstd = rsqrtf(var + 1e-5f);
  outp[base + tid]       = (v0 - mu) * rstd * g[tid] + beta[tid];
  outp[base + tid + 256] = (v1 - mu) * rstd * g[tid + 256] + beta[tid + 256];
}

// ---------------------------------------------------------------------------
__global__ __launch_bounds__(256) void k_head_partial(
    const float* __restrict__ llo, const float* __restrict__ lho,
    const float* __restrict__ llg, const float* __restrict__ lhg,
    const float* __restrict__ hw, float* __restrict__ part)
{
  __shared__ float lds[8][512];
  int x = blockIdx.x;
  int branch = x / DWT_, t = x % DWT_;
  const float* seq = branch ? lho : llo;
  const float* gt  = branch ? lhg : llg;
  int tid = threadIdx.x;
  for (int i = tid; i < 8 * 512; i += 256) {
    int b = i >> 9, d = i & 511;
    lds[b][d] = seq[((size_t)b * DWT_ + t) * D_ + d] * gt[(size_t)t * D_ + d];
  }
  __syncthreads();
  size_t kbase = (size_t)x * D_;
  float acc[3] = {0.f, 0.f, 0.f};
  int pb[3], pr[3];
#pragma unroll
  for (int pi = 0; pi < 3; ++pi) {
    int pidx = tid + 256 * pi; pb[pi] = pidx / 96; pr[pi] = pidx % 96;
  }
  for (int k = 0; k < 512; ++k) {
    const float* wrow = hw + (kbase + k) * 96;
#pragma unroll
    for (int pi = 0; pi < 3; ++pi) acc[pi] += lds[pb[pi]][k] * wrow[pr[pi]];
  }
#pragma unroll
  for (int pi = 0; pi < 3; ++pi) part[(size_t)x * 768 + tid + 256 * pi] = acc[pi];
}

__global__ __launch_bounds__(128) void k_head_final(const float* __restrict__ part,
    const float* __restrict__ hb, const float* __restrict__ rw,
    const float* __restrict__ rb, const float* __restrict__ meanp,
    const float* __restrict__ stdp, float* __restrict__ preds)
{
  int b = blockIdx.x, p = threadIdx.x;
  if (p >= 96) return;
  float acc = hb[p];
  for (int c = 0; c < 1022; ++c) acc += part[(size_t)c * 768 + b * 96 + p];
  preds[b * 96 + p] = (acc - rb[0]) / (rw[0] + 1e-10f) * stdp[b] + meanp[b];
}

// ---------------------------------------------------------------------------
__global__ __launch_bounds__(512) void k_recon(const float* __restrict__ llo,
    const float* __restrict__ lho, const float* __restrict__ h,
    const float* __restrict__ g, float* __restrict__ outp)
{
  int o = blockIdx.x, b = blockIdx.y, d = threadIdx.x;
  const float* hd = h + d * 4;
  const float* gd = g + d * 4;
  float acc = 0.f;
  if ((o & 1) == 0) {
    int t = o >> 1;
    if (t >= 1) {
      size_t i = ((size_t)b * DWT_ + t - 1) * D_ + d;
      acc += llo[i] * hd[3] + lho[i] * gd[3];
    }
    size_t i = ((size_t)b * DWT_ + t) * D_ + d;
    acc += llo[i] * hd[1] + lho[i] * gd[1];
  } else {
    int t = (o - 1) >> 1;
    size_t i = ((size_t)b * DWT_ + t) * D_ + d;
    acc += llo[i] * hd[2] + lho[i] * gd[2];
    if (t + 1 < DWT_) {
      size_t i2 = ((size_t)b * DWT_ + t + 1) * D_ + d;
      acc += llo[i2] * hd[0] + lho[i2] * gd[0];
    }
  }
  outp[((size_t)b * D_ + d) * RECON_LEN + o] = acc;
}

// ---------------------------------------------------------------------------
extern "C" void kernel_launch(void* const* d_in, const int* in_sizes, int n_in,
                              void* d_out, int out_size, void* d_ws, size_t ws_size,
                              hipStream_t stream)
{
  const float* x       = (const float*)d_in[0];
  const float* revin_w = (const float*)d_in[1];
  const float* revin_b = (const float*)d_in[2];
  const float* patch_W = (const float*)d_in[3];
  const float* patch_b = (const float*)d_in[4];
  const float* pos_emb = (const float*)d_in[5];
  const float* dwt_h   = (const float*)d_in[6];
  const float* dwt_g   = (const float*)d_in[7];
  const float* raw_tau = (const float*)d_in[8];
  const float* attn_W  = (const float*)d_in[9];
  const float* attn_b  = (const float*)d_in[10];
  const float* mlp_W1  = (const float*)d_in[11];
  const float* mlp_b1  = (const float*)d_in[12];
  const float* mlp_W2  = (const float*)d_in[13];
  const float* mlp_b2  = (const float*)d_in[14];
  const float* ln_g    = (const float*)d_in[15];
  const float* ln_b    = (const float*)d_in[16];
  const float* ll_gate = (const float*)d_in[17];
  const float* lh_gate = (const float*)d_in[18];
  const float* head_W  = (const float*)d_in[19];
  const float* head_b  = (const float*)d_in[20];

  float* ws  = (float*)d_ws;
  float* out = (float*)d_out;

  float* meanp = ws + WS_MEAN;
  float* stdp  = ws + WS_STD;
  float* xn    = ws + WS_XN;
  float* pseq  = ws + WS_PSEQ;
  float* llseq = ws + WS_LLSEQ;
  float* lhseq = ws + WS_LHSEQ;
  float* Qb    = ws + WS_Q;
  float* Kb    = ws + WS_K;
  float* Vb    = ws + WS_V;
  float* Ob    = ws + WS_OT;
  float* llout = ws + WS_LLOUT;
  float* lhout = ws + WS_LHOUT;
  float* crossb= ws + WS_CROSS;
  float* gateb = ws + WS_GATE;
  float* llf   = ws + WS_LLF;
  float* lhf   = ws + WS_LHF;
  float* hid   = ws + WS_HID;
  float* llo   = ws + WS_LLO;
  float* lho   = ws + WS_LHO;
  float* part  = ws + WS_PART;

  unsigned short* wt  = (unsigned short*)(ws + WS_PSEQ);  // bf16 arena (after dwt)
  unsigned short* w1t = wt + 12 * 262144;                 // 2 x [2048][512]
  unsigned short* w2t = w1t + 2 * 1048576;                // 2 x [512][2048]

  // ---- stage 0: RevIN + patch embed + patches output + DWT ----
  k_revin<<<8, 256, 0, stream>>>(x, revin_w, revin_b, meanp, stdp, xn);
  k_patch<<<dim3(N_, B_), 512, 0, stream>>>(xn, patch_W, patch_b, pos_emb, pseq);
  k_transpose<<<dim3(16, 32, B_), dim3(32, 8), 0, stream>>>(pseq, out + PATCHES_O);
  k_dwt<<<dim3(DWT_, B_), 512, 0, stream>>>(pseq, dwt_h, dwt_g, llseq, lhseq,
                                            out + OUT_LL_O, out + OUT_LH_O);

  // ---- weight transpose+convert (pseq region is dead now) ----
  k_wt<<<dim3(16, 16, 12), dim3(32, 8), 0, stream>>>(attn_W, wt, 512, 512);
  k_wt<<<dim3(64, 16, 2), dim3(32, 8), 0, stream>>>(mlp_W1, w1t, 512, 2048);
  k_wt<<<dim3(16, 64, 2), dim3(32, 8), 0, stream>>>(mlp_W2, w2t, 2048, 512);

  auto gemm64 = [&](const float* A, const unsigned short* WT, const float* bias,
                    const float* res, float* C, int N, int K, int act) {
    k_gemm_mfma<64><<<dim3(N / 128, 64), 256, 0, stream>>>(A, WT, bias, res, C,
                                                           MR_, N, K, act);
  };

  // ---- stage 1: three MHAs ----
  auto mha = [&](const float* qx, const float* kx, const float* vx, int widx,
                 const float* gate, float* dst) {
    const unsigned short* W = wt + (size_t)widx * 4 * 262144;
    const float* bb = attn_b + (size_t)widx * 4 * D_;
    gemm64(qx, W + 0 * 262144, bb + 0 * D_, nullptr, Qb, D_, D_, 0);
    gemm64(kx, W + 1 * 262144, bb + 1 * D_, nullptr, Kb, D_, D_, 0);
    gemm64(vx, W + 2 * 262144, bb + 2 * D_, nullptr, Vb, D_, D_, 0);
    k_fattn<<<dim3(B_ * 8, 8), 256, 0, stream>>>(Qb, Kb, Vb, Ob, gate);
    gemm64(Ob, W + 3 * 262144, bb + 3 * D_, nullptr, dst, D_, D_, 0);
  };

  mha(llseq, llseq, llseq, 0, nullptr, llout);
  k_gate<<<MR_, 64, 0, stream>>>(lhseq, raw_tau, gateb);
  mha(lhseq, lhseq, lhseq, 1, gateb, lhout);
  mha(llout, lhout, lhout, 2, nullptr, crossb);

  // ---- stage 2: LN + MLP (gelu fused in W1 epilogue, residual in W2) ----
  k_ln<<<MR_, 256, 0, stream>>>(llseq, llout, crossb, ln_g, ln_b, llf);
  k_ln<<<MR_, 256, 0, stream>>>(lhseq, lhout, nullptr, ln_g + D_, ln_b + D_, lhf);

  k_gemm_mfma<128><<<dim3(16, 32), 256, 0, stream>>>(llf, w1t, mlp_b1, nullptr,
                                                     hid, MR_, DFF_, D_, 1);
  gemm64(hid, w2t, mlp_b2, llf, llo, D_, DFF_, 0);

  k_gemm_mfma<128><<<dim3(16, 32), 256, 0, stream>>>(lhf, w1t + 1048576,
                                                     mlp_b1 + DFF_, nullptr,
                                                     hid, MR_, DFF_, D_, 1);
  gemm64(hid, w2t + 1048576, mlp_b2 + D_, lhf, lho, D_, DFF_, 0);

  // ---- stage 3: head + denorm ----
  k_head_partial<<<2 * DWT_, 256, 0, stream>>>(llo, lho, ll_gate, lh_gate, head_W, part);
  k_head_final<<<B_, 128, 0, stream>>>(part, head_b, revin_w, revin_b, meanp, stdp,
                                       out + PREDS_O);

  // ---- stage 4: inverse DWT recon ----
  k_recon<<<dim3(RECON_LEN, B_), 512, 0, stream>>>(llo, lho, dwt_h, dwt_g, out + RECON_O);
}

// Round 4
// 771.617 us; speedup vs baseline: 6.3861x; 1.8518x over previous
//
#include <hip/hip_runtime.h>
#include <math.h>

#define B_    8
#define SEQ_  8192
#define D_    512
#define N_    1023
#define DWT_  511
#define DFF_  2048
#define MR_   (B_ * DWT_)          // 4088 rows for all [B*L, D] GEMMs

// ---------------- d_out layout (flat concat of the 5 outputs) ----------------
#define PREDS_O    0
#define RECON_O    768
#define RECON_LEN  1022
#define PATCHES_O  (RECON_O + 8*512*1022)   // 4186880
#define OUT_LL_O   (PATCHES_O + 8*512*1023) // 8377088
#define OUT_LH_O   (OUT_LL_O + 8*512*511)   // 10470144

// ---------------- workspace layout (floats) ----------------
#define WS_MEAN   ((size_t)0)
#define WS_STD    ((size_t)8)
#define WS_XN     ((size_t)16)
#define WS_PSEQ   ((size_t)65552)
#define WS_LLSEQ  ((size_t)4255760)
#define WS_LHSEQ  ((size_t)6348816)
#define WS_Q      ((size_t)8441872)
#define WS_K      ((size_t)10534928)
#define WS_V      ((size_t)12627984)
#define WS_OT     ((size_t)14721040)
#define WS_LLOUT  ((size_t)16814096)
#define WS_LHOUT  ((size_t)18907152)
#define WS_CROSS  ((size_t)21000208)
#define WS_GATE   ((size_t)23093264)
#define WS_LLF    ((size_t)23097352)
#define WS_LHF    ((size_t)25190408)
// aliases (phase-disjoint):
#define WS_HID    WS_Q        // bf16 hid [4088][2048] = 16.7MB inside Q..OT region
#define WS_LLO    WS_LLOUT
#define WS_LHO    WS_LHOUT
#define WS_PART   WS_CROSS    // 1022*768 = 784896 < 2093056
// bf16 transposed weights live in the pseq region (dead after k_dwt)

using bf16x8 = __attribute__((ext_vector_type(8))) short;
using u16x8  = __attribute__((ext_vector_type(8))) unsigned short;
using f32x4  = __attribute__((ext_vector_type(4))) float;

__device__ inline unsigned short f2bf(float f) {
  unsigned u = __float_as_uint(f);
  u += 0x7fffu + ((u >> 16) & 1u);    // round-to-nearest-even
  return (unsigned short)(u >> 16);
}

// ---------------------------------------------------------------------------
__global__ __launch_bounds__(256) void k_revin(const float* __restrict__ x,
    const float* __restrict__ rw, const float* __restrict__ rb,
    float* __restrict__ meanp, float* __restrict__ stdp, float* __restrict__ xn)
{
  __shared__ float rs[256], rs2[256];
  int b = blockIdx.x, tid = threadIdx.x;
  const float* xb = x + (size_t)b * SEQ_;
  float s = 0.f, s2 = 0.f;
  for (int i = tid; i < SEQ_; i += 256) { float v = xb[i]; s += v; s2 += v * v; }
  rs[tid] = s; rs2[tid] = s2; __syncthreads();
  for (int o = 128; o > 0; o >>= 1) {
    if (tid < o) { rs[tid] += rs[tid + o]; rs2[tid] += rs2[tid + o]; }
    __syncthreads();
  }
  float mu = rs[0] / SEQ_;
  float var = rs2[0] / SEQ_ - mu * mu;
  float sd = sqrtf(var + 1e-5f);
  if (tid == 0) { meanp[b] = mu; stdp[b] = sd; }
  float w = rw[0], bb = rb[0], inv = 1.f / sd;
  for (int i = tid; i < SEQ_; i += 256)
    xn[(size_t)b * SEQ_ + i] = (xb[i] - mu) * inv * w + bb;
}

// ---------------------------------------------------------------------------
__global__ __launch_bounds__(512) void k_patch(const float* __restrict__ xn,
    const float* __restrict__ pW, const float* __restrict__ pb,
    const float* __restrict__ pos, float* __restrict__ p_seq)
{
  __shared__ float sx[16];
  int n = blockIdx.x, b = blockIdx.y, d = threadIdx.x;
  if (threadIdx.x < 16) sx[threadIdx.x] = xn[(size_t)b * SEQ_ + n * 8 + threadIdx.x];
  __syncthreads();
  float acc = pb[d] + pos[(size_t)n * D_ + d];
#pragma unroll
  for (int k = 0; k < 16; ++k) acc += sx[k] * pW[k * D_ + d];
  p_seq[((size_t)b * N_ + n) * D_ + d] = acc;
}

// ---------------------------------------------------------------------------
__global__ __launch_bounds__(256) void k_transpose(const float* __restrict__ p_seq,
                                                   float* __restrict__ outp)
{
  __shared__ float tile[32][33];
  int d0 = blockIdx.x * 32, n0 = blockIdx.y * 32, b = blockIdx.z;
  int tx = threadIdx.x, ty = threadIdx.y;
#pragma unroll
  for (int r = 0; r < 4; ++r) {
    int n = n0 + ty + 8 * r;
    if (n < N_) tile[ty + 8 * r][tx] = p_seq[((size_t)b * N_ + n) * D_ + d0 + tx];
  }
  __syncthreads();
#pragma unroll
  for (int r = 0; r < 4; ++r) {
    int d = d0 + ty + 8 * r, n = n0 + tx;
    if (n < N_) outp[((size_t)b * D_ + d) * N_ + n] = tile[tx][ty + 8 * r];
  }
}

// ---------------------------------------------------------------------------
__global__ __launch_bounds__(512) void k_dwt(const float* __restrict__ p_seq,
    const float* __restrict__ h, const float* __restrict__ g,
    float* __restrict__ ll_seq, float* __restrict__ lh_seq,
    float* __restrict__ ll_out, float* __restrict__ lh_out)
{
  int t = blockIdx.x, b = blockIdx.y, d = threadIdx.x;
  float ah = 0.f, ag = 0.f;
#pragma unroll
  for (int k = 0; k < 4; ++k) {
    int n = 2 * t + k - 1;
    if (n >= 0 && n < N_) {
      float v = p_seq[((size_t)b * N_ + n) * D_ + d];
      ah += v * h[d * 4 + k];
      ag += v * g[d * 4 + k];
    }
  }
  ll_seq[((size_t)b * DWT_ + t) * D_ + d] = ah;
  lh_seq[((size_t)b * DWT_ + t) * D_ + d] = ag;
  ll_out[((size_t)b * D_ + d) * DWT_ + t] = ah;
  lh_out[((size_t)b * D_ + d) * DWT_ + t] = ag;
}

// ---------------------------------------------------------------------------
// weight transpose+convert: src fp32 [K][N] (z-th matrix) -> dst bf16 [N][K]
__global__ __launch_bounds__(256) void k_wt(const float* __restrict__ src,
    unsigned short* __restrict__ dst, int K, int N)
{
  __shared__ float t[32][33];
  int z = blockIdx.z;
  src += (size_t)z * K * N;
  dst += (size_t)z * K * N;
  int n0 = blockIdx.x * 32, k0 = blockIdx.y * 32;
  int tx = threadIdx.x, ty = threadIdx.y;     // (32, 8)
#pragma unroll
  for (int r = 0; r < 4; ++r)
    t[ty + 8 * r][tx] = src[(size_t)(k0 + ty + 8 * r) * N + n0 + tx];
  __syncthreads();
#pragma unroll
  for (int r = 0; r < 4; ++r)
    dst[(size_t)(n0 + ty + 8 * r) * K + k0 + tx] = f2bf(t[tx][ty + 8 * r]);
}

// ---------------------------------------------------------------------------
// C[M,N] = A[M,K] @ WT[N,K](bf16)^T + bias (+res) (opt gelu), via MFMA.
// AF32: A is fp32 (convert during staging) else bf16.
// CMODE: 0 = fp32 C [m][n]; 1 = bf16 C [m][n]; 2 = bf16 C transposed per-b
//        head layout (V): C[(b*512 + n)*512 + key], m = b*511 + key.
template<int BM, int AF32, int CMODE>
__global__ __launch_bounds__(256) void k_gemm_mfma(
    const void* __restrict__ Ap, const unsigned short* __restrict__ WT,
    const float* __restrict__ bias, const float* __restrict__ res,
    void* __restrict__ Cp, int M, int N, int K, int act)
{
  __shared__ unsigned char lds[(BM + 128) * 128];
  unsigned char* sA = lds;
  unsigned char* sB = lds + BM * 128;

  const int tid = threadIdx.x;
  const int wid = tid >> 6, lane = tid & 63;
  const int n0 = blockIdx.x * 128, m0 = blockIdx.y * BM;
  constexpr int MI = 4;
  constexpr int NI = (BM == 128) ? 4 : 2;
  const int wrow = (BM == 128) ? (wid >> 1) * 64 : 0;
  const int wcol = (BM == 128) ? (wid & 1) * 64 : wid * 32;
  const int l16 = lane & 15, lh = lane >> 4;

  f32x4 acc[MI][NI];
#pragma unroll
  for (int i = 0; i < MI; ++i)
#pragma unroll
    for (int j = 0; j < NI; ++j) acc[i][j] = (f32x4){0.f, 0.f, 0.f, 0.f};

  constexpr int AITER = BM / 32;
  for (int k0 = 0; k0 < K; k0 += 64) {
    __syncthreads();
    // ---- stage A ----
#pragma unroll
    for (int it = 0; it < AITER; ++it) {
      int i = it * 256 + tid;
      int row = i >> 3, oct = i & 7;
      int gr = m0 + row; if (gr > M - 1) gr = M - 1;
      if (AF32) {
        const float* src = (const float*)Ap + (size_t)gr * K + k0 + oct * 8;
        float4 v0 = *(const float4*)src;
        float4 v1 = *(const float4*)(src + 4);
        u16x8 pk;
        pk[0] = f2bf(v0.x); pk[1] = f2bf(v0.y); pk[2] = f2bf(v0.z); pk[3] = f2bf(v0.w);
        pk[4] = f2bf(v1.x); pk[5] = f2bf(v1.y); pk[6] = f2bf(v1.z); pk[7] = f2bf(v1.w);
        *(u16x8*)(sA + row * 128 + ((oct ^ (row & 7)) << 4)) = pk;
      } else {
        u16x8 pk = *(const u16x8*)((const unsigned short*)Ap + (size_t)gr * K + k0 + oct * 8);
        *(u16x8*)(sA + row * 128 + ((oct ^ (row & 7)) << 4)) = pk;
      }
    }
    // ---- stage B (bf16, [N][K]) ----
#pragma unroll
    for (int it = 0; it < 4; ++it) {
      int i = it * 256 + tid;
      int row = i >> 3, oct = i & 7;
      uint4 v = *(const uint4*)(WT + (size_t)(n0 + row) * K + k0 + oct * 8);
      *(uint4*)(sB + row * 128 + ((oct ^ (row & 7)) << 4)) = v;
    }
    __syncthreads();
    // ---- MFMA ----
#pragma unroll
    for (int s = 0; s < 2; ++s) {
      bf16x8 af[MI], bfr[NI];
#pragma unroll
      for (int i = 0; i < MI; ++i) {
        int r = wrow + i * 16 + l16;
        af[i] = *(const bf16x8*)(sA + r * 128 + (((s * 4 + lh) ^ (r & 7)) << 4));
      }
#pragma unroll
      for (int j = 0; j < NI; ++j) {
        int r = wcol + j * 16 + l16;
        bfr[j] = *(const bf16x8*)(sB + r * 128 + (((s * 4 + lh) ^ (r & 7)) << 4));
      }
#pragma unroll
      for (int i = 0; i < MI; ++i)
#pragma unroll
        for (int j = 0; j < NI; ++j)
          acc[i][j] = __builtin_amdgcn_mfma_f32_16x16x32_bf16(af[i], bfr[j],
                                                              acc[i][j], 0, 0, 0);
    }
  }
  // ---- epilogue ----
#pragma unroll
  for (int i = 0; i < MI; ++i) {
#pragma unroll
    for (int r = 0; r < 4; ++r) {
      int m = m0 + wrow + i * 16 + lh * 4 + r;
      if (m >= M) continue;
#pragma unroll
      for (int j = 0; j < NI; ++j) {
        int n = n0 + wcol + j * 16 + l16;
        float v = acc[i][j][r] + bias[n];
        if (act) v = 0.5f * v * (1.f + erff(v * 0.70710678118654752f));
        if (CMODE == 0) {
          if (res) v += res[(size_t)m * N + n];
          ((float*)Cp)[(size_t)m * N + n] = v;
        } else if (CMODE == 1) {
          ((unsigned short*)Cp)[(size_t)m * N + n] = f2bf(v);
        } else {
          int bb = m / DWT_;
          int key = m - bb * DWT_;
          ((unsigned short*)Cp)[((size_t)(bb * 512 + n)) * 512 + key] = f2bf(v);
        }
      }
    }
  }
}

// ---------------------------------------------------------------------------
__global__ __launch_bounds__(64) void k_gate(const float* __restrict__ lh_seq,
    const float* __restrict__ raw_tau, float* __restrict__ gate)
{
  int row = blockIdx.x, lane = threadIdx.x;
  float s = 0.f;
#pragma unroll
  for (int j = 0; j < 8; ++j) s += fabsf(lh_seq[(size_t)row * D_ + lane + 64 * j]);
#pragma unroll
  for (int off = 32; off; off >>= 1) s += __shfl_xor(s, off);
  if (lane == 0) {
    float tau = 1.f / (1.f + expf(-raw_tau[0]));
    float e = s / (float)D_;
    gate[row] = 1.f / (1.f + expf(-(e - tau) * 10.f));
  }
}

// ---------------------------------------------------------------------------
// MFMA flash attention. Block = (bh, qtile of 64), 4 waves.
// S^T = mfma(A=K, B=Q): lane owns q = q0 + w*16 + (lane&15); keys in regs+xor16/32.
// P -> wave-private LDS (bf16, swizzled) -> A-frag of PV. V from transposed
// global Vt[(b*8+h)*64+d][key] staged as [d][key] tile (B-frag of PV).
__global__ __launch_bounds__(256) void k_mattn(
    const unsigned short* __restrict__ Qb, const unsigned short* __restrict__ Kb,
    const unsigned short* __restrict__ Vt, const float* __restrict__ gate,
    unsigned short* __restrict__ Ob)
{
  __shared__ unsigned char sQ[8192], sK[8192], sV[8192], sP[8192];
  __shared__ float sG[64];

  const int bh = blockIdx.x;
  const int b = bh >> 3, h = bh & 7;
  const int q0 = blockIdx.y * 64;
  const int tid = threadIdx.x;
  const int w = tid >> 6, lane = tid & 63;
  const int l16 = lane & 15, lh = lane >> 4;
  const bool hg = (gate != nullptr);

  // stage Q tile [64 q][64 d]
#pragma unroll
  for (int it = 0; it < 2; ++it) {
    int i = it * 256 + tid;
    int row = i >> 3, oct = i & 7;
    int qr = q0 + row; if (qr > DWT_ - 1) qr = DWT_ - 1;
    u16x8 v = *(const u16x8*)(Qb + (size_t)(b * DWT_ + qr) * 512 + h * 64 + oct * 8);
    *(u16x8*)(sQ + row * 128 + ((oct ^ (row & 7)) << 4)) = v;
  }

  float m_ = -1e30f, l_ = 0.f;
  f32x4 accO[4];
#pragma unroll
  for (int jb = 0; jb < 4; ++jb) accO[jb] = (f32x4){0.f, 0.f, 0.f, 0.f};

  const unsigned short* vrow = Vt + (size_t)bh * 64 * 512;
  unsigned char* sPw = sP + w * 2048;   // wave-private [16 q][64 key] bf16

  for (int kt = 0; kt < 8; ++kt) {
    const int k0 = kt * 64;
    __syncthreads();
#pragma unroll
    for (int it = 0; it < 2; ++it) {
      int i = it * 256 + tid;
      int row = i >> 3, oct = i & 7;
      int kr = k0 + row; if (kr > DWT_ - 1) kr = DWT_ - 1;
      u16x8 v = *(const u16x8*)(Kb + (size_t)(b * DWT_ + kr) * 512 + h * 64 + oct * 8);
      *(u16x8*)(sK + row * 128 + ((oct ^ (row & 7)) << 4)) = v;
    }
#pragma unroll
    for (int it = 0; it < 2; ++it) {
      int i = it * 256 + tid;
      int row = i >> 3, oct = i & 7;      // row = d
      u16x8 v = *(const u16x8*)(vrow + (size_t)row * 512 + k0 + oct * 8);
      *(u16x8*)(sV + row * 128 + ((oct ^ (row & 7)) << 4)) = v;
    }
    if (hg && tid < 64) {
      int kk = k0 + tid;
      sG[tid] = (kk < DWT_) ? gate[(size_t)b * DWT_ + kk] : 0.f;
    }
    __syncthreads();

    // ---- S^T strip: rows = 64 keys (4 blocks), cols = wave's 16 q ----
    f32x4 sacc[4];
#pragma unroll
    for (int i = 0; i < 4; ++i) sacc[i] = (f32x4){0.f, 0.f, 0.f, 0.f};
#pragma unroll
    for (int s = 0; s < 2; ++s) {
      int qr = w * 16 + l16;
      bf16x8 qf = *(const bf16x8*)(sQ + qr * 128 + ((((s << 2) + lh) ^ (qr & 7)) << 4));
#pragma unroll
      for (int i = 0; i < 4; ++i) {
        int krr = i * 16 + l16;
        bf16x8 kf = *(const bf16x8*)(sK + krr * 128 + ((((s << 2) + lh) ^ (krr & 7)) << 4));
        sacc[i] = __builtin_amdgcn_mfma_f32_16x16x32_bf16(kf, qf, sacc[i], 0, 0, 0);
      }
    }

    // ---- softmax (lane owns one q; keys: 16 in-reg + xor16/32) ----
    float sv[4][4];
    float tm = -1e30f;
#pragma unroll
    for (int i = 0; i < 4; ++i)
#pragma unroll
      for (int r = 0; r < 4; ++r) {
        float v = sacc[i][r] * 0.125f;
        if (k0 + i * 16 + lh * 4 + r >= DWT_) v = -1e30f;
        sv[i][r] = v;
        tm = fmaxf(tm, v);
      }
    tm = fmaxf(tm, __shfl_xor(tm, 16));
    tm = fmaxf(tm, __shfl_xor(tm, 32));
    float mn = fmaxf(m_, tm);
    float corr = __expf(m_ - mn);
    m_ = mn;
    float ts = 0.f;
    float p[4][4];
#pragma unroll
    for (int i = 0; i < 4; ++i)
#pragma unroll
      for (int r = 0; r < 4; ++r) {
        float e = __expf(sv[i][r] - mn);
        p[i][r] = e; ts += e;
      }
    ts += __shfl_xor(ts, 16);
    ts += __shfl_xor(ts, 32);
    l_ = l_ * corr + ts;

    // rescale accO (rows q-local = lh*4 + r; corr held by lane q-local)
#pragma unroll
    for (int r = 0; r < 4; ++r) {
      float cr = __shfl(corr, (lh << 2) + r);
#pragma unroll
      for (int jb = 0; jb < 4; ++jb) accO[jb][r] *= cr;
    }

    // gate + write P bf16 to wave-private LDS [q=l16][key]
#pragma unroll
    for (int i = 0; i < 4; ++i)
#pragma unroll
      for (int r = 0; r < 4; ++r) {
        float pv = p[i][r];
        int key = i * 16 + (lh << 2) + r;
        if (hg) pv *= sG[key];
        int slot = (key >> 3) ^ (l16 & 7);
        *(unsigned short*)(sPw + l16 * 128 + (slot << 4) + (key & 7) * 2) = f2bf(pv);
      }

    // ---- PV: A = P [16q][64key], B = V [key][d] from sV[d][key] ----
#pragma unroll
    for (int s = 0; s < 2; ++s) {
      bf16x8 pf = *(const bf16x8*)(sPw + l16 * 128 + ((((s << 2) + lh) ^ (l16 & 7)) << 4));
#pragma unroll
      for (int jb = 0; jb < 4; ++jb) {
        int vr = jb * 16 + l16;
        bf16x8 vf = *(const bf16x8*)(sV + vr * 128 + ((((s << 2) + lh) ^ (vr & 7)) << 4));
        accO[jb] = __builtin_amdgcn_mfma_f32_16x16x32_bf16(pf, vf, accO[jb], 0, 0, 0);
      }
    }
  }

  // ---- epilogue: O = accO / l, write bf16 ----
  float linv = 1.f / l_;
#pragma unroll
  for (int r = 0; r < 4; ++r) {
    float li = __shfl(linv, (lh << 2) + r);
    int q = q0 + w * 16 + (lh << 2) + r;
    if (q >= DWT_) continue;
#pragma unroll
    for (int jb = 0; jb < 4; ++jb) {
      Ob[(size_t)(b * DWT_ + q) * 512 + h * 64 + jb * 16 + l16] = f2bf(accO[jb][r] * li);
    }
  }
}

// ---------------------------------------------------------------------------
__global__ __launch_bounds__(256) void k_ln(const float* __restrict__ a,
    const float* __restrict__ b2, const float* __restrict__ c,
    const float* __restrict__ g, const float* __restrict__ beta,
    float* __restrict__ outp)
{
  __shared__ float red[256], red2[256];
  int row = blockIdx.x, tid = threadIdx.x;
  size_t base = (size_t)row * D_;
  float v0 = a[base + tid], v1 = a[base + tid + 256];
  if (b2) { v0 += b2[base + tid]; v1 += b2[base + tid + 256]; }
  if (c)  { v0 += c[base + tid];  v1 += c[base + tid + 256]; }
  red[tid] = v0 + v1; red2[tid] = v0 * v0 + v1 * v1;
  __syncthreads();
  for (int o = 128; o > 0; o >>= 1) {
    if (tid < o) { red[tid] += red[tid + o]; red2[tid] += red2[tid + o]; }
    __syncthreads();
  }
  float mu = red[0] / (float)D_;
  float var = red2[0] / (float)D_ - mu * mu;
  float rstd = rsqrtf(var + 1e-5f);
  outp[base + tid]       = (v0 - mu) * rstd * g[tid] + beta[tid];
  outp[base + tid + 256] = (v1 - mu) * rstd * g[tid + 256] + beta[tid + 256];
}

// ---------------------------------------------------------------------------
__global__ __launch_bounds__(256) void k_head_partial(
    const float* __restrict__ llo, const float* __restrict__ lho,
    const float* __restrict__ llg, const float* __restrict__ lhg,
    const float* __restrict__ hw, float* __restrict__ part)
{
  __shared__ float lds[8][512];
  int x = blockIdx.x;
  int branch = x / DWT_, t = x % DWT_;
  const float* seq = branch ? lho : llo;
  const float* gt  = branch ? lhg : llg;
  int tid = threadIdx.x;
  for (int i = tid; i < 8 * 512; i += 256) {
    int b = i >> 9, d = i & 511;
    lds[b][d] = seq[((size_t)b * DWT_ + t) * D_ + d] * gt[(size_t)t * D_ + d];
  }
  __syncthreads();
  size_t kbase = (size_t)x * D_;
  float acc[3] = {0.f, 0.f, 0.f};
  int pb[3], pr[3];
#pragma unroll
  for (int pi = 0; pi < 3; ++pi) {
    int pidx = tid + 256 * pi; pb[pi] = pidx / 96; pr[pi] = pidx % 96;
  }
  for (int k = 0; k < 512; ++k) {
    const float* wrow = hw + (kbase + k) * 96;
#pragma unroll
    for (int pi = 0; pi < 3; ++pi) acc[pi] += lds[pb[pi]][k] * wrow[pr[pi]];
  }
#pragma unroll
  for (int pi = 0; pi < 3; ++pi) part[(size_t)x * 768 + tid + 256 * pi] = acc[pi];
}

__global__ __launch_bounds__(128) void k_head_final(const float* __restrict__ part,
    const float* __restrict__ hb, const float* __restrict__ rw,
    const float* __restrict__ rb, const float* __restrict__ meanp,
    const float* __restrict__ stdp, float* __restrict__ preds)
{
  int b = blockIdx.x, p = threadIdx.x;
  if (p >= 96) return;
  float acc = hb[p];
  for (int c = 0; c < 1022; ++c) acc += part[(size_t)c * 768 + b * 96 + p];
  preds[b * 96 + p] = (acc - rb[0]) / (rw[0] + 1e-10f) * stdp[b] + meanp[b];
}

// ---------------------------------------------------------------------------
__global__ __launch_bounds__(512) void k_recon(const float* __restrict__ llo,
    const float* __restrict__ lho, const float* __restrict__ h,
    const float* __restrict__ g, float* __restrict__ outp)
{
  int o = blockIdx.x, b = blockIdx.y, d = threadIdx.x;
  const float* hd = h + d * 4;
  const float* gd = g + d * 4;
  float acc = 0.f;
  if ((o & 1) == 0) {
    int t = o >> 1;
    if (t >= 1) {
      size_t i = ((size_t)b * DWT_ + t - 1) * D_ + d;
      acc += llo[i] * hd[3] + lho[i] * gd[3];
    }
    size_t i = ((size_t)b * DWT_ + t) * D_ + d;
    acc += llo[i] * hd[1] + lho[i] * gd[1];
  } else {
    int t = (o - 1) >> 1;
    size_t i = ((size_t)b * DWT_ + t) * D_ + d;
    acc += llo[i] * hd[2] + lho[i] * gd[2];
    if (t + 1 < DWT_) {
      size_t i2 = ((size_t)b * DWT_ + t + 1) * D_ + d;
      acc += llo[i2] * hd[0] + lho[i2] * gd[0];
    }
  }
  outp[((size_t)b * D_ + d) * RECON_LEN + o] = acc;
}

// ---------------------------------------------------------------------------
extern "C" void kernel_launch(void* const* d_in, const int* in_sizes, int n_in,
                              void* d_out, int out_size, void* d_ws, size_t ws_size,
                              hipStream_t stream)
{
  const float* x       = (const float*)d_in[0];
  const float* revin_w = (const float*)d_in[1];
  const float* revin_b = (const float*)d_in[2];
  const float* patch_W = (const float*)d_in[3];
  const float* patch_b = (const float*)d_in[4];
  const float* pos_emb = (const float*)d_in[5];
  const float* dwt_h   = (const float*)d_in[6];
  const float* dwt_g   = (const float*)d_in[7];
  const float* raw_tau = (const float*)d_in[8];
  const float* attn_W  = (const float*)d_in[9];
  const float* attn_b  = (const float*)d_in[10];
  const float* mlp_W1  = (const float*)d_in[11];
  const float* mlp_b1  = (const float*)d_in[12];
  const float* mlp_W2  = (const float*)d_in[13];
  const float* mlp_b2  = (const float*)d_in[14];
  const float* ln_g    = (const float*)d_in[15];
  const float* ln_b    = (const float*)d_in[16];
  const float* ll_gate = (const float*)d_in[17];
  const float* lh_gate = (const float*)d_in[18];
  const float* head_W  = (const float*)d_in[19];
  const float* head_b  = (const float*)d_in[20];

  float* ws  = (float*)d_ws;
  float* out = (float*)d_out;

  float* meanp = ws + WS_MEAN;
  float* stdp  = ws + WS_STD;
  float* xn    = ws + WS_XN;
  float* pseq  = ws + WS_PSEQ;
  float* llseq = ws + WS_LLSEQ;
  float* lhseq = ws + WS_LHSEQ;
  float* llout = ws + WS_LLOUT;
  float* lhout = ws + WS_LHOUT;
  float* crossb= ws + WS_CROSS;
  float* gateb = ws + WS_GATE;
  float* llf   = ws + WS_LLF;
  float* lhf   = ws + WS_LHF;
  float* llo   = ws + WS_LLO;
  float* lho   = ws + WS_LHO;
  float* part  = ws + WS_PART;

  unsigned short* Qb16  = (unsigned short*)(ws + WS_Q);
  unsigned short* Kb16  = (unsigned short*)(ws + WS_K);
  unsigned short* Vt16  = (unsigned short*)(ws + WS_V);   // [4096][512] per-head T
  unsigned short* Ob16  = (unsigned short*)(ws + WS_OT);
  unsigned short* hid16 = (unsigned short*)(ws + WS_HID); // [4088][2048]

  unsigned short* wt  = (unsigned short*)(ws + WS_PSEQ);  // bf16 weights (after dwt)
  unsigned short* w1t = wt + 12 * 262144;                 // 2 x [2048][512]
  unsigned short* w2t = w1t + 2 * 1048576;                // 2 x [512][2048]

  // ---- stage 0: RevIN + patch embed + patches output + DWT ----
  k_revin<<<8, 256, 0, stream>>>(x, revin_w, revin_b, meanp, stdp, xn);
  k_patch<<<dim3(N_, B_), 512, 0, stream>>>(xn, patch_W, patch_b, pos_emb, pseq);
  k_transpose<<<dim3(16, 32, B_), dim3(32, 8), 0, stream>>>(pseq, out + PATCHES_O);
  k_dwt<<<dim3(DWT_, B_), 512, 0, stream>>>(pseq, dwt_h, dwt_g, llseq, lhseq,
                                            out + OUT_LL_O, out + OUT_LH_O);

  // ---- weight transpose+convert (pseq region is dead now) ----
  k_wt<<<dim3(16, 16, 12), dim3(32, 8), 0, stream>>>(attn_W, wt, 512, 512);
  k_wt<<<dim3(64, 16, 2), dim3(32, 8), 0, stream>>>(mlp_W1, w1t, 512, 2048);
  k_wt<<<dim3(16, 64, 2), dim3(32, 8), 0, stream>>>(mlp_W2, w2t, 2048, 512);

  // ---- stage 1: three MHAs ----
  auto mha = [&](const float* qx, const float* kx, const float* vx, int widx,
                 const float* gate, float* dst) {
    const unsigned short* W = wt + (size_t)widx * 4 * 262144;
    const float* bb = attn_b + (size_t)widx * 4 * D_;
    k_gemm_mfma<64,1,1><<<dim3(4, 64), 256, 0, stream>>>(qx, W + 0 * 262144,
        bb + 0 * D_, nullptr, Qb16, MR_, D_, D_, 0);
    k_gemm_mfma<64,1,1><<<dim3(4, 64), 256, 0, stream>>>(kx, W + 1 * 262144,
        bb + 1 * D_, nullptr, Kb16, MR_, D_, D_, 0);
    k_gemm_mfma<64,1,2><<<dim3(4, 64), 256, 0, stream>>>(vx, W + 2 * 262144,
        bb + 2 * D_, nullptr, Vt16, MR_, D_, D_, 0);
    k_mattn<<<dim3(64, 8), 256, 0, stream>>>(Qb16, Kb16, Vt16, gate, Ob16);
    k_gemm_mfma<64,0,0><<<dim3(4, 64), 256, 0, stream>>>(Ob16, W + 3 * 262144,
        bb + 3 * D_, nullptr, dst, MR_, D_, D_, 0);
  };

  mha(llseq, llseq, llseq, 0, nullptr, llout);
  k_gate<<<MR_, 64, 0, stream>>>(lhseq, raw_tau, gateb);
  mha(lhseq, lhseq, lhseq, 1, gateb, lhout);
  mha(llout, lhout, lhout, 2, nullptr, crossb);

  // ---- stage 2: LN + MLP (gelu fused in W1 epilogue, residual in W2) ----
  k_ln<<<MR_, 256, 0, stream>>>(llseq, llout, crossb, ln_g, ln_b, llf);
  k_ln<<<MR_, 256, 0, stream>>>(lhseq, lhout, nullptr, ln_g + D_, ln_b + D_, lhf);

  k_gemm_mfma<128,1,1><<<dim3(16, 32), 256, 0, stream>>>(llf, w1t, mlp_b1,
      nullptr, hid16, MR_, DFF_, D_, 1);
  k_gemm_mfma<64,0,0><<<dim3(4, 64), 256, 0, stream>>>(hid16, w2t, mlp_b2,
      llf, llo, MR_, D_, DFF_, 0);

  k_gemm_mfma<128,1,1><<<dim3(16, 32), 256, 0, stream>>>(lhf, w1t + 1048576,
      mlp_b1 + DFF_, nullptr, hid16, MR_, DFF_, D_, 1);
  k_gemm_mfma<64,0,0><<<dim3(4, 64), 256, 0, stream>>>(hid16, w2t + 1048576,
      mlp_b2 + D_, lhf, lho, MR_, D_, DFF_, 0);

  // ---- stage 3: head + denorm ----
  k_head_partial<<<2 * DWT_, 256, 0, stream>>>(llo, lho, ll_gate, lh_gate, head_W, part);
  k_head_final<<<B_, 128, 0, stream>>>(part, head_b, revin_w, revin_b, meanp, stdp,
                                       out + PREDS_O);

  // ---- stage 4: inverse DWT recon ----
  k_recon<<<dim3(RECON_LEN, B_), 512, 0, stream>>>(llo, lho, dwt_h, dwt_g, out + RECON_O);
}

// Round 5
// 603.911 us; speedup vs baseline: 8.1595x; 1.2777x over previous
//
#include <hip/hip_runtime.h>
#include <math.h>

#define B_    8
#define SEQ_  8192
#define D_    512
#define N_    1023
#define DWT_  511
#define DFF_  2048
#define MR_   (B_ * DWT_)          // 4088 rows for all [B*L, D] GEMMs

// ---------------- d_out layout (flat concat of the 5 outputs) ----------------
#define PREDS_O    0
#define RECON_O    768
#define RECON_LEN  1022
#define PATCHES_O  (RECON_O + 8*512*1022)   // 4186880
#define OUT_LL_O   (PATCHES_O + 8*512*1023) // 8377088
#define OUT_LH_O   (OUT_LL_O + 8*512*511)   // 10470144

// ---------------- workspace layout (floats) ----------------
#define WS_MEAN   ((size_t)0)
#define WS_STD    ((size_t)8)
#define WS_XN     ((size_t)16)
#define WS_PSEQ   ((size_t)65552)
#define WS_LLSEQ  ((size_t)4255760)
#define WS_LHSEQ  ((size_t)6348816)
#define WS_LLOUT  ((size_t)16814096)
#define WS_LHOUT  ((size_t)18907152)
#define WS_CROSS  ((size_t)21000208)
#define WS_GATE   ((size_t)23093264)
#define WS_LLF    ((size_t)23097352)
#define WS_LHF    ((size_t)25190408)
#define WS_LLO    WS_LLOUT
#define WS_LHO    WS_LHOUT
#define WS_PART   WS_CROSS    // head partials alias cross (phase-disjoint)
// new double-z bf16 buffers beyond the old arena (ws_size ~766MiB per poison fill)
#define WS_QB     ((size_t)27283464)            // 2 x [4088][512] bf16
#define WS_KB     (WS_QB + 2093056)
#define WS_VT     (WS_KB + 2093056)             // 2 x [4096][512] bf16
#define WS_OB     (WS_VT + 2097152)
#define WS_HID2   (WS_OB + 2093056)             // 2 x [4088][2048] bf16

using bf16x8 = __attribute__((ext_vector_type(8))) short;
using u16x8  = __attribute__((ext_vector_type(8))) unsigned short;
using f32x4  = __attribute__((ext_vector_type(4))) float;

__device__ inline unsigned short f2bf(float f) {
  unsigned u = __float_as_uint(f);
  u += 0x7fffu + ((u >> 16) & 1u);    // round-to-nearest-even
  return (unsigned short)(u >> 16);
}

// ---------------------------------------------------------------------------
__global__ __launch_bounds__(256) void k_revin(const float* __restrict__ x,
    const float* __restrict__ rw, const float* __restrict__ rb,
    float* __restrict__ meanp, float* __restrict__ stdp, float* __restrict__ xn)
{
  __shared__ float rs[256], rs2[256];
  int b = blockIdx.x, tid = threadIdx.x;
  const float* xb = x + (size_t)b * SEQ_;
  float s = 0.f, s2 = 0.f;
  for (int i = tid; i < SEQ_; i += 256) { float v = xb[i]; s += v; s2 += v * v; }
  rs[tid] = s; rs2[tid] = s2; __syncthreads();
  for (int o = 128; o > 0; o >>= 1) {
    if (tid < o) { rs[tid] += rs[tid + o]; rs2[tid] += rs2[tid + o]; }
    __syncthreads();
  }
  float mu = rs[0] / SEQ_;
  float var = rs2[0] / SEQ_ - mu * mu;
  float sd = sqrtf(var + 1e-5f);
  if (tid == 0) { meanp[b] = mu; stdp[b] = sd; }
  float w = rw[0], bb = rb[0], inv = 1.f / sd;
  for (int i = tid; i < SEQ_; i += 256)
    xn[(size_t)b * SEQ_ + i] = (xb[i] - mu) * inv * w + bb;
}

// ---------------------------------------------------------------------------
__global__ __launch_bounds__(512) void k_patch(const float* __restrict__ xn,
    const float* __restrict__ pW, const float* __restrict__ pb,
    const float* __restrict__ pos, float* __restrict__ p_seq)
{
  __shared__ float sx[16];
  int n = blockIdx.x, b = blockIdx.y, d = threadIdx.x;
  if (threadIdx.x < 16) sx[threadIdx.x] = xn[(size_t)b * SEQ_ + n * 8 + threadIdx.x];
  __syncthreads();
  float acc = pb[d] + pos[(size_t)n * D_ + d];
#pragma unroll
  for (int k = 0; k < 16; ++k) acc += sx[k] * pW[k * D_ + d];
  p_seq[((size_t)b * N_ + n) * D_ + d] = acc;
}

// ---------------------------------------------------------------------------
__global__ __launch_bounds__(256) void k_transpose(const float* __restrict__ p_seq,
                                                   float* __restrict__ outp)
{
  __shared__ float tile[32][33];
  int d0 = blockIdx.x * 32, n0 = blockIdx.y * 32, b = blockIdx.z;
  int tx = threadIdx.x, ty = threadIdx.y;
#pragma unroll
  for (int r = 0; r < 4; ++r) {
    int n = n0 + ty + 8 * r;
    if (n < N_) tile[ty + 8 * r][tx] = p_seq[((size_t)b * N_ + n) * D_ + d0 + tx];
  }
  __syncthreads();
#pragma unroll
  for (int r = 0; r < 4; ++r) {
    int d = d0 + ty + 8 * r, n = n0 + tx;
    if (n < N_) outp[((size_t)b * D_ + d) * N_ + n] = tile[tx][ty + 8 * r];
  }
}

// ---------------------------------------------------------------------------
__global__ __launch_bounds__(512) void k_dwt(const float* __restrict__ p_seq,
    const float* __restrict__ h, const float* __restrict__ g,
    float* __restrict__ ll_seq, float* __restrict__ lh_seq,
    float* __restrict__ ll_out, float* __restrict__ lh_out)
{
  int t = blockIdx.x, b = blockIdx.y, d = threadIdx.x;
  float ah = 0.f, ag = 0.f;
#pragma unroll
  for (int k = 0; k < 4; ++k) {
    int n = 2 * t + k - 1;
    if (n >= 0 && n < N_) {
      float v = p_seq[((size_t)b * N_ + n) * D_ + d];
      ah += v * h[d * 4 + k];
      ag += v * g[d * 4 + k];
    }
  }
  ll_seq[((size_t)b * DWT_ + t) * D_ + d] = ah;
  lh_seq[((size_t)b * DWT_ + t) * D_ + d] = ag;
  ll_out[((size_t)b * D_ + d) * DWT_ + t] = ah;
  lh_out[((size_t)b * D_ + d) * DWT_ + t] = ag;
}

// ---------------------------------------------------------------------------
// weight transpose+convert: src fp32 [K][N] (z-th matrix) -> dst bf16 [N][K]
__global__ __launch_bounds__(256) void k_wt(const float* __restrict__ src,
    unsigned short* __restrict__ dst, int K, int N)
{
  __shared__ float t[32][33];
  int z = blockIdx.z;
  src += (size_t)z * K * N;
  dst += (size_t)z * K * N;
  int n0 = blockIdx.x * 32, k0 = blockIdx.y * 32;
  int tx = threadIdx.x, ty = threadIdx.y;     // (32, 8)
#pragma unroll
  for (int r = 0; r < 4; ++r)
    t[ty + 8 * r][tx] = src[(size_t)(k0 + ty + 8 * r) * N + n0 + tx];
  __syncthreads();
#pragma unroll
  for (int r = 0; r < 4; ++r)
    dst[(size_t)(n0 + ty + 8 * r) * K + k0 + tx] = f2bf(t[tx][ty + 8 * r]);
}

// ---------------------------------------------------------------------------
// C = A @ WT^T + bias (+res) (opt gelu) via MFMA, z-batched.
// AF32: A fp32 (convert during staging) else bf16.
// CMODE 0: fp32 C[m][n] (+res). CMODE 1: bf16 C[m][n].
// CMODE 3: fused QKV: n<512 -> Q bf16 [m][n]; <1024 -> K bf16; >=1024 -> V
//          transposed bf16 [(b*512+n-1024)][key]. A chosen per n-segment.
// z strides: WT += z*zsW, bias += z*zsB; fixed out strides for CMODE 1/3.
template<int BM, int AF32, int CMODE>
__global__ __launch_bounds__(256, BM == 64 ? 4 : 2) void k_gemm_mfma(
    const void* __restrict__ A00, const void* __restrict__ A01,
    const void* __restrict__ A10, const void* __restrict__ A11,
    const unsigned short* __restrict__ WT, const float* __restrict__ bias,
    const float* __restrict__ res0, const float* __restrict__ res1,
    void* __restrict__ C0, void* __restrict__ C1, void* __restrict__ C2,
    int M, int N, int K, int act, int zsW, int zsB)
{
  __shared__ unsigned char lds[(BM + 128) * 128];
  unsigned char* sA = lds;
  unsigned char* sB = lds + BM * 128;

  const int tid = threadIdx.x;
  const int wid = tid >> 6, lane = tid & 63;
  const int n0 = blockIdx.x * 128, m0 = blockIdx.y * BM;
  const int z = blockIdx.z;
  constexpr int MI = 4;
  constexpr int NI = (BM == 128) ? 4 : 2;
  const int wrow = (BM == 128) ? (wid >> 1) * 64 : 0;
  const int wcol = (BM == 128) ? (wid & 1) * 64 : wid * 32;
  const int l16 = lane & 15, lh = lane >> 4;

  const unsigned short* wt_ = WT + (size_t)z * zsW;
  const float* bias_ = bias + (size_t)z * zsB;
  const void* Ap;
  if (CMODE == 3) Ap = z ? (n0 < 512 ? A10 : A11) : (n0 < 512 ? A00 : A01);
  else            Ap = z ? A10 : A00;

  f32x4 acc[MI][NI];
#pragma unroll
  for (int i = 0; i < MI; ++i)
#pragma unroll
    for (int j = 0; j < NI; ++j) acc[i][j] = (f32x4){0.f, 0.f, 0.f, 0.f};

  constexpr int AITER = BM / 32;
  for (int k0 = 0; k0 < K; k0 += 64) {
    __syncthreads();
    // ---- stage A ----
#pragma unroll
    for (int it = 0; it < AITER; ++it) {
      int i = it * 256 + tid;
      int row = i >> 3, oct = i & 7;
      int gr = m0 + row; if (gr > M - 1) gr = M - 1;
      if (AF32) {
        const float* src = (const float*)Ap + (size_t)gr * K + k0 + oct * 8;
        float4 v0 = *(const float4*)src;
        float4 v1 = *(const float4*)(src + 4);
        u16x8 pk;
        pk[0] = f2bf(v0.x); pk[1] = f2bf(v0.y); pk[2] = f2bf(v0.z); pk[3] = f2bf(v0.w);
        pk[4] = f2bf(v1.x); pk[5] = f2bf(v1.y); pk[6] = f2bf(v1.z); pk[7] = f2bf(v1.w);
        *(u16x8*)(sA + row * 128 + ((oct ^ (row & 7)) << 4)) = pk;
      } else {
        u16x8 pk = *(const u16x8*)((const unsigned short*)Ap + (size_t)gr * K + k0 + oct * 8);
        *(u16x8*)(sA + row * 128 + ((oct ^ (row & 7)) << 4)) = pk;
      }
    }
    // ---- stage B (bf16, [N][K]) ----
#pragma unroll
    for (int it = 0; it < 4; ++it) {
      int i = it * 256 + tid;
      int row = i >> 3, oct = i & 7;
      uint4 v = *(const uint4*)(wt_ + (size_t)(n0 + row) * K + k0 + oct * 8);
      *(uint4*)(sB + row * 128 + ((oct ^ (row & 7)) << 4)) = v;
    }
    __syncthreads();
    // ---- MFMA ----
#pragma unroll
    for (int s = 0; s < 2; ++s) {
      bf16x8 af[MI], bfr[NI];
#pragma unroll
      for (int i = 0; i < MI; ++i) {
        int r = wrow + i * 16 + l16;
        af[i] = *(const bf16x8*)(sA + r * 128 + (((s * 4 + lh) ^ (r & 7)) << 4));
      }
#pragma unroll
      for (int j = 0; j < NI; ++j) {
        int r = wcol + j * 16 + l16;
        bfr[j] = *(const bf16x8*)(sB + r * 128 + (((s * 4 + lh) ^ (r & 7)) << 4));
      }
#pragma unroll
      for (int i = 0; i < MI; ++i)
#pragma unroll
        for (int j = 0; j < NI; ++j)
          acc[i][j] = __builtin_amdgcn_mfma_f32_16x16x32_bf16(af[i], bfr[j],
                                                              acc[i][j], 0, 0, 0);
    }
  }
  // ---- epilogue ----
  const float* res_ = z ? res1 : res0;
#pragma unroll
  for (int i = 0; i < MI; ++i) {
#pragma unroll
    for (int r = 0; r < 4; ++r) {
      int m = m0 + wrow + i * 16 + lh * 4 + r;
      if (m >= M) continue;
#pragma unroll
      for (int j = 0; j < NI; ++j) {
        int n = n0 + wcol + j * 16 + l16;
        float v = acc[i][j][r] + bias_[n];
        if (act) v = 0.5f * v * (1.f + erff(v * 0.70710678118654752f));
        if (CMODE == 0) {
          float* Cp = (float*)(z ? C1 : C0);
          if (res_) v += res_[(size_t)m * N + n];
          Cp[(size_t)m * N + n] = v;
        } else if (CMODE == 1) {
          unsigned short* Cp = (unsigned short*)(z ? C1 : C0);
          Cp[(size_t)m * N + n] = f2bf(v);
        } else {
          if (n < 512) {
            ((unsigned short*)C0)[(size_t)z * 2093056 + (size_t)m * 512 + n] = f2bf(v);
          } else if (n < 1024) {
            ((unsigned short*)C1)[(size_t)z * 2093056 + (size_t)m * 512 + (n - 512)] = f2bf(v);
          } else {
            int bb = m / DWT_;
            int key = m - bb * DWT_;
            ((unsigned short*)C2)[(size_t)z * 2097152 +
                ((size_t)(bb * 512 + (n - 1024))) * 512 + key] = f2bf(v);
          }
        }
      }
    }
  }
}

// ---------------------------------------------------------------------------
__global__ __launch_bounds__(64) void k_gate(const float* __restrict__ lh_seq,
    const float* __restrict__ raw_tau, float* __restrict__ gate)
{
  int row = blockIdx.x, lane = threadIdx.x;
  float s = 0.f;
#pragma unroll
  for (int j = 0; j < 8; ++j) s += fabsf(lh_seq[(size_t)row * D_ + lane + 64 * j]);
#pragma unroll
  for (int off = 32; off; off >>= 1) s += __shfl_xor(s, off);
  if (lane == 0) {
    float tau = 1.f / (1.f + expf(-raw_tau[0]));
    float e = s / (float)D_;
    gate[row] = 1.f / (1.f + expf(-(e - tau) * 10.f));
  }
}

// ---------------------------------------------------------------------------
// MFMA flash attention, z-batched. Block = (bh, qtile of 64, z), 4 waves.
// gate applies only to z==1 (LH branch of the batched call).
__global__ __launch_bounds__(256) void k_mattn(
    const unsigned short* __restrict__ Qb, const unsigned short* __restrict__ Kb,
    const unsigned short* __restrict__ Vt, const float* __restrict__ gate,
    unsigned short* __restrict__ Ob)
{
  __shared__ unsigned char sQ[8192], sK[8192], sV[8192], sP[8192];
  __shared__ float sG[64];

  const int bh = blockIdx.x;
  const int b = bh >> 3;
  const int q0 = blockIdx.y * 64;
  const int z = blockIdx.z;
  const int tid = threadIdx.x;
  const int w = tid >> 6, lane = tid & 63;
  const int l16 = lane & 15, lh = lane >> 4;
  const bool hg = (z == 1) && (gate != nullptr);

  const unsigned short* Qz = Qb + (size_t)z * 2093056;
  const unsigned short* Kz = Kb + (size_t)z * 2093056;
  const unsigned short* Vz = Vt + (size_t)z * 2097152;
  unsigned short* Oz = Ob + (size_t)z * 2093056;
  const int h64 = (bh & 7) * 64;

  // stage Q tile [64 q][64 d]
#pragma unroll
  for (int it = 0; it < 2; ++it) {
    int i = it * 256 + tid;
    int row = i >> 3, oct = i & 7;
    int qr = q0 + row; if (qr > DWT_ - 1) qr = DWT_ - 1;
    u16x8 v = *(const u16x8*)(Qz + (size_t)(b * DWT_ + qr) * 512 + h64 + oct * 8);
    *(u16x8*)(sQ + row * 128 + ((oct ^ (row & 7)) << 4)) = v;
  }

  float m_ = -1e30f, l_ = 0.f;
  f32x4 accO[4];
#pragma unroll
  for (int jb = 0; jb < 4; ++jb) accO[jb] = (f32x4){0.f, 0.f, 0.f, 0.f};

  const unsigned short* vrow = Vz + (size_t)bh * 64 * 512;
  unsigned char* sPw = sP + w * 2048;   // wave-private [16 q][64 key] bf16

  for (int kt = 0; kt < 8; ++kt) {
    const int k0 = kt * 64;
    __syncthreads();
#pragma unroll
    for (int it = 0; it < 2; ++it) {
      int i = it * 256 + tid;
      int row = i >> 3, oct = i & 7;
      int kr = k0 + row; if (kr > DWT_ - 1) kr = DWT_ - 1;
      u16x8 v = *(const u16x8*)(Kz + (size_t)(b * DWT_ + kr) * 512 + h64 + oct * 8);
      *(u16x8*)(sK + row * 128 + ((oct ^ (row & 7)) << 4)) = v;
    }
#pragma unroll
    for (int it = 0; it < 2; ++it) {
      int i = it * 256 + tid;
      int row = i >> 3, oct = i & 7;      // row = d
      u16x8 v = *(const u16x8*)(vrow + (size_t)row * 512 + k0 + oct * 8);
      *(u16x8*)(sV + row * 128 + ((oct ^ (row & 7)) << 4)) = v;
    }
    if (hg && tid < 64) {
      int kk = k0 + tid;
      sG[tid] = (kk < DWT_) ? gate[(size_t)b * DWT_ + kk] : 0.f;
    }
    __syncthreads();

    // ---- S^T strip: rows = 64 keys (4 blocks), cols = wave's 16 q ----
    f32x4 sacc[4];
#pragma unroll
    for (int i = 0; i < 4; ++i) sacc[i] = (f32x4){0.f, 0.f, 0.f, 0.f};
#pragma unroll
    for (int s = 0; s < 2; ++s) {
      int qr = w * 16 + l16;
      bf16x8 qf = *(const bf16x8*)(sQ + qr * 128 + ((((s << 2) + lh) ^ (qr & 7)) << 4));
#pragma unroll
      for (int i = 0; i < 4; ++i) {
        int krr = i * 16 + l16;
        bf16x8 kf = *(const bf16x8*)(sK + krr * 128 + ((((s << 2) + lh) ^ (krr & 7)) << 4));
        sacc[i] = __builtin_amdgcn_mfma_f32_16x16x32_bf16(kf, qf, sacc[i], 0, 0, 0);
      }
    }

    // ---- softmax (lane owns one q) ----
    float sv[4][4];
    float tm = -1e30f;
#pragma unroll
    for (int i = 0; i < 4; ++i)
#pragma unroll
      for (int r = 0; r < 4; ++r) {
        float v = sacc[i][r] * 0.125f;
        if (k0 + i * 16 + lh * 4 + r >= DWT_) v = -1e30f;
        sv[i][r] = v;
        tm = fmaxf(tm, v);
      }
    tm = fmaxf(tm, __shfl_xor(tm, 16));
    tm = fmaxf(tm, __shfl_xor(tm, 32));
    float mn = fmaxf(m_, tm);
    float corr = __expf(m_ - mn);
    m_ = mn;
    float ts = 0.f;
    float p[4][4];
#pragma unroll
    for (int i = 0; i < 4; ++i)
#pragma unroll
      for (int r = 0; r < 4; ++r) {
        float e = __expf(sv[i][r] - mn);
        p[i][r] = e; ts += e;
      }
    ts += __shfl_xor(ts, 16);
    ts += __shfl_xor(ts, 32);
    l_ = l_ * corr + ts;

    // rescale accO (rows q-local = lh*4 + r; corr held by lane q-local)
#pragma unroll
    for (int r = 0; r < 4; ++r) {
      float cr = __shfl(corr, (lh << 2) + r);
#pragma unroll
      for (int jb = 0; jb < 4; ++jb) accO[jb][r] *= cr;
    }

    // gate + write P bf16 to wave-private LDS [q=l16][key]
#pragma unroll
    for (int i = 0; i < 4; ++i)
#pragma unroll
      for (int r = 0; r < 4; ++r) {
        float pv = p[i][r];
        int key = i * 16 + (lh << 2) + r;
        if (hg) pv *= sG[key];
        int slot = (key >> 3) ^ (l16 & 7);
        *(unsigned short*)(sPw + l16 * 128 + (slot << 4) + (key & 7) * 2) = f2bf(pv);
      }

    // ---- PV: A = P [16q][64key], B = V [key][d] from sV[d][key] ----
#pragma unroll
    for (int s = 0; s < 2; ++s) {
      bf16x8 pf = *(const bf16x8*)(sPw + l16 * 128 + ((((s << 2) + lh) ^ (l16 & 7)) << 4));
#pragma unroll
      for (int jb = 0; jb < 4; ++jb) {
        int vr = jb * 16 + l16;
        bf16x8 vf = *(const bf16x8*)(sV + vr * 128 + ((((s << 2) + lh) ^ (vr & 7)) << 4));
        accO[jb] = __builtin_amdgcn_mfma_f32_16x16x32_bf16(pf, vf, accO[jb], 0, 0, 0);
      }
    }
  }

  // ---- epilogue ----
  float linv = 1.f / l_;
#pragma unroll
  for (int r = 0; r < 4; ++r) {
    float li = __shfl(linv, (lh << 2) + r);
    int q = q0 + w * 16 + (lh << 2) + r;
    if (q >= DWT_) continue;
#pragma unroll
    for (int jb = 0; jb < 4; ++jb) {
      Oz[(size_t)(b * DWT_ + q) * 512 + h64 + jb * 16 + l16] = f2bf(accO[jb][r] * li);
    }
  }
}

// ---------------------------------------------------------------------------
// fused LayerNorm for both branches: y = blockIdx.y selects LL (with cross) / LH
__global__ __launch_bounds__(256) void k_ln2(
    const float* __restrict__ llseq, const float* __restrict__ llout,
    const float* __restrict__ crossb,
    const float* __restrict__ lhseq, const float* __restrict__ lhout,
    const float* __restrict__ g, const float* __restrict__ beta,
    float* __restrict__ llf, float* __restrict__ lhf)
{
  __shared__ float red[256], red2[256];
  int row = blockIdx.x, tid = threadIdx.x, zz = blockIdx.y;
  const float* a  = zz ? lhseq : llseq;
  const float* b2 = zz ? lhout : llout;
  const float* c  = zz ? nullptr : crossb;
  const float* gg = g + zz * D_;
  const float* bb = beta + zz * D_;
  float* outp = zz ? lhf : llf;
  size_t base = (size_t)row * D_;
  float v0 = a[base + tid] + b2[base + tid];
  float v1 = a[base + tid + 256] + b2[base + tid + 256];
  if (c) { v0 += c[base + tid]; v1 += c[base + tid + 256]; }
  red[tid] = v0 + v1; red2[tid] = v0 * v0 + v1 * v1;
  __syncthreads();
  for (int o = 128; o > 0; o >>= 1) {
    if (tid < o) { red[tid] += red[tid + o]; red2[tid] += red2[tid + o]; }
    __syncthreads();
  }
  float mu = red[0] / (float)D_;
  float var = red2[0] / (float)D_ - mu * mu;
  float rstd = rsqrtf(var + 1e-5f);
  outp[base + tid]       = (v0 - mu) * rstd * gg[tid] + bb[tid];
  outp[base + tid + 256] = (v1 - mu) * rstd * gg[tid + 256] + bb[tid + 256];
}

// ---------------------------------------------------------------------------
__global__ __launch_bounds__(256) void k_head_partial(
    const float* __restrict__ llo, const float* __restrict__ lho,
    const float* __restrict__ llg, const float* __restrict__ lhg,
    const float* __restrict__ hw, float* __restrict__ part)
{
  __shared__ float lds[8][512];
  int x = blockIdx.x;
  int branch = x / DWT_, t = x % DWT_;
  const float* seq = branch ? lho : llo;
  const float* gt  = branch ? lhg : llg;
  int tid = threadIdx.x;
  for (int i = tid; i < 8 * 512; i += 256) {
    int b = i >> 9, d = i & 511;
    lds[b][d] = seq[((size_t)b * DWT_ + t) * D_ + d] * gt[(size_t)t * D_ + d];
  }
  __syncthreads();
  size_t kbase = (size_t)x * D_;
  float acc[3] = {0.f, 0.f, 0.f};
  int pb[3], pr[3];
#pragma unroll
  for (int pi = 0; pi < 3; ++pi) {
    int pidx = tid + 256 * pi; pb[pi] = pidx / 96; pr[pi] = pidx % 96;
  }
  for (int k = 0; k < 512; ++k) {
    const float* wrow = hw + (kbase + k) * 96;
#pragma unroll
    for (int pi = 0; pi < 3; ++pi) acc[pi] += lds[pb[pi]][k] * wrow[pr[pi]];
  }
#pragma unroll
  for (int pi = 0; pi < 3; ++pi) part[(size_t)x * 768 + tid + 256 * pi] = acc[pi];
}

__global__ __launch_bounds__(128) void k_head_final(const float* __restrict__ part,
    const float* __restrict__ hb, const float* __restrict__ rw,
    const float* __restrict__ rb, const float* __restrict__ meanp,
    const float* __restrict__ stdp, float* __restrict__ preds)
{
  int b = blockIdx.x, p = threadIdx.x;
  if (p >= 96) return;
  float acc = hb[p];
  for (int c = 0; c < 1022; ++c) acc += part[(size_t)c * 768 + b * 96 + p];
  preds[b * 96 + p] = (acc - rb[0]) / (rw[0] + 1e-10f) * stdp[b] + meanp[b];
}

// ---------------------------------------------------------------------------
__global__ __launch_bounds__(512) void k_recon(const float* __restrict__ llo,
    const float* __restrict__ lho, const float* __restrict__ h,
    const float* __restrict__ g, float* __restrict__ outp)
{
  int o = blockIdx.x, b = blockIdx.y, d = threadIdx.x;
  const float* hd = h + d * 4;
  const float* gd = g + d * 4;
  float acc = 0.f;
  if ((o & 1) == 0) {
    int t = o >> 1;
    if (t >= 1) {
      size_t i = ((size_t)b * DWT_ + t - 1) * D_ + d;
      acc += llo[i] * hd[3] + lho[i] * gd[3];
    }
    size_t i = ((size_t)b * DWT_ + t) * D_ + d;
    acc += llo[i] * hd[1] + lho[i] * gd[1];
  } else {
    int t = (o - 1) >> 1;
    size_t i = ((size_t)b * DWT_ + t) * D_ + d;
    acc += llo[i] * hd[2] + lho[i] * gd[2];
    if (t + 1 < DWT_) {
      size_t i2 = ((size_t)b * DWT_ + t + 1) * D_ + d;
      acc += llo[i2] * hd[0] + lho[i2] * gd[0];
    }
  }
  outp[((size_t)b * D_ + d) * RECON_LEN + o] = acc;
}

// ---------------------------------------------------------------------------
extern "C" void kernel_launch(void* const* d_in, const int* in_sizes, int n_in,
                              void* d_out, int out_size, void* d_ws, size_t ws_size,
                              hipStream_t stream)
{
  const float* x       = (const float*)d_in[0];
  const float* revin_w = (const float*)d_in[1];
  const float* revin_b = (const float*)d_in[2];
  const float* patch_W = (const float*)d_in[3];
  const float* patch_b = (const float*)d_in[4];
  const float* pos_emb = (const float*)d_in[5];
  const float* dwt_h   = (const float*)d_in[6];
  const float* dwt_g   = (const float*)d_in[7];
  const float* raw_tau = (const float*)d_in[8];
  const float* attn_W  = (const float*)d_in[9];
  const float* attn_b  = (const float*)d_in[10];
  const float* mlp_W1  = (const float*)d_in[11];
  const float* mlp_b1  = (const float*)d_in[12];
  const float* mlp_W2  = (const float*)d_in[13];
  const float* mlp_b2  = (const float*)d_in[14];
  const float* ln_g    = (const float*)d_in[15];
  const float* ln_b    = (const float*)d_in[16];
  const float* ll_gate = (const float*)d_in[17];
  const float* lh_gate = (const float*)d_in[18];
  const float* head_W  = (const float*)d_in[19];
  const float* head_b  = (const float*)d_in[20];

  float* ws  = (float*)d_ws;
  float* out = (float*)d_out;

  float* meanp = ws + WS_MEAN;
  float* stdp  = ws + WS_STD;
  float* xn    = ws + WS_XN;
  float* pseq  = ws + WS_PSEQ;
  float* llseq = ws + WS_LLSEQ;
  float* lhseq = ws + WS_LHSEQ;
  float* llout = ws + WS_LLOUT;
  float* lhout = ws + WS_LHOUT;
  float* crossb= ws + WS_CROSS;
  float* gateb = ws + WS_GATE;
  float* llf   = ws + WS_LLF;
  float* lhf   = ws + WS_LHF;
  float* llo   = ws + WS_LLO;
  float* lho   = ws + WS_LHO;
  float* part  = ws + WS_PART;

  unsigned short* Qb16  = (unsigned short*)(ws + WS_QB);
  unsigned short* Kb16  = (unsigned short*)(ws + WS_KB);
  unsigned short* Vt16  = (unsigned short*)(ws + WS_VT);
  unsigned short* Ob16  = (unsigned short*)(ws + WS_OB);
  unsigned short* hid16 = (unsigned short*)(ws + WS_HID2);

  unsigned short* wt  = (unsigned short*)(ws + WS_PSEQ);  // bf16 weights (after dwt)
  unsigned short* w1t = wt + 12 * 262144;                 // 2 x [2048][512]
  unsigned short* w2t = w1t + 2 * 1048576;                // 2 x [512][2048]

  // ---- stage 0: RevIN + patch embed + patches output + DWT ----
  k_revin<<<8, 256, 0, stream>>>(x, revin_w, revin_b, meanp, stdp, xn);
  k_patch<<<dim3(N_, B_), 512, 0, stream>>>(xn, patch_W, patch_b, pos_emb, pseq);
  k_transpose<<<dim3(16, 32, B_), dim3(32, 8), 0, stream>>>(pseq, out + PATCHES_O);
  k_dwt<<<dim3(DWT_, B_), 512, 0, stream>>>(pseq, dwt_h, dwt_g, llseq, lhseq,
                                            out + OUT_LL_O, out + OUT_LH_O);
  k_gate<<<MR_, 64, 0, stream>>>(lhseq, raw_tau, gateb);

  // ---- weight transpose+convert (pseq region is dead now) ----
  k_wt<<<dim3(16, 16, 12), dim3(32, 8), 0, stream>>>(attn_W, wt, 512, 512);
  k_wt<<<dim3(64, 16, 2), dim3(32, 8), 0, stream>>>(mlp_W1, w1t, 512, 2048);
  k_wt<<<dim3(16, 64, 2), dim3(32, 8), 0, stream>>>(mlp_W2, w2t, 2048, 512);

  // ---- stage 1: LL + LH MHAs batched ----
  k_gemm_mfma<64,1,3><<<dim3(12, 64, 2), 256, 0, stream>>>(
      llseq, llseq, lhseq, lhseq, wt, attn_b, nullptr, nullptr,
      Qb16, Kb16, Vt16, MR_, 1536, D_, 0, 4 * 262144, 2048);
  k_mattn<<<dim3(64, 8, 2), 256, 0, stream>>>(Qb16, Kb16, Vt16, gateb, Ob16);
  k_gemm_mfma<64,0,0><<<dim3(4, 64, 2), 256, 0, stream>>>(
      Ob16, nullptr, Ob16 + (size_t)2093056, nullptr, wt + 3 * 262144,
      attn_b + 1536, nullptr, nullptr, llout, lhout, nullptr,
      MR_, D_, D_, 0, 4 * 262144, 2048);

  // ---- cross MHA: Q from llout, K/V from lhout ----
  k_gemm_mfma<64,1,3><<<dim3(12, 64, 1), 256, 0, stream>>>(
      llout, lhout, nullptr, nullptr, wt + 8 * 262144, attn_b + 2 * 2048,
      nullptr, nullptr, Qb16, Kb16, Vt16, MR_, 1536, D_, 0, 0, 0);
  k_mattn<<<dim3(64, 8, 1), 256, 0, stream>>>(Qb16, Kb16, Vt16, nullptr, Ob16);
  k_gemm_mfma<64,0,0><<<dim3(4, 64, 1), 256, 0, stream>>>(
      Ob16, nullptr, nullptr, nullptr, wt + 11 * 262144, attn_b + 2 * 2048 + 1536,
      nullptr, nullptr, crossb, nullptr, nullptr, MR_, D_, D_, 0, 0, 0);

  // ---- stage 2: fused LN + batched MLP ----
  k_ln2<<<dim3(MR_, 2), 256, 0, stream>>>(llseq, llout, crossb, lhseq, lhout,
                                          ln_g, ln_b, llf, lhf);
  k_gemm_mfma<128,1,1><<<dim3(16, 32, 2), 256, 0, stream>>>(
      llf, nullptr, lhf, nullptr, w1t, mlp_b1, nullptr, nullptr,
      hid16, hid16 + (size_t)4088 * 2048, nullptr, MR_, DFF_, D_, 1,
      1048576, 2048);
  k_gemm_mfma<64,0,0><<<dim3(4, 64, 2), 256, 0, stream>>>(
      hid16, nullptr, hid16 + (size_t)4088 * 2048, nullptr, w2t, mlp_b2,
      llf, lhf, llo, lho, nullptr, MR_, D_, DFF_, 0, 1048576, 512);

  // ---- stage 3: head + denorm ----
  k_head_partial<<<2 * DWT_, 256, 0, stream>>>(llo, lho, ll_gate, lh_gate, head_W, part);
  k_head_final<<<B_, 128, 0, stream>>>(part, head_b, revin_w, revin_b, meanp, stdp,
                                       out + PREDS_O);

  // ---- stage 4: inverse DWT recon ----
  k_recon<<<dim3(RECON_LEN, B_), 512, 0, stream>>>(llo, lho, dwt_h, dwt_g, out + RECON_O);
}

// Round 6
// 533.653 us; speedup vs baseline: 9.2338x; 1.1317x over previous
//
#include <hip/hip_runtime.h>
#include <math.h>

#define B_    8
#define SEQ_  8192
#define D_    512
#define N_    1023
#define DWT_  511
#define DFF_  2048
#define MR_   (B_ * DWT_)          // 4088 rows for all [B*L, D] GEMMs

// ---------------- d_out layout (flat concat of the 5 outputs) ----------------
#define PREDS_O    0
#define RECON_O    768
#define RECON_LEN  1022
#define PATCHES_O  (RECON_O + 8*512*1022)   // 4186880
#define OUT_LL_O   (PATCHES_O + 8*512*1023) // 8377088
#define OUT_LH_O   (OUT_LL_O + 8*512*511)   // 10470144

// ---------------- workspace layout (floats) ----------------
#define WS_MEAN   ((size_t)0)
#define WS_STD    ((size_t)8)
#define WS_XN     ((size_t)16)
#define WS_PSEQ   ((size_t)65552)
#define WS_LLSEQ  ((size_t)4255760)
#define WS_LHSEQ  ((size_t)6348816)
#define WS_LLOUT  ((size_t)16814096)
#define WS_LHOUT  ((size_t)18907152)
#define WS_CROSS  ((size_t)21000208)
#define WS_LLF    ((size_t)23097352)   // now bf16 [4088][512] (half the region)
#define WS_LHF    ((size_t)25190408)   // now bf16
#define WS_LLO    WS_LLOUT
#define WS_LHO    WS_LHOUT
#define WS_PART   WS_CROSS    // head partials alias cross (phase-disjoint)
#define WS_GATE   ((size_t)23093264)
// double-z bf16 buffers beyond the old arena (ws ~766MiB)
#define WS_QB     ((size_t)27283464)            // 2 x [4088][512] bf16
#define WS_KB     (WS_QB + 2093056)
#define WS_VT     (WS_KB + 2093056)             // 2 x [4096][512] bf16
#define WS_OB     (WS_VT + 2097152)
#define WS_HID2   (WS_OB + 2093056)             // 2 x [4088][2048] bf16

using bf16x8 = __attribute__((ext_vector_type(8))) short;
using u16x8  = __attribute__((ext_vector_type(8))) unsigned short;
using f32x4  = __attribute__((ext_vector_type(4))) float;

__device__ inline unsigned short f2bf(float f) {
  unsigned u = __float_as_uint(f);
  u += 0x7fffu + ((u >> 16) & 1u);    // round-to-nearest-even
  return (unsigned short)(u >> 16);
}
__device__ inline float bf2f(unsigned short h) {
  return __uint_as_float(((unsigned)h) << 16);
}

// ---------------------------------------------------------------------------
__global__ __launch_bounds__(256) void k_revin(const float* __restrict__ x,
    const float* __restrict__ rw, const float* __restrict__ rb,
    float* __restrict__ meanp, float* __restrict__ stdp, float* __restrict__ xn)
{
  __shared__ float rs[256], rs2[256];
  int b = blockIdx.x, tid = threadIdx.x;
  const float* xb = x + (size_t)b * SEQ_;
  float s = 0.f, s2 = 0.f;
  for (int i = tid; i < SEQ_; i += 256) { float v = xb[i]; s += v; s2 += v * v; }
  rs[tid] = s; rs2[tid] = s2; __syncthreads();
  for (int o = 128; o > 0; o >>= 1) {
    if (tid < o) { rs[tid] += rs[tid + o]; rs2[tid] += rs2[tid + o]; }
    __syncthreads();
  }
  float mu = rs[0] / SEQ_;
  float var = rs2[0] / SEQ_ - mu * mu;
  float sd = sqrtf(var + 1e-5f);
  if (tid == 0) { meanp[b] = mu; stdp[b] = sd; }
  float w = rw[0], bb = rb[0], inv = 1.f / sd;
  for (int i = tid; i < SEQ_; i += 256)
    xn[(size_t)b * SEQ_ + i] = (xb[i] - mu) * inv * w + bb;
}

// ---------------------------------------------------------------------------
__global__ __launch_bounds__(512) void k_patch(const float* __restrict__ xn,
    const float* __restrict__ pW, const float* __restrict__ pb,
    const float* __restrict__ pos, float* __restrict__ p_seq)
{
  __shared__ float sx[16];
  int n = blockIdx.x, b = blockIdx.y, d = threadIdx.x;
  if (threadIdx.x < 16) sx[threadIdx.x] = xn[(size_t)b * SEQ_ + n * 8 + threadIdx.x];
  __syncthreads();
  float acc = pb[d] + pos[(size_t)n * D_ + d];
#pragma unroll
  for (int k = 0; k < 16; ++k) acc += sx[k] * pW[k * D_ + d];
  p_seq[((size_t)b * N_ + n) * D_ + d] = acc;
}

// ---------------------------------------------------------------------------
__global__ __launch_bounds__(256) void k_transpose(const float* __restrict__ p_seq,
                                                   float* __restrict__ outp)
{
  __shared__ float tile[32][33];
  int d0 = blockIdx.x * 32, n0 = blockIdx.y * 32, b = blockIdx.z;
  int tx = threadIdx.x, ty = threadIdx.y;
#pragma unroll
  for (int r = 0; r < 4; ++r) {
    int n = n0 + ty + 8 * r;
    if (n < N_) tile[ty + 8 * r][tx] = p_seq[((size_t)b * N_ + n) * D_ + d0 + tx];
  }
  __syncthreads();
#pragma unroll
  for (int r = 0; r < 4; ++r) {
    int d = d0 + ty + 8 * r, n = n0 + tx;
    if (n < N_) outp[((size_t)b * D_ + d) * N_ + n] = tile[tx][ty + 8 * r];
  }
}

// ---------------------------------------------------------------------------
// DWT + fused energy gate (gate = sigmoid((mean_d|LH| - tau)*10))
__global__ __launch_bounds__(512) void k_dwt(const float* __restrict__ p_seq,
    const float* __restrict__ h, const float* __restrict__ g,
    float* __restrict__ ll_seq, float* __restrict__ lh_seq,
    float* __restrict__ ll_out, float* __restrict__ lh_out,
    const float* __restrict__ raw_tau, float* __restrict__ gate)
{
  __shared__ float red[512];
  int t = blockIdx.x, b = blockIdx.y, d = threadIdx.x;
  float ah = 0.f, ag = 0.f;
#pragma unroll
  for (int k = 0; k < 4; ++k) {
    int n = 2 * t + k - 1;
    if (n >= 0 && n < N_) {
      float v = p_seq[((size_t)b * N_ + n) * D_ + d];
      ah += v * h[d * 4 + k];
      ag += v * g[d * 4 + k];
    }
  }
  ll_seq[((size_t)b * DWT_ + t) * D_ + d] = ah;
  lh_seq[((size_t)b * DWT_ + t) * D_ + d] = ag;
  ll_out[((size_t)b * D_ + d) * DWT_ + t] = ah;
  lh_out[((size_t)b * D_ + d) * DWT_ + t] = ag;
  red[d] = fabsf(ag);
  __syncthreads();
  for (int o = 256; o > 0; o >>= 1) {
    if (d < o) red[d] += red[d + o];
    __syncthreads();
  }
  if (d == 0) {
    float tau = 1.f / (1.f + expf(-raw_tau[0]));
    float e = red[0] / (float)D_;
    gate[(size_t)b * DWT_ + t] = 1.f / (1.f + expf(-(e - tau) * 10.f));
  }
}

// ---------------------------------------------------------------------------
// weight transpose+convert: src fp32 [K][N] (z-th matrix) -> dst bf16 [N][K]
__global__ __launch_bounds__(256) void k_wt(const float* __restrict__ src,
    unsigned short* __restrict__ dst, int K, int N)
{
  __shared__ float t[32][33];
  int z = blockIdx.z;
  src += (size_t)z * K * N;
  dst += (size_t)z * K * N;
  int n0 = blockIdx.x * 32, k0 = blockIdx.y * 32;
  int tx = threadIdx.x, ty = threadIdx.y;     // (32, 8)
#pragma unroll
  for (int r = 0; r < 4; ++r)
    t[ty + 8 * r][tx] = src[(size_t)(k0 + ty + 8 * r) * N + n0 + tx];
  __syncthreads();
#pragma unroll
  for (int r = 0; r < 4; ++r)
    dst[(size_t)(n0 + ty + 8 * r) * K + k0 + tx] = f2bf(t[tx][ty + 8 * r]);
}

// ---------------------------------------------------------------------------
// C = A @ WT^T + bias (+res) (opt gelu) via MFMA, z-batched.
// AF32: A fp32 (convert during staging) else bf16.
// CMODE 0: fp32 C[m][n] (+res; RESBF: residual stored bf16). 1: bf16 C[m][n].
// CMODE 3: fused QKV: n<512 -> Q bf16; <1024 -> K bf16; >=1024 -> V transposed.
template<int BM, int AF32, int CMODE, int RESBF = 0>
__global__ __launch_bounds__(256, BM == 64 ? 4 : 2) void k_gemm_mfma(
    const void* __restrict__ A00, const void* __restrict__ A01,
    const void* __restrict__ A10, const void* __restrict__ A11,
    const unsigned short* __restrict__ WT, const float* __restrict__ bias,
    const void* __restrict__ res0, const void* __restrict__ res1,
    void* __restrict__ C0, void* __restrict__ C1, void* __restrict__ C2,
    int M, int N, int K, int act, int zsW, int zsB)
{
  __shared__ unsigned char lds[(BM + 128) * 128];
  unsigned char* sA = lds;
  unsigned char* sB = lds + BM * 128;

  const int tid = threadIdx.x;
  const int wid = tid >> 6, lane = tid & 63;
  const int n0 = blockIdx.x * 128, m0 = blockIdx.y * BM;
  const int z = blockIdx.z;
  constexpr int MI = 4;
  constexpr int NI = (BM == 128) ? 4 : 2;
  const int wrow = (BM == 128) ? (wid >> 1) * 64 : 0;
  const int wcol = (BM == 128) ? (wid & 1) * 64 : wid * 32;
  const int l16 = lane & 15, lh = lane >> 4;

  const unsigned short* wt_ = WT + (size_t)z * zsW;
  const float* bias_ = bias + (size_t)z * zsB;
  const void* Ap;
  if (CMODE == 3) Ap = z ? (n0 < 512 ? A10 : A11) : (n0 < 512 ? A00 : A01);
  else            Ap = z ? A10 : A00;

  f32x4 acc[MI][NI];
#pragma unroll
  for (int i = 0; i < MI; ++i)
#pragma unroll
    for (int j = 0; j < NI; ++j) acc[i][j] = (f32x4){0.f, 0.f, 0.f, 0.f};

  constexpr int AITER = BM / 32;
  for (int k0 = 0; k0 < K; k0 += 64) {
    __syncthreads();
    // ---- stage A ----
#pragma unroll
    for (int it = 0; it < AITER; ++it) {
      int i = it * 256 + tid;
      int row = i >> 3, oct = i & 7;
      int gr = m0 + row; if (gr > M - 1) gr = M - 1;
      if (AF32) {
        const float* src = (const float*)Ap + (size_t)gr * K + k0 + oct * 8;
        float4 v0 = *(const float4*)src;
        float4 v1 = *(const float4*)(src + 4);
        u16x8 pk;
        pk[0] = f2bf(v0.x); pk[1] = f2bf(v0.y); pk[2] = f2bf(v0.z); pk[3] = f2bf(v0.w);
        pk[4] = f2bf(v1.x); pk[5] = f2bf(v1.y); pk[6] = f2bf(v1.z); pk[7] = f2bf(v1.w);
        *(u16x8*)(sA + row * 128 + ((oct ^ (row & 7)) << 4)) = pk;
      } else {
        u16x8 pk = *(const u16x8*)((const unsigned short*)Ap + (size_t)gr * K + k0 + oct * 8);
        *(u16x8*)(sA + row * 128 + ((oct ^ (row & 7)) << 4)) = pk;
      }
    }
    // ---- stage B (bf16, [N][K]) ----
#pragma unroll
    for (int it = 0; it < 4; ++it) {
      int i = it * 256 + tid;
      int row = i >> 3, oct = i & 7;
      uint4 v = *(const uint4*)(wt_ + (size_t)(n0 + row) * K + k0 + oct * 8);
      *(uint4*)(sB + row * 128 + ((oct ^ (row & 7)) << 4)) = v;
    }
    __syncthreads();
    // ---- MFMA ----
#pragma unroll
    for (int s = 0; s < 2; ++s) {
      bf16x8 af[MI], bfr[NI];
#pragma unroll
      for (int i = 0; i < MI; ++i) {
        int r = wrow + i * 16 + l16;
        af[i] = *(const bf16x8*)(sA + r * 128 + (((s * 4 + lh) ^ (r & 7)) << 4));
      }
#pragma unroll
      for (int j = 0; j < NI; ++j) {
        int r = wcol + j * 16 + l16;
        bfr[j] = *(const bf16x8*)(sB + r * 128 + (((s * 4 + lh) ^ (r & 7)) << 4));
      }
#pragma unroll
      for (int i = 0; i < MI; ++i)
#pragma unroll
        for (int j = 0; j < NI; ++j)
          acc[i][j] = __builtin_amdgcn_mfma_f32_16x16x32_bf16(af[i], bfr[j],
                                                              acc[i][j], 0, 0, 0);
    }
  }
  // ---- epilogue ----
  const void* res_ = z ? res1 : res0;
#pragma unroll
  for (int i = 0; i < MI; ++i) {
#pragma unroll
    for (int r = 0; r < 4; ++r) {
      int m = m0 + wrow + i * 16 + lh * 4 + r;
      if (m >= M) continue;
#pragma unroll
      for (int j = 0; j < NI; ++j) {
        int n = n0 + wcol + j * 16 + l16;
        float v = acc[i][j][r] + bias_[n];
        if (act) v = 0.5f * v * (1.f + erff(v * 0.70710678118654752f));
        if (CMODE == 0) {
          float* Cp = (float*)(z ? C1 : C0);
          if (res_) {
            float rv = RESBF ? bf2f(((const unsigned short*)res_)[(size_t)m * N + n])
                             : ((const float*)res_)[(size_t)m * N + n];
            v += rv;
          }
          Cp[(size_t)m * N + n] = v;
        } else if (CMODE == 1) {
          unsigned short* Cp = (unsigned short*)(z ? C1 : C0);
          Cp[(size_t)m * N + n] = f2bf(v);
        } else {
          if (n < 512) {
            ((unsigned short*)C0)[(size_t)z * 2093056 + (size_t)m * 512 + n] = f2bf(v);
          } else if (n < 1024) {
            ((unsigned short*)C1)[(size_t)z * 2093056 + (size_t)m * 512 + (n - 512)] = f2bf(v);
          } else {
            int bb = m / DWT_;
            int key = m - bb * DWT_;
            ((unsigned short*)C2)[(size_t)z * 2097152 +
                ((size_t)(bb * 512 + (n - 1024))) * 512 + key] = f2bf(v);
          }
        }
      }
    }
  }
}

// ---------------------------------------------------------------------------
// MFMA flash attention, z-batched, register-prefetched K/V staging (T14).
__global__ __launch_bounds__(256) void k_mattn(
    const unsigned short* __restrict__ Qb, const unsigned short* __restrict__ Kb,
    const unsigned short* __restrict__ Vt, const float* __restrict__ gate,
    unsigned short* __restrict__ Ob)
{
  __shared__ unsigned char sQ[8192], sK[8192], sV[8192], sP[8192];
  __shared__ float sG[64];

  const int bh = blockIdx.x;
  const int b = bh >> 3;
  const int q0 = blockIdx.y * 64;
  const int z = blockIdx.z;
  const int tid = threadIdx.x;
  const int w = tid >> 6, lane = tid & 63;
  const int l16 = lane & 15, lh = lane >> 4;
  const bool hg = (z == 1) && (gate != nullptr);
  const int bD = b * DWT_;

  const unsigned short* Qz = Qb + (size_t)z * 2093056;
  const unsigned short* Kz = Kb + (size_t)z * 2093056;
  const unsigned short* Vz = Vt + (size_t)z * 2097152;
  unsigned short* Oz = Ob + (size_t)z * 2093056;
  const int h64 = (bh & 7) * 64;
  const unsigned short* vrow = Vz + (size_t)bh * 64 * 512;

  // stage Q tile [64 q][64 d]
#pragma unroll
  for (int it = 0; it < 2; ++it) {
    int i = it * 256 + tid;
    int row = i >> 3, oct = i & 7;
    int qr = q0 + row; if (qr > DWT_ - 1) qr = DWT_ - 1;
    u16x8 v = *(const u16x8*)(Qz + (size_t)(bD + qr) * 512 + h64 + oct * 8);
    *(u16x8*)(sQ + row * 128 + ((oct ^ (row & 7)) << 4)) = v;
  }

  // preload full gate vector (2 keys per thread)
  float ga = 0.f, gb2 = 0.f;
  if (hg) {
    int k = 2 * tid;
    ga  = (k     < DWT_) ? gate[(size_t)bD + k]     : 0.f;
    gb2 = (k + 1 < DWT_) ? gate[(size_t)bD + k + 1] : 0.f;
  }

  float m_ = -1e30f, l_ = 0.f;
  f32x4 accO[4];
#pragma unroll
  for (int jb = 0; jb < 4; ++jb) accO[jb] = (f32x4){0.f, 0.f, 0.f, 0.f};

  unsigned char* sPw = sP + w * 2048;   // wave-private [16 q][64 key] bf16

  uint4 pk0, pk1, pv0, pv1;
#define LOADT(kt_) do {                                                      \
    int k0_ = (kt_) * 64;                                                    \
    int row_ = tid >> 3, oct_ = tid & 7;                                     \
    int kr0_ = k0_ + row_;      if (kr0_ > DWT_ - 1) kr0_ = DWT_ - 1;        \
    int kr1_ = k0_ + row_ + 32; if (kr1_ > DWT_ - 1) kr1_ = DWT_ - 1;        \
    pk0 = *(const uint4*)(Kz + (size_t)(bD + kr0_) * 512 + h64 + oct_ * 8);  \
    pk1 = *(const uint4*)(Kz + (size_t)(bD + kr1_) * 512 + h64 + oct_ * 8);  \
    pv0 = *(const uint4*)(vrow + (size_t)row_ * 512 + k0_ + oct_ * 8);       \
    pv1 = *(const uint4*)(vrow + (size_t)(row_ + 32) * 512 + k0_ + oct_ * 8);\
  } while (0)

  LOADT(0);
  for (int kt = 0; kt < 8; ++kt) {
    const int k0 = kt * 64;
    __syncthreads();                    // prior-iter PV reads complete
    {
      int row = tid >> 3, oct = tid & 7, row1 = (tid >> 3) + 32;
      *(uint4*)(sK + row  * 128 + ((oct ^ (row  & 7)) << 4)) = pk0;
      *(uint4*)(sK + row1 * 128 + ((oct ^ (row1 & 7)) << 4)) = pk1;
      *(uint4*)(sV + row  * 128 + ((oct ^ (row  & 7)) << 4)) = pv0;
      *(uint4*)(sV + row1 * 128 + ((oct ^ (row1 & 7)) << 4)) = pv1;
    }
    if (hg && (tid >> 5) == kt) {
      sG[(tid & 31) * 2]     = ga;
      sG[(tid & 31) * 2 + 1] = gb2;
    }
    __syncthreads();
    if (kt < 7) LOADT(kt + 1);          // prefetch next tile under compute

    // ---- S^T strip: rows = 64 keys (4 blocks), cols = wave's 16 q ----
    f32x4 sacc[4];
#pragma unroll
    for (int i = 0; i < 4; ++i) sacc[i] = (f32x4){0.f, 0.f, 0.f, 0.f};
#pragma unroll
    for (int s = 0; s < 2; ++s) {
      int qr = w * 16 + l16;
      bf16x8 qf = *(const bf16x8*)(sQ + qr * 128 + ((((s << 2) + lh) ^ (qr & 7)) << 4));
#pragma unroll
      for (int i = 0; i < 4; ++i) {
        int krr = i * 16 + l16;
        bf16x8 kf = *(const bf16x8*)(sK + krr * 128 + ((((s << 2) + lh) ^ (krr & 7)) << 4));
        sacc[i] = __builtin_amdgcn_mfma_f32_16x16x32_bf16(kf, qf, sacc[i], 0, 0, 0);
      }
    }

    // ---- softmax (lane owns one q) ----
    float sv[4][4];
    float tm = -1e30f;
#pragma unroll
    for (int i = 0; i < 4; ++i)
#pragma unroll
      for (int r = 0; r < 4; ++r) {
        float v = sacc[i][r] * 0.125f;
        if (k0 + i * 16 + lh * 4 + r >= DWT_) v = -1e30f;
        sv[i][r] = v;
        tm = fmaxf(tm, v);
      }
    tm = fmaxf(tm, __shfl_xor(tm, 16));
    tm = fmaxf(tm, __shfl_xor(tm, 32));
    float mn = fmaxf(m_, tm);
    float corr = __expf(m_ - mn);
    m_ = mn;
    float ts = 0.f;
    float p[4][4];
#pragma unroll
    for (int i = 0; i < 4; ++i)
#pragma unroll
      for (int r = 0; r < 4; ++r) {
        float e = __expf(sv[i][r] - mn);
        p[i][r] = e; ts += e;
      }
    ts += __shfl_xor(ts, 16);
    ts += __shfl_xor(ts, 32);
    l_ = l_ * corr + ts;

    // rescale accO (rows q-local = lh*4 + r; corr held by lane q-local)
#pragma unroll
    for (int r = 0; r < 4; ++r) {
      float cr = __shfl(corr, (lh << 2) + r);
#pragma unroll
      for (int jb = 0; jb < 4; ++jb) accO[jb][r] *= cr;
    }

    // gate + write P bf16 to wave-private LDS [q=l16][key]
#pragma unroll
    for (int i = 0; i < 4; ++i)
#pragma unroll
      for (int r = 0; r < 4; ++r) {
        float pv = p[i][r];
        int key = i * 16 + (lh << 2) + r;
        if (hg) pv *= sG[key];
        int slot = (key >> 3) ^ (l16 & 7);
        *(unsigned short*)(sPw + l16 * 128 + (slot << 4) + (key & 7) * 2) = f2bf(pv);
      }

    // ---- PV: A = P [16q][64key], B = V [key][d] from sV[d][key] ----
#pragma unroll
    for (int s = 0; s < 2; ++s) {
      bf16x8 pf = *(const bf16x8*)(sPw + l16 * 128 + ((((s << 2) + lh) ^ (l16 & 7)) << 4));
#pragma unroll
      for (int jb = 0; jb < 4; ++jb) {
        int vr = jb * 16 + l16;
        bf16x8 vf = *(const bf16x8*)(sV + vr * 128 + ((((s << 2) + lh) ^ (vr & 7)) << 4));
        accO[jb] = __builtin_amdgcn_mfma_f32_16x16x32_bf16(pf, vf, accO[jb], 0, 0, 0);
      }
    }
  }
#undef LOADT

  // ---- epilogue ----
  float linv = 1.f / l_;
#pragma unroll
  for (int r = 0; r < 4; ++r) {
    float li = __shfl(linv, (lh << 2) + r);
    int q = q0 + w * 16 + (lh << 2) + r;
    if (q >= DWT_) continue;
#pragma unroll
    for (int jb = 0; jb < 4; ++jb) {
      Oz[(size_t)(bD + q) * 512 + h64 + jb * 16 + l16] = f2bf(accO[jb][r] * li);
    }
  }
}

// ---------------------------------------------------------------------------
// fused LayerNorm for both branches -> bf16 outputs
__global__ __launch_bounds__(256) void k_ln2(
    const float* __restrict__ llseq, const float* __restrict__ llout,
    const float* __restrict__ crossb,
    const float* __restrict__ lhseq, const float* __restrict__ lhout,
    const float* __restrict__ g, const float* __restrict__ beta,
    unsigned short* __restrict__ llf, unsigned short* __restrict__ lhf)
{
  __shared__ float red[256], red2[256];
  int row = blockIdx.x, tid = threadIdx.x, zz = blockIdx.y;
  const float* a  = zz ? lhseq : llseq;
  const float* b2 = zz ? lhout : llout;
  const float* c  = zz ? nullptr : crossb;
  const float* gg = g + zz * D_;
  const float* bb = beta + zz * D_;
  unsigned short* outp = zz ? lhf : llf;
  size_t base = (size_t)row * D_;
  float v0 = a[base + tid] + b2[base + tid];
  float v1 = a[base + tid + 256] + b2[base + tid + 256];
  if (c) { v0 += c[base + tid]; v1 += c[base + tid + 256]; }
  red[tid] = v0 + v1; red2[tid] = v0 * v0 + v1 * v1;
  __syncthreads();
  for (int o = 128; o > 0; o >>= 1) {
    if (tid < o) { red[tid] += red[tid + o]; red2[tid] += red2[tid + o]; }
    __syncthreads();
  }
  float mu = red[0] / (float)D_;
  float var = red2[0] / (float)D_ - mu * mu;
  float rstd = rsqrtf(var + 1e-5f);
  outp[base + tid]       = f2bf((v0 - mu) * rstd * gg[tid] + bb[tid]);
  outp[base + tid + 256] = f2bf((v1 - mu) * rstd * gg[tid + 256] + bb[tid + 256]);
}

// ---------------------------------------------------------------------------
__global__ __launch_bounds__(256) void k_head_partial(
    const float* __restrict__ llo, const float* __restrict__ lho,
    const float* __restrict__ llg, const float* __restrict__ lhg,
    const float* __restrict__ hw, float* __restrict__ part)
{
  __shared__ float lds[8][512];
  int x = blockIdx.x;
  int branch = x / DWT_, t = x % DWT_;
  const float* seq = branch ? lho : llo;
  const float* gt  = branch ? lhg : llg;
  int tid = threadIdx.x;
  for (int i = tid; i < 8 * 512; i += 256) {
    int b = i >> 9, d = i & 511;
    lds[b][d] = seq[((size_t)b * DWT_ + t) * D_ + d] * gt[(size_t)t * D_ + d];
  }
  __syncthreads();
  size_t kbase = (size_t)x * D_;
  float acc[3] = {0.f, 0.f, 0.f};
  int pb[3], pr[3];
#pragma unroll
  for (int pi = 0; pi < 3; ++pi) {
    int pidx = tid + 256 * pi; pb[pi] = pidx / 96; pr[pi] = pidx % 96;
  }
  for (int k = 0; k < 512; ++k) {
    const float* wrow = hw + (kbase + k) * 96;
#pragma unroll
    for (int pi = 0; pi < 3; ++pi) acc[pi] += lds[pb[pi]][k] * wrow[pr[pi]];
  }
#pragma unroll
  for (int pi = 0; pi < 3; ++pi) part[(size_t)x * 768 + tid + 256 * pi] = acc[pi];
}

// wave-per-(b,p) reduction over 1022 chunks
__global__ __launch_bounds__(256) void k_head_final(const float* __restrict__ part,
    const float* __restrict__ hb, const float* __restrict__ rw,
    const float* __restrict__ rb, const float* __restrict__ meanp,
    const float* __restrict__ stdp, float* __restrict__ preds)
{
  int wv = (blockIdx.x << 2) + (threadIdx.x >> 6);
  int lane = threadIdx.x & 63;
  if (wv >= 768) return;
  int b = wv / 96, p = wv - b * 96;
  float s = 0.f;
  for (int c = lane; c < 2 * DWT_; c += 64) s += part[(size_t)c * 768 + b * 96 + p];
#pragma unroll
  for (int off = 32; off; off >>= 1) s += __shfl_xor(s, off);
  if (lane == 0) {
    float acc = s + hb[p];
    preds[b * 96 + p] = (acc - rb[0]) / (rw[0] + 1e-10f) * stdp[b] + meanp[b];
  }
}

// ---------------------------------------------------------------------------
__global__ __launch_bounds__(512) void k_recon(const float* __restrict__ llo,
    const float* __restrict__ lho, const float* __restrict__ h,
    const float* __restrict__ g, float* __restrict__ outp)
{
  int o = blockIdx.x, b = blockIdx.y, d = threadIdx.x;
  const float* hd = h + d * 4;
  const float* gd = g + d * 4;
  float acc = 0.f;
  if ((o & 1) == 0) {
    int t = o >> 1;
    if (t >= 1) {
      size_t i = ((size_t)b * DWT_ + t - 1) * D_ + d;
      acc += llo[i] * hd[3] + lho[i] * gd[3];
    }
    size_t i = ((size_t)b * DWT_ + t) * D_ + d;
    acc += llo[i] * hd[1] + lho[i] * gd[1];
  } else {
    int t = (o - 1) >> 1;
    size_t i = ((size_t)b * DWT_ + t) * D_ + d;
    acc += llo[i] * hd[2] + lho[i] * gd[2];
    if (t + 1 < DWT_) {
      size_t i2 = ((size_t)b * DWT_ + t + 1) * D_ + d;
      acc += llo[i2] * hd[0] + lho[i2] * gd[0];
    }
  }
  outp[((size_t)b * D_ + d) * RECON_LEN + o] = acc;
}

// ---------------------------------------------------------------------------
extern "C" void kernel_launch(void* const* d_in, const int* in_sizes, int n_in,
                              void* d_out, int out_size, void* d_ws, size_t ws_size,
                              hipStream_t stream)
{
  const float* x       = (const float*)d_in[0];
  const float* revin_w = (const float*)d_in[1];
  const float* revin_b = (const float*)d_in[2];
  const float* patch_W = (const float*)d_in[3];
  const float* patch_b = (const float*)d_in[4];
  const float* pos_emb = (const float*)d_in[5];
  const float* dwt_h   = (const float*)d_in[6];
  const float* dwt_g   = (const float*)d_in[7];
  const float* raw_tau = (const float*)d_in[8];
  const float* attn_W  = (const float*)d_in[9];
  const float* attn_b  = (const float*)d_in[10];
  const float* mlp_W1  = (const float*)d_in[11];
  const float* mlp_b1  = (const float*)d_in[12];
  const float* mlp_W2  = (const float*)d_in[13];
  const float* mlp_b2  = (const float*)d_in[14];
  const float* ln_g    = (const float*)d_in[15];
  const float* ln_b    = (const float*)d_in[16];
  const float* ll_gate = (const float*)d_in[17];
  const float* lh_gate = (const float*)d_in[18];
  const float* head_W  = (const float*)d_in[19];
  const float* head_b  = (const float*)d_in[20];

  float* ws  = (float*)d_ws;
  float* out = (float*)d_out;

  float* meanp = ws + WS_MEAN;
  float* stdp  = ws + WS_STD;
  float* xn    = ws + WS_XN;
  float* pseq  = ws + WS_PSEQ;
  float* llseq = ws + WS_LLSEQ;
  float* lhseq = ws + WS_LHSEQ;
  float* llout = ws + WS_LLOUT;
  float* lhout = ws + WS_LHOUT;
  float* crossb= ws + WS_CROSS;
  float* gateb = ws + WS_GATE;
  float* llo   = ws + WS_LLO;
  float* lho   = ws + WS_LHO;
  float* part  = ws + WS_PART;

  unsigned short* llf16 = (unsigned short*)(ws + WS_LLF);
  unsigned short* lhf16 = (unsigned short*)(ws + WS_LHF);
  unsigned short* Qb16  = (unsigned short*)(ws + WS_QB);
  unsigned short* Kb16  = (unsigned short*)(ws + WS_KB);
  unsigned short* Vt16  = (unsigned short*)(ws + WS_VT);
  unsigned short* Ob16  = (unsigned short*)(ws + WS_OB);
  unsigned short* hid16 = (unsigned short*)(ws + WS_HID2);

  unsigned short* wt  = (unsigned short*)(ws + WS_PSEQ);  // bf16 weights (after dwt)
  unsigned short* w1t = wt + 12 * 262144;                 // 2 x [2048][512]
  unsigned short* w2t = w1t + 2 * 1048576;                // 2 x [512][2048]

  // ---- stage 0: RevIN + patch embed + patches output + DWT(+gate) ----
  k_revin<<<8, 256, 0, stream>>>(x, revin_w, revin_b, meanp, stdp, xn);
  k_patch<<<dim3(N_, B_), 512, 0, stream>>>(xn, patch_W, patch_b, pos_emb, pseq);
  k_transpose<<<dim3(16, 32, B_), dim3(32, 8), 0, stream>>>(pseq, out + PATCHES_O);
  k_dwt<<<dim3(DWT_, B_), 512, 0, stream>>>(pseq, dwt_h, dwt_g, llseq, lhseq,
                                            out + OUT_LL_O, out + OUT_LH_O,
                                            raw_tau, gateb);

  // ---- weight transpose+convert (pseq region is dead now) ----
  k_wt<<<dim3(16, 16, 12), dim3(32, 8), 0, stream>>>(attn_W, wt, 512, 512);
  k_wt<<<dim3(64, 16, 2), dim3(32, 8), 0, stream>>>(mlp_W1, w1t, 512, 2048);
  k_wt<<<dim3(16, 64, 2), dim3(32, 8), 0, stream>>>(mlp_W2, w2t, 2048, 512);

  // ---- stage 1: LL + LH MHAs batched ----
  k_gemm_mfma<64,1,3><<<dim3(12, 64, 2), 256, 0, stream>>>(
      llseq, llseq, lhseq, lhseq, wt, attn_b, nullptr, nullptr,
      Qb16, Kb16, Vt16, MR_, 1536, D_, 0, 4 * 262144, 2048);
  k_mattn<<<dim3(64, 8, 2), 256, 0, stream>>>(Qb16, Kb16, Vt16, gateb, Ob16);
  k_gemm_mfma<64,0,0><<<dim3(4, 64, 2), 256, 0, stream>>>(
      Ob16, nullptr, Ob16 + (size_t)2093056, nullptr, wt + 3 * 262144,
      attn_b + 1536, nullptr, nullptr, llout, lhout, nullptr,
      MR_, D_, D_, 0, 4 * 262144, 2048);

  // ---- cross MHA: Q from llout, K/V from lhout ----
  k_gemm_mfma<64,1,3><<<dim3(12, 64, 1), 256, 0, stream>>>(
      llout, lhout, nullptr, nullptr, wt + 8 * 262144, attn_b + 2 * 2048,
      nullptr, nullptr, Qb16, Kb16, Vt16, MR_, 1536, D_, 0, 0, 0);
  k_mattn<<<dim3(64, 8, 1), 256, 0, stream>>>(Qb16, Kb16, Vt16, nullptr, Ob16);
  k_gemm_mfma<64,0,0><<<dim3(4, 64, 1), 256, 0, stream>>>(
      Ob16, nullptr, nullptr, nullptr, wt + 11 * 262144, attn_b + 2 * 2048 + 1536,
      nullptr, nullptr, crossb, nullptr, nullptr, MR_, D_, D_, 0, 0, 0);

  // ---- stage 2: fused LN (bf16 out) + batched MLP ----
  k_ln2<<<dim3(MR_, 2), 256, 0, stream>>>(llseq, llout, crossb, lhseq, lhout,
                                          ln_g, ln_b, llf16, lhf16);
  k_gemm_mfma<128,0,1><<<dim3(16, 32, 2), 256, 0, stream>>>(
      llf16, nullptr, lhf16, nullptr, w1t, mlp_b1, nullptr, nullptr,
      hid16, hid16 + (size_t)4088 * 2048, nullptr, MR_, DFF_, D_, 1,
      1048576, 2048);
  k_gemm_mfma<64,0,0,1><<<dim3(4, 64, 2), 256, 0, stream>>>(
      hid16, nullptr, hid16 + (size_t)4088 * 2048, nullptr, w2t, mlp_b2,
      llf16, lhf16, llo, lho, nullptr, MR_, D_, DFF_, 0, 1048576, 512);

  // ---- stage 3: head + denorm ----
  k_head_partial<<<2 * DWT_, 256, 0, stream>>>(llo, lho, ll_gate, lh_gate, head_W, part);
  k_head_final<<<192, 256, 0, stream>>>(part, head_b, revin_w, revin_b, meanp, stdp,
                                        out + PREDS_O);

  // ---- stage 4: inverse DWT recon ----
  k_recon<<<dim3(RECON_LEN, B_), 512, 0, stream>>>(llo, lho, dwt_h, dwt_g, out + RECON_O);
}

// Round 7
// 487.358 us; speedup vs baseline: 10.1109x; 1.0950x over previous
//
#include <hip/hip_runtime.h>
#include <math.h>

#define B_    8
#define SEQ_  8192
#define D_    512
#define N_    1023
#define DWT_  511
#define DFF_  2048
#define MR_   (B_ * DWT_)          // 4088 rows for all [B*L, D] GEMMs

// ---------------- d_out layout (flat concat of the 5 outputs) ----------------
#define PREDS_O    0
#define RECON_O    768
#define RECON_LEN  1022
#define PATCHES_O  (RECON_O + 8*512*1022)   // 4186880
#define OUT_LL_O   (PATCHES_O + 8*512*1023) // 8377088
#define OUT_LH_O   (OUT_LL_O + 8*512*511)   // 10470144

// ---------------- workspace layout (float units) ----------------
#define WS_MEAN   ((size_t)0)
#define WS_STD    ((size_t)8)
#define WS_XN     ((size_t)16)
#define WS_PSEQ   ((size_t)65552)
#define WS_LLSEQ  ((size_t)4255760)    // bf16 [4088][512] (uses half region)
#define WS_LHSEQ  ((size_t)6348816)    // bf16
#define WS_LLOUT  ((size_t)16814096)
#define WS_LHOUT  ((size_t)18907152)
#define WS_CROSS  ((size_t)21000208)
#define WS_GATE   ((size_t)23093264)
#define WS_LLF    ((size_t)23097352)   // bf16 [4088][512]
#define WS_LHF    ((size_t)25190408)   // bf16
#define WS_LLO    WS_LLOUT
#define WS_LHO    WS_LHOUT
#define WS_PART   WS_CROSS             // head partials alias cross (disjoint phase)
// bf16 buffers beyond the old arena (ws ~766MiB)
#define WS_QB     ((size_t)27283464)   // 2 x [4088][512] bf16
#define WS_KB     (WS_QB + 2093056)
#define WS_VT     (WS_KB + 2093056)    // 2 x [4096][512] bf16
#define WS_OB     (WS_VT + 2097152)
#define WS_HID2   (WS_OB + 2093056)    // 2 x [4088][2048] bf16
#define WS_LLO16  (WS_HID2 + 8372224)  // 2 x [4088][512] bf16 (llout16, lhout16)

using bf16x8 = __attribute__((ext_vector_type(8))) short;
using u16x8  = __attribute__((ext_vector_type(8))) unsigned short;
using f32x4  = __attribute__((ext_vector_type(4))) float;

__device__ inline unsigned short f2bf(float f) {
  unsigned u = __float_as_uint(f);
  u += 0x7fffu + ((u >> 16) & 1u);    // round-to-nearest-even
  return (unsigned short)(u >> 16);
}
__device__ inline float bf2f(unsigned short h) {
  return __uint_as_float(((unsigned)h) << 16);
}

// async global->LDS DMA, 16B per lane; lds base must be wave-uniform.
__device__ __forceinline__ void gld16(const void* g, void* lds) {
  __builtin_amdgcn_global_load_lds(
      (const __attribute__((address_space(1))) unsigned int*)g,
      (__attribute__((address_space(3))) unsigned int*)lds, 16, 0, 0);
}

// ---------------------------------------------------------------------------
__global__ __launch_bounds__(256) void k_revin(const float* __restrict__ x,
    const float* __restrict__ rw, const float* __restrict__ rb,
    float* __restrict__ meanp, float* __restrict__ stdp, float* __restrict__ xn)
{
  __shared__ float rs[256], rs2[256];
  int b = blockIdx.x, tid = threadIdx.x;
  const float* xb = x + (size_t)b * SEQ_;
  float s = 0.f, s2 = 0.f;
  for (int i = tid; i < SEQ_; i += 256) { float v = xb[i]; s += v; s2 += v * v; }
  rs[tid] = s; rs2[tid] = s2; __syncthreads();
  for (int o = 128; o > 0; o >>= 1) {
    if (tid < o) { rs[tid] += rs[tid + o]; rs2[tid] += rs2[tid + o]; }
    __syncthreads();
  }
  float mu = rs[0] / SEQ_;
  float var = rs2[0] / SEQ_ - mu * mu;
  float sd = sqrtf(var + 1e-5f);
  if (tid == 0) { meanp[b] = mu; stdp[b] = sd; }
  float w = rw[0], bb = rb[0], inv = 1.f / sd;
  for (int i = tid; i < SEQ_; i += 256)
    xn[(size_t)b * SEQ_ + i] = (xb[i] - mu) * inv * w + bb;
}

// ---------------------------------------------------------------------------
__global__ __launch_bounds__(512) void k_patch(const float* __restrict__ xn,
    const float* __restrict__ pW, const float* __restrict__ pb,
    const float* __restrict__ pos, float* __restrict__ p_seq)
{
  __shared__ float sx[16];
  int n = blockIdx.x, b = blockIdx.y, d = threadIdx.x;
  if (threadIdx.x < 16) sx[threadIdx.x] = xn[(size_t)b * SEQ_ + n * 8 + threadIdx.x];
  __syncthreads();
  float acc = pb[d] + pos[(size_t)n * D_ + d];
#pragma unroll
  for (int k = 0; k < 16; ++k) acc += sx[k] * pW[k * D_ + d];
  p_seq[((size_t)b * N_ + n) * D_ + d] = acc;
}

// ---------------------------------------------------------------------------
__global__ __launch_bounds__(256) void k_transpose(const float* __restrict__ p_seq,
                                                   float* __restrict__ outp)
{
  __shared__ float tile[32][33];
  int d0 = blockIdx.x * 32, n0 = blockIdx.y * 32, b = blockIdx.z;
  int tx = threadIdx.x, ty = threadIdx.y;
#pragma unroll
  for (int r = 0; r < 4; ++r) {
    int n = n0 + ty + 8 * r;
    if (n < N_) tile[ty + 8 * r][tx] = p_seq[((size_t)b * N_ + n) * D_ + d0 + tx];
  }
  __syncthreads();
#pragma unroll
  for (int r = 0; r < 4; ++r) {
    int d = d0 + ty + 8 * r, n = n0 + tx;
    if (n < N_) outp[((size_t)b * D_ + d) * N_ + n] = tile[tx][ty + 8 * r];
  }
}

// ---------------------------------------------------------------------------
// DWT + fused energy gate; sequence outputs in bf16, d_out copies in fp32
__global__ __launch_bounds__(512) void k_dwt(const float* __restrict__ p_seq,
    const float* __restrict__ h, const float* __restrict__ g,
    unsigned short* __restrict__ ll_seq, unsigned short* __restrict__ lh_seq,
    float* __restrict__ ll_out, float* __restrict__ lh_out,
    const float* __restrict__ raw_tau, float* __restrict__ gate)
{
  __shared__ float red[512];
  int t = blockIdx.x, b = blockIdx.y, d = threadIdx.x;
  float ah = 0.f, ag = 0.f;
#pragma unroll
  for (int k = 0; k < 4; ++k) {
    int n = 2 * t + k - 1;
    if (n >= 0 && n < N_) {
      float v = p_seq[((size_t)b * N_ + n) * D_ + d];
      ah += v * h[d * 4 + k];
      ag += v * g[d * 4 + k];
    }
  }
  ll_seq[((size_t)b * DWT_ + t) * D_ + d] = f2bf(ah);
  lh_seq[((size_t)b * DWT_ + t) * D_ + d] = f2bf(ag);
  ll_out[((size_t)b * D_ + d) * DWT_ + t] = ah;
  lh_out[((size_t)b * D_ + d) * DWT_ + t] = ag;
  red[d] = fabsf(ag);
  __syncthreads();
  for (int o = 256; o > 0; o >>= 1) {
    if (d < o) red[d] += red[d + o];
    __syncthreads();
  }
  if (d == 0) {
    float tau = 1.f / (1.f + expf(-raw_tau[0]));
    float e = red[0] / (float)D_;
    gate[(size_t)b * DWT_ + t] = 1.f / (1.f + expf(-(e - tau) * 10.f));
  }
}

// ---------------------------------------------------------------------------
// weight transpose+convert: src fp32 [K][N] (z-th matrix) -> dst bf16 [N][K]
__global__ __launch_bounds__(256) void k_wt(const float* __restrict__ src,
    unsigned short* __restrict__ dst, int K, int N)
{
  __shared__ float t[32][33];
  int z = blockIdx.z;
  src += (size_t)z * K * N;
  dst += (size_t)z * K * N;
  int n0 = blockIdx.x * 32, k0 = blockIdx.y * 32;
  int tx = threadIdx.x, ty = threadIdx.y;     // (32, 8)
#pragma unroll
  for (int r = 0; r < 4; ++r)
    t[ty + 8 * r][tx] = src[(size_t)(k0 + ty + 8 * r) * N + n0 + tx];
  __syncthreads();
#pragma unroll
  for (int r = 0; r < 4; ++r)
    dst[(size_t)(n0 + ty + 8 * r) * K + k0 + tx] = f2bf(t[tx][ty + 8 * r]);
}

// ---------------------------------------------------------------------------
// C = A(bf16) @ WT(bf16 [N][K])^T + bias (+res) (opt gelu) via MFMA, z-batched.
// Staging via global_load_lds DMA: linear LDS dest + pre-swizzled global src.
// CMODE 0: fp32 C[m][n] (+res; RESBF: residual bf16). 1: bf16 C[m][n].
// CMODE 3: fused QKV: n<512->Q bf16; <1024->K bf16; >=1024->V transposed.
// CMODE 4: fp32 C0/C1 AND bf16 copy into C2 (+z*2093056 u16).
template<int BM, int CMODE, int RESBF = 0>
__global__ __launch_bounds__(256, BM == 64 ? 4 : 2) void k_gemm_mfma(
    const void* __restrict__ A00, const void* __restrict__ A01,
    const void* __restrict__ A10, const void* __restrict__ A11,
    const unsigned short* __restrict__ WT, const float* __restrict__ bias,
    const void* __restrict__ res0, const void* __restrict__ res1,
    void* __restrict__ C0, void* __restrict__ C1, void* __restrict__ C2,
    int M, int N, int K, int act, int zsW, int zsB)
{
  __shared__ unsigned char lds[(BM + 128) * 128];
  unsigned char* sA = lds;
  unsigned char* sB = lds + BM * 128;

  const int tid = threadIdx.x;
  const int wid = tid >> 6, lane = tid & 63;
  const int n0 = blockIdx.x * 128, m0 = blockIdx.y * BM;
  const int z = blockIdx.z;
  constexpr int MI = 4;
  constexpr int NI = (BM == 128) ? 4 : 2;
  const int wrow = (BM == 128) ? (wid >> 1) * 64 : 0;
  const int wcol = (BM == 128) ? (wid & 1) * 64 : wid * 32;
  const int l16 = lane & 15, lh = lane >> 4;

  const unsigned short* wt_ = WT + (size_t)z * zsW;
  const float* bias_ = bias + (size_t)z * zsB;
  const unsigned short* Ap;
  if (CMODE == 3) Ap = (const unsigned short*)(z ? (n0 < 512 ? A10 : A11)
                                                 : (n0 < 512 ? A00 : A01));
  else            Ap = (const unsigned short*)(z ? A10 : A00);

  f32x4 acc[MI][NI];
#pragma unroll
  for (int i = 0; i < MI; ++i)
#pragma unroll
    for (int j = 0; j < NI; ++j) acc[i][j] = (f32x4){0.f, 0.f, 0.f, 0.f};

  for (int k0 = 0; k0 < K; k0 += 64) {
    __syncthreads();
    // ---- stage A via DMA (pre-swizzled source) ----
    constexpr int PA = BM / 32;            // passes per wave
#pragma unroll
    for (int p = 0; p < PA; ++p) {
      int s0 = wid * (BM * 2) + p * 64;
      int s = s0 + lane;
      int row = s >> 3, oct = s & 7;
      int gr = m0 + row; if (gr > M - 1) gr = M - 1;
      gld16(Ap + (size_t)gr * K + k0 + ((oct ^ (row & 7)) << 3),
            sA + (size_t)s0 * 16);
    }
    // ---- stage B via DMA ----
#pragma unroll
    for (int p = 0; p < 4; ++p) {
      int s0 = wid * 256 + p * 64;
      int s = s0 + lane;
      int row = s >> 3, oct = s & 7;
      gld16(wt_ + (size_t)(n0 + row) * K + k0 + ((oct ^ (row & 7)) << 3),
            sB + (size_t)s0 * 16);
    }
    __syncthreads();
    // ---- MFMA ----
#pragma unroll
    for (int s = 0; s < 2; ++s) {
      bf16x8 af[MI], bfr[NI];
#pragma unroll
      for (int i = 0; i < MI; ++i) {
        int r = wrow + i * 16 + l16;
        af[i] = *(const bf16x8*)(sA + r * 128 + (((s * 4 + lh) ^ (r & 7)) << 4));
      }
#pragma unroll
      for (int j = 0; j < NI; ++j) {
        int r = wcol + j * 16 + l16;
        bfr[j] = *(const bf16x8*)(sB + r * 128 + (((s * 4 + lh) ^ (r & 7)) << 4));
      }
#pragma unroll
      for (int i = 0; i < MI; ++i)
#pragma unroll
        for (int j = 0; j < NI; ++j)
          acc[i][j] = __builtin_amdgcn_mfma_f32_16x16x32_bf16(af[i], bfr[j],
                                                              acc[i][j], 0, 0, 0);
    }
  }
  // ---- epilogue ----
  const void* res_ = z ? res1 : res0;
#pragma unroll
  for (int i = 0; i < MI; ++i) {
#pragma unroll
    for (int r = 0; r < 4; ++r) {
      int m = m0 + wrow + i * 16 + lh * 4 + r;
      if (m >= M) continue;
#pragma unroll
      for (int j = 0; j < NI; ++j) {
        int n = n0 + wcol + j * 16 + l16;
        float v = acc[i][j][r] + bias_[n];
        if (act) v = 0.5f * v * (1.f + erff(v * 0.70710678118654752f));
        if (CMODE == 0) {
          float* Cp = (float*)(z ? C1 : C0);
          if (res_) {
            float rv = RESBF ? bf2f(((const unsigned short*)res_)[(size_t)m * N + n])
                             : ((const float*)res_)[(size_t)m * N + n];
            v += rv;
          }
          Cp[(size_t)m * N + n] = v;
        } else if (CMODE == 1) {
          unsigned short* Cp = (unsigned short*)(z ? C1 : C0);
          Cp[(size_t)m * N + n] = f2bf(v);
        } else if (CMODE == 4) {
          float* Cp = (float*)(z ? C1 : C0);
          Cp[(size_t)m * N + n] = v;
          ((unsigned short*)C2)[(size_t)z * 2093056 + (size_t)m * N + n] = f2bf(v);
        } else {
          if (n < 512) {
            ((unsigned short*)C0)[(size_t)z * 2093056 + (size_t)m * 512 + n] = f2bf(v);
          } else if (n < 1024) {
            ((unsigned short*)C1)[(size_t)z * 2093056 + (size_t)m * 512 + (n - 512)] = f2bf(v);
          } else {
            int bb = m / DWT_;
            int key = m - bb * DWT_;
            ((unsigned short*)C2)[(size_t)z * 2097152 +
                ((size_t)(bb * 512 + (n - 1024))) * 512 + key] = f2bf(v);
          }
        }
      }
    }
  }
}

// ---------------------------------------------------------------------------
// MFMA flash attention, z-batched, register-prefetched K/V staging (T14).
__global__ __launch_bounds__(256) void k_mattn(
    const unsigned short* __restrict__ Qb, const unsigned short* __restrict__ Kb,
    const unsigned short* __restrict__ Vt, const float* __restrict__ gate,
    unsigned short* __restrict__ Ob)
{
  __shared__ unsigned char sQ[8192], sK[8192], sV[8192], sP[8192];
  __shared__ float sG[64];

  const int bh = blockIdx.x;
  const int b = bh >> 3;
  const int q0 = blockIdx.y * 64;
  const int z = blockIdx.z;
  const int tid = threadIdx.x;
  const int w = tid >> 6, lane = tid & 63;
  const int l16 = lane & 15, lh = lane >> 4;
  const bool hg = (z == 1) && (gate != nullptr);
  const int bD = b * DWT_;

  const unsigned short* Qz = Qb + (size_t)z * 2093056;
  const unsigned short* Kz = Kb + (size_t)z * 2093056;
  const unsigned short* Vz = Vt + (size_t)z * 2097152;
  unsigned short* Oz = Ob + (size_t)z * 2093056;
  const int h64 = (bh & 7) * 64;
  const unsigned short* vrow = Vz + (size_t)bh * 64 * 512;

  // stage Q tile [64 q][64 d]
#pragma unroll
  for (int it = 0; it < 2; ++it) {
    int i = it * 256 + tid;
    int row = i >> 3, oct = i & 7;
    int qr = q0 + row; if (qr > DWT_ - 1) qr = DWT_ - 1;
    u16x8 v = *(const u16x8*)(Qz + (size_t)(bD + qr) * 512 + h64 + oct * 8);
    *(u16x8*)(sQ + row * 128 + ((oct ^ (row & 7)) << 4)) = v;
  }

  // preload full gate vector (2 keys per thread)
  float ga = 0.f, gb2 = 0.f;
  if (hg) {
    int k = 2 * tid;
    ga  = (k     < DWT_) ? gate[(size_t)bD + k]     : 0.f;
    gb2 = (k + 1 < DWT_) ? gate[(size_t)bD + k + 1] : 0.f;
  }

  float m_ = -1e30f, l_ = 0.f;
  f32x4 accO[4];
#pragma unroll
  for (int jb = 0; jb < 4; ++jb) accO[jb] = (f32x4){0.f, 0.f, 0.f, 0.f};

  unsigned char* sPw = sP + w * 2048;   // wave-private [16 q][64 key] bf16

  uint4 pk0, pk1, pv0, pv1;
#define LOADT(kt_) do {                                                      \
    int k0_ = (kt_) * 64;                                                    \
    int row_ = tid >> 3, oct_ = tid & 7;                                     \
    int kr0_ = k0_ + row_;      if (kr0_ > DWT_ - 1) kr0_ = DWT_ - 1;        \
    int kr1_ = k0_ + row_ + 32; if (kr1_ > DWT_ - 1) kr1_ = DWT_ - 1;        \
    pk0 = *(const uint4*)(Kz + (size_t)(bD + kr0_) * 512 + h64 + oct_ * 8);  \
    pk1 = *(const uint4*)(Kz + (size_t)(bD + kr1_) * 512 + h64 + oct_ * 8);  \
    pv0 = *(const uint4*)(vrow + (size_t)row_ * 512 + k0_ + oct_ * 8);       \
    pv1 = *(const uint4*)(vrow + (size_t)(row_ + 32) * 512 + k0_ + oct_ * 8);\
  } while (0)

  LOADT(0);
  for (int kt = 0; kt < 8; ++kt) {
    const int k0 = kt * 64;
    __syncthreads();                    // prior-iter PV reads complete
    {
      int row = tid >> 3, oct = tid & 7, row1 = (tid >> 3) + 32;
      *(uint4*)(sK + row  * 128 + ((oct ^ (row  & 7)) << 4)) = pk0;
      *(uint4*)(sK + row1 * 128 + ((oct ^ (row1 & 7)) << 4)) = pk1;
      *(uint4*)(sV + row  * 128 + ((oct ^ (row  & 7)) << 4)) = pv0;
      *(uint4*)(sV + row1 * 128 + ((oct ^ (row1 & 7)) << 4)) = pv1;
    }
    if (hg && (tid >> 5) == kt) {
      sG[(tid & 31) * 2]     = ga;
      sG[(tid & 31) * 2 + 1] = gb2;
    }
    __syncthreads();
    if (kt < 7) LOADT(kt + 1);          // prefetch next tile under compute

    // ---- S^T strip: rows = 64 keys (4 blocks), cols = wave's 16 q ----
    f32x4 sacc[4];
#pragma unroll
    for (int i = 0; i < 4; ++i) sacc[i] = (f32x4){0.f, 0.f, 0.f, 0.f};
#pragma unroll
    for (int s = 0; s < 2; ++s) {
      int qr = w * 16 + l16;
      bf16x8 qf = *(const bf16x8*)(sQ + qr * 128 + ((((s << 2) + lh) ^ (qr & 7)) << 4));
#pragma unroll
      for (int i = 0; i < 4; ++i) {
        int krr = i * 16 + l16;
        bf16x8 kf = *(const bf16x8*)(sK + krr * 128 + ((((s << 2) + lh) ^ (krr & 7)) << 4));
        sacc[i] = __builtin_amdgcn_mfma_f32_16x16x32_bf16(kf, qf, sacc[i], 0, 0, 0);
      }
    }

    // ---- softmax (lane owns one q) ----
    float sv[4][4];
    float tm = -1e30f;
#pragma unroll
    for (int i = 0; i < 4; ++i)
#pragma unroll
      for (int r = 0; r < 4; ++r) {
        float v = sacc[i][r] * 0.125f;
        if (k0 + i * 16 + lh * 4 + r >= DWT_) v = -1e30f;
        sv[i][r] = v;
        tm = fmaxf(tm, v);
      }
    tm = fmaxf(tm, __shfl_xor(tm, 16));
    tm = fmaxf(tm, __shfl_xor(tm, 32));
    float mn = fmaxf(m_, tm);
    float corr = __expf(m_ - mn);
    m_ = mn;
    float ts = 0.f;
    float p[4][4];
#pragma unroll
    for (int i = 0; i < 4; ++i)
#pragma unroll
      for (int r = 0; r < 4; ++r) {
        float e = __expf(sv[i][r] - mn);
        p[i][r] = e; ts += e;
      }
    ts += __shfl_xor(ts, 16);
    ts += __shfl_xor(ts, 32);
    l_ = l_ * corr + ts;

    // rescale accO (rows q-local = lh*4 + r; corr held by lane q-local)
#pragma unroll
    for (int r = 0; r < 4; ++r) {
      float cr = __shfl(corr, (lh << 2) + r);
#pragma unroll
      for (int jb = 0; jb < 4; ++jb) accO[jb][r] *= cr;
    }

    // gate + write P bf16 to wave-private LDS [q=l16][key]
#pragma unroll
    for (int i = 0; i < 4; ++i)
#pragma unroll
      for (int r = 0; r < 4; ++r) {
        float pv = p[i][r];
        int key = i * 16 + (lh << 2) + r;
        if (hg) pv *= sG[key];
        int slot = (key >> 3) ^ (l16 & 7);
        *(unsigned short*)(sPw + l16 * 128 + (slot << 4) + (key & 7) * 2) = f2bf(pv);
      }

    // ---- PV: A = P [16q][64key], B = V [key][d] from sV[d][key] ----
#pragma unroll
    for (int s = 0; s < 2; ++s) {
      bf16x8 pf = *(const bf16x8*)(sPw + l16 * 128 + ((((s << 2) + lh) ^ (l16 & 7)) << 4));
#pragma unroll
      for (int jb = 0; jb < 4; ++jb) {
        int vr = jb * 16 + l16;
        bf16x8 vf = *(const bf16x8*)(sV + vr * 128 + ((((s << 2) + lh) ^ (vr & 7)) << 4));
        accO[jb] = __builtin_amdgcn_mfma_f32_16x16x32_bf16(pf, vf, accO[jb], 0, 0, 0);
      }
    }
  }
#undef LOADT

  // ---- epilogue ----
  float linv = 1.f / l_;
#pragma unroll
  for (int r = 0; r < 4; ++r) {
    float li = __shfl(linv, (lh << 2) + r);
    int q = q0 + w * 16 + (lh << 2) + r;
    if (q >= DWT_) continue;
#pragma unroll
    for (int jb = 0; jb < 4; ++jb) {
      Oz[(size_t)(bD + q) * 512 + h64 + jb * 16 + l16] = f2bf(accO[jb][r] * li);
    }
  }
}

// ---------------------------------------------------------------------------
// fused LayerNorm for both branches; seq inputs bf16 -> bf16 outputs
__global__ __launch_bounds__(256) void k_ln2(
    const unsigned short* __restrict__ llseq, const float* __restrict__ llout,
    const float* __restrict__ crossb,
    const unsigned short* __restrict__ lhseq, const float* __restrict__ lhout,
    const float* __restrict__ g, const float* __restrict__ beta,
    unsigned short* __restrict__ llf, unsigned short* __restrict__ lhf)
{
  __shared__ float red[256], red2[256];
  int row = blockIdx.x, tid = threadIdx.x, zz = blockIdx.y;
  const unsigned short* a = zz ? lhseq : llseq;
  const float* b2 = zz ? lhout : llout;
  const float* c  = zz ? nullptr : crossb;
  const float* gg = g + zz * D_;
  const float* bb = beta + zz * D_;
  unsigned short* outp = zz ? lhf : llf;
  size_t base = (size_t)row * D_;
  float v0 = bf2f(a[base + tid]) + b2[base + tid];
  float v1 = bf2f(a[base + tid + 256]) + b2[base + tid + 256];
  if (c) { v0 += c[base + tid]; v1 += c[base + tid + 256]; }
  red[tid] = v0 + v1; red2[tid] = v0 * v0 + v1 * v1;
  __syncthreads();
  for (int o = 128; o > 0; o >>= 1) {
    if (tid < o) { red[tid] += red[tid + o]; red2[tid] += red2[tid + o]; }
    __syncthreads();
  }
  float mu = red[0] / (float)D_;
  float var = red2[0] / (float)D_ - mu * mu;
  float rstd = rsqrtf(var + 1e-5f);
  outp[base + tid]       = f2bf((v0 - mu) * rstd * gg[tid] + bb[tid]);
  outp[base + tid + 256] = f2bf((v1 - mu) * rstd * gg[tid + 256] + bb[tid + 256]);
}

// ---------------------------------------------------------------------------
// head partial: block x = branch*511 + t; thread -> 4 consecutive p (float4 W)
__global__ __launch_bounds__(256) void k_head_partial(
    const float* __restrict__ llo, const float* __restrict__ lho,
    const float* __restrict__ llg, const float* __restrict__ lhg,
    const float* __restrict__ hw, float* __restrict__ part)
{
  __shared__ float lds[8][512];
  int x = blockIdx.x;
  int branch = x / DWT_, t = x % DWT_;
  const float* seq = branch ? lho : llo;
  const float* gt  = branch ? lhg : llg;
  int tid = threadIdx.x;
  for (int i = tid; i < 8 * 512; i += 256) {
    int b = i >> 9, d = i & 511;
    lds[b][d] = seq[((size_t)b * DWT_ + t) * D_ + d] * gt[(size_t)t * D_ + d];
  }
  __syncthreads();
  if (tid < 192) {
    int b = tid / 24, j = tid % 24;          // 24 float4-groups cover 96 preds
    const float* wbase = hw + (size_t)x * D_ * 96 + j * 4;
    float4 acc = make_float4(0.f, 0.f, 0.f, 0.f);
    for (int k = 0; k < 512; ++k) {
      float4 wv = *(const float4*)(wbase + (size_t)k * 96);
      float a = lds[b][k];
      acc.x += a * wv.x; acc.y += a * wv.y; acc.z += a * wv.z; acc.w += a * wv.w;
    }
    *(float4*)&part[(size_t)x * 768 + b * 96 + j * 4] = acc;
  }
}

// wave-per-(b,p) reduction over 1022 chunks
__global__ __launch_bounds__(256) void k_head_final(const float* __restrict__ part,
    const float* __restrict__ hb, const float* __restrict__ rw,
    const float* __restrict__ rb, const float* __restrict__ meanp,
    const float* __restrict__ stdp, float* __restrict__ preds)
{
  int wv = (blockIdx.x << 2) + (threadIdx.x >> 6);
  int lane = threadIdx.x & 63;
  if (wv >= 768) return;
  int b = wv / 96, p = wv - b * 96;
  float s = 0.f;
  for (int c = lane; c < 2 * DWT_; c += 64) s += part[(size_t)c * 768 + b * 96 + p];
#pragma unroll
  for (int off = 32; off; off >>= 1) s += __shfl_xor(s, off);
  if (lane == 0) {
    float acc = s + hb[p];
    preds[b * 96 + p] = (acc - rb[0]) / (rw[0] + 1e-10f) * stdp[b] + meanp[b];
  }
}

// ---------------------------------------------------------------------------
__global__ __launch_bounds__(512) void k_recon(const float* __restrict__ llo,
    const float* __restrict__ lho, const float* __restrict__ h,
    const float* __restrict__ g, float* __restrict__ outp)
{
  int o = blockIdx.x, b = blockIdx.y, d = threadIdx.x;
  const float* hd = h + d * 4;
  const float* gd = g + d * 4;
  float acc = 0.f;
  if ((o & 1) == 0) {
    int t = o >> 1;
    if (t >= 1) {
      size_t i = ((size_t)b * DWT_ + t - 1) * D_ + d;
      acc += llo[i] * hd[3] + lho[i] * gd[3];
    }
    size_t i = ((size_t)b * DWT_ + t) * D_ + d;
    acc += llo[i] * hd[1] + lho[i] * gd[1];
  } else {
    int t = (o - 1) >> 1;
    size_t i = ((size_t)b * DWT_ + t) * D_ + d;
    acc += llo[i] * hd[2] + lho[i] * gd[2];
    if (t + 1 < DWT_) {
      size_t i2 = ((size_t)b * DWT_ + t + 1) * D_ + d;
      acc += llo[i2] * hd[0] + lho[i2] * gd[0];
    }
  }
  outp[((size_t)b * D_ + d) * RECON_LEN + o] = acc;
}

// ---------------------------------------------------------------------------
extern "C" void kernel_launch(void* const* d_in, const int* in_sizes, int n_in,
                              void* d_out, int out_size, void* d_ws, size_t ws_size,
                              hipStream_t stream)
{
  const float* x       = (const float*)d_in[0];
  const float* revin_w = (const float*)d_in[1];
  const float* revin_b = (const float*)d_in[2];
  const float* patch_W = (const float*)d_in[3];
  const float* patch_b = (const float*)d_in[4];
  const float* pos_emb = (const float*)d_in[5];
  const float* dwt_h   = (const float*)d_in[6];
  const float* dwt_g   = (const float*)d_in[7];
  const float* raw_tau = (const float*)d_in[8];
  const float* attn_W  = (const float*)d_in[9];
  const float* attn_b  = (const float*)d_in[10];
  const float* mlp_W1  = (const float*)d_in[11];
  const float* mlp_b1  = (const float*)d_in[12];
  const float* mlp_W2  = (const float*)d_in[13];
  const float* mlp_b2  = (const float*)d_in[14];
  const float* ln_g    = (const float*)d_in[15];
  const float* ln_b    = (const float*)d_in[16];
  const float* ll_gate = (const float*)d_in[17];
  const float* lh_gate = (const float*)d_in[18];
  const float* head_W  = (const float*)d_in[19];
  const float* head_b  = (const float*)d_in[20];

  float* ws  = (float*)d_ws;
  float* out = (float*)d_out;

  float* meanp = ws + WS_MEAN;
  float* stdp  = ws + WS_STD;
  float* xn    = ws + WS_XN;
  float* pseq  = ws + WS_PSEQ;
  float* llout = ws + WS_LLOUT;
  float* lhout = ws + WS_LHOUT;
  float* crossb= ws + WS_CROSS;
  float* gateb = ws + WS_GATE;
  float* llo   = ws + WS_LLO;
  float* lho   = ws + WS_LHO;
  float* part  = ws + WS_PART;

  unsigned short* llseq16 = (unsigned short*)(ws + WS_LLSEQ);
  unsigned short* lhseq16 = (unsigned short*)(ws + WS_LHSEQ);
  unsigned short* llf16 = (unsigned short*)(ws + WS_LLF);
  unsigned short* lhf16 = (unsigned short*)(ws + WS_LHF);
  unsigned short* Qb16  = (unsigned short*)(ws + WS_QB);
  unsigned short* Kb16  = (unsigned short*)(ws + WS_KB);
  unsigned short* Vt16  = (unsigned short*)(ws + WS_VT);
  unsigned short* Ob16  = (unsigned short*)(ws + WS_OB);
  unsigned short* hid16 = (unsigned short*)(ws + WS_HID2);
  unsigned short* llout16 = (unsigned short*)(ws + WS_LLO16);
  unsigned short* lhout16 = llout16 + 2093056;

  unsigned short* wt  = (unsigned short*)(ws + WS_PSEQ);  // bf16 weights (after dwt)
  unsigned short* w1t = wt + 12 * 262144;                 // 2 x [2048][512]
  unsigned short* w2t = w1t + 2 * 1048576;                // 2 x [512][2048]

  // ---- stage 0: RevIN + patch embed + patches output + DWT(+gate) ----
  k_revin<<<8, 256, 0, stream>>>(x, revin_w, revin_b, meanp, stdp, xn);
  k_patch<<<dim3(N_, B_), 512, 0, stream>>>(xn, patch_W, patch_b, pos_emb, pseq);
  k_transpose<<<dim3(16, 32, B_), dim3(32, 8), 0, stream>>>(pseq, out + PATCHES_O);
  k_dwt<<<dim3(DWT_, B_), 512, 0, stream>>>(pseq, dwt_h, dwt_g, llseq16, lhseq16,
                                            out + OUT_LL_O, out + OUT_LH_O,
                                            raw_tau, gateb);

  // ---- weight transpose+convert (pseq region is dead now) ----
  k_wt<<<dim3(16, 16, 12), dim3(32, 8), 0, stream>>>(attn_W, wt, 512, 512);
  k_wt<<<dim3(64, 16, 2), dim3(32, 8), 0, stream>>>(mlp_W1, w1t, 512, 2048);
  k_wt<<<dim3(16, 64, 2), dim3(32, 8), 0, stream>>>(mlp_W2, w2t, 2048, 512);

  // ---- stage 1: LL + LH MHAs batched ----
  k_gemm_mfma<64,3><<<dim3(12, 64, 2), 256, 0, stream>>>(
      llseq16, llseq16, lhseq16, lhseq16, wt, attn_b, nullptr, nullptr,
      Qb16, Kb16, Vt16, MR_, 1536, D_, 0, 4 * 262144, 2048);
  k_mattn<<<dim3(64, 8, 2), 256, 0, stream>>>(Qb16, Kb16, Vt16, gateb, Ob16);
  k_gemm_mfma<64,4><<<dim3(4, 64, 2), 256, 0, stream>>>(
      Ob16, nullptr, Ob16 + (size_t)2093056, nullptr, wt + 3 * 262144,
      attn_b + 1536, nullptr, nullptr, llout, lhout, llout16,
      MR_, D_, D_, 0, 4 * 262144, 2048);

  // ---- cross MHA: Q from llout16, K/V from lhout16 ----
  k_gemm_mfma<64,3><<<dim3(12, 64, 1), 256, 0, stream>>>(
      llout16, lhout16, nullptr, nullptr, wt + 8 * 262144, attn_b + 2 * 2048,
      nullptr, nullptr, Qb16, Kb16, Vt16, MR_, 1536, D_, 0, 0, 0);
  k_mattn<<<dim3(64, 8, 1), 256, 0, stream>>>(Qb16, Kb16, Vt16, nullptr, Ob16);
  k_gemm_mfma<64,0><<<dim3(4, 64, 1), 256, 0, stream>>>(
      Ob16, nullptr, nullptr, nullptr, wt + 11 * 262144, attn_b + 2 * 2048 + 1536,
      nullptr, nullptr, crossb, nullptr, nullptr, MR_, D_, D_, 0, 0, 0);

  // ---- stage 2: fused LN (bf16 out) + batched MLP ----
  k_ln2<<<dim3(MR_, 2), 256, 0, stream>>>(llseq16, llout, crossb, lhseq16, lhout,
                                          ln_g, ln_b, llf16, lhf16);
  k_gemm_mfma<128,1><<<dim3(16, 32, 2), 256, 0, stream>>>(
      llf16, nullptr, lhf16, nullptr, w1t, mlp_b1, nullptr, nullptr,
      hid16, hid16 + (size_t)4088 * 2048, nullptr, MR_, DFF_, D_, 1,
      1048576, 2048);
  k_gemm_mfma<64,0,1><<<dim3(4, 64, 2), 256, 0, stream>>>(
      hid16, nullptr, hid16 + (size_t)4088 * 2048, nullptr, w2t, mlp_b2,
      llf16, lhf16, llo, lho, nullptr, MR_, D_, DFF_, 0, 1048576, 512);

  // ---- stage 3: head + denorm ----
  k_head_partial<<<2 * DWT_, 256, 0, stream>>>(llo, lho, ll_gate, lh_gate, head_W, part);
  k_head_final<<<192, 256, 0, stream>>>(part, head_b, revin_w, revin_b, meanp, stdp,
                                        out + PREDS_O);

  // ---- stage 4: inverse DWT recon ----
  k_recon<<<dim3(RECON_LEN, B_), 512, 0, stream>>>(llo, lho, dwt_h, dwt_g, out + RECON_O);
}